// Round 1
// baseline (5523.544 us; speedup 1.0000x reference)
//
#include <hip/hip_runtime.h>

#define INF 128
#define HF 64

// ---------------- degree / norm ----------------

__global__ void degree_kernel(const int* __restrict__ src, const int* __restrict__ dst,
                              float* __restrict__ dout, float* __restrict__ din, int E) {
    int i = blockIdx.x * blockDim.x + threadIdx.x;
    int stride = gridDim.x * blockDim.x;
    for (; i < E; i += stride) {
        atomicAdd(&dout[src[i]], 1.0f);
        atomicAdd(&din[dst[i]], 1.0f);
    }
}

__global__ void norm_kernel(float* __restrict__ a, float* __restrict__ b, int N) {
    int i = blockIdx.x * blockDim.x + threadIdx.x;
    if (i < N) {
        float v = a[i]; a[i] = v > 0.f ? rsqrtf(v) : 0.f;
        float w = b[i]; b[i] = w > 0.f ? rsqrtf(w) : 0.f;
    }
}

// ---------------- GEMM: H[N,OUT] = (X * rowscale) @ W[128,OUT] ----------------

__device__ inline void fma4(float4& a, float s, const float4& w) {
    a.x = fmaf(s, w.x, a.x);
    a.y = fmaf(s, w.y, a.y);
    a.z = fmaf(s, w.z, a.z);
    a.w = fmaf(s, w.w, a.w);
}

template<int OUT, int RPB>
__global__ __launch_bounds__(256) void gemm_kernel(const float* __restrict__ X,
        const float* __restrict__ rowscale,   // may be null
        const float* __restrict__ W,
        float* __restrict__ H, int N) {
    constexpr int CQ = OUT / 4;      // float4 columns
    constexpr int RP = 256 / CQ;     // row-pairs per block
    static_assert(RPB == 2 * RP, "rows per block mismatch");

    __shared__ float sW[INF * OUT];
    __shared__ float sX[RPB][INF + 4];   // +4 pad, keeps float4 alignment (528B rows)

    const int tid = threadIdx.x;
    const int row0 = blockIdx.x * RPB;

    // stage W (broadcast) into LDS
    for (int i = tid; i < INF * OUT / 4; i += 256)
        reinterpret_cast<float4*>(sW)[i] = reinterpret_cast<const float4*>(W)[i];

    // stage RPB rows of X (optionally row-scaled)
    for (int i = tid; i < RPB * (INF / 4); i += 256) {
        int r  = i >> 5;        // INF/4 == 32
        int kc = i & 31;
        int gr = row0 + r;
        float4 v = make_float4(0.f, 0.f, 0.f, 0.f);
        if (gr < N) {
            v = reinterpret_cast<const float4*>(X)[(size_t)gr * (INF / 4) + kc];
            if (rowscale) {
                float s = rowscale[gr];
                v.x *= s; v.y *= s; v.z *= s; v.w *= s;
            }
        }
        *reinterpret_cast<float4*>(&sX[r][kc * 4]) = v;
    }
    __syncthreads();

    const int cq = tid % CQ;
    const int rp = tid / CQ;
    const int r0 = 2 * rp, r1 = 2 * rp + 1;

    float4 acc0 = make_float4(0.f, 0.f, 0.f, 0.f);
    float4 acc1 = make_float4(0.f, 0.f, 0.f, 0.f);

    #pragma unroll
    for (int k4 = 0; k4 < INF / 4; ++k4) {
        float4 xa = *reinterpret_cast<const float4*>(&sX[r0][k4 * 4]);
        float4 xb = *reinterpret_cast<const float4*>(&sX[r1][k4 * 4]);
        const float4* wr = reinterpret_cast<const float4*>(sW + (k4 * 4) * OUT) + cq;
        float4 w0 = wr[0];
        float4 w1 = wr[CQ];
        float4 w2 = wr[2 * CQ];
        float4 w3 = wr[3 * CQ];
        fma4(acc0, xa.x, w0); fma4(acc0, xa.y, w1); fma4(acc0, xa.z, w2); fma4(acc0, xa.w, w3);
        fma4(acc1, xb.x, w0); fma4(acc1, xb.y, w1); fma4(acc1, xb.z, w2); fma4(acc1, xb.w, w3);
    }

    if (row0 + r0 < N)
        reinterpret_cast<float4*>(H)[(size_t)(row0 + r0) * CQ + cq] = acc0;
    if (row0 + r1 < N)
        reinterpret_cast<float4*>(H)[(size_t)(row0 + r1) * CQ + cq] = acc1;
}

// ---------------- edge scatter: agg[dst] += H[src] ----------------

template<int F>
__global__ __launch_bounds__(256) void scatter_kernel(const float* __restrict__ H,
        const int* __restrict__ src, const int* __restrict__ dst,
        float* __restrict__ agg, int E) {
    constexpr int LPE = F / 4;   // lanes per edge, each lane owns a float4
    int gid = blockIdx.x * blockDim.x + threadIdx.x;
    int e = gid / LPE;
    int l = gid % LPE;
    if (e >= E) return;
    int s = src[e], d = dst[e];
    float4 v = reinterpret_cast<const float4*>(H)[(size_t)s * LPE + l];
    float* p = agg + (size_t)d * F + l * 4;
    atomicAdd(p + 0, v.x);
    atomicAdd(p + 1, v.y);
    atomicAdd(p + 2, v.z);
    atomicAdd(p + 3, v.w);
}

// ---------------- post: out = relu(agg*nin + b) [* nout] ----------------

template<int F>
__global__ __launch_bounds__(256) void post_kernel(const float* __restrict__ agg,
        const float* __restrict__ nin, const float* __restrict__ bias,
        const float* __restrict__ nout_or_null,
        float* __restrict__ out, int N) {
    constexpr int CQ = F / 4;
    int i = blockIdx.x * blockDim.x + threadIdx.x;
    if (i >= N * CQ) return;
    int row = i / CQ;
    int cq  = i % CQ;
    float4 v = reinterpret_cast<const float4*>(agg)[i];
    float s = nin[row];
    float4 b = reinterpret_cast<const float4*>(bias)[cq];
    float4 r;
    r.x = fmaxf(fmaf(v.x, s, b.x), 0.f);
    r.y = fmaxf(fmaf(v.y, s, b.y), 0.f);
    r.z = fmaxf(fmaf(v.z, s, b.z), 0.f);
    r.w = fmaxf(fmaf(v.w, s, b.w), 0.f);
    if (nout_or_null) {
        float t = nout_or_null[row];
        r.x *= t; r.y *= t; r.z *= t; r.w *= t;
    }
    reinterpret_cast<float4*>(out)[i] = r;
}

// ---------------- launch ----------------

extern "C" void kernel_launch(void* const* d_in, const int* in_sizes, int n_in,
                              void* d_out, int out_size, void* d_ws, size_t ws_size,
                              hipStream_t stream) {
    const float* x  = (const float*)d_in[0];
    const float* W1 = (const float*)d_in[1];
    const float* b1 = (const float*)d_in[2];
    const float* W2 = (const float*)d_in[3];
    const float* b2 = (const float*)d_in[4];
    const int*   src = (const int*)d_in[5];
    const int*   dst = (const int*)d_in[6];

    const int N = in_sizes[0] / INF;   // 100000
    const int E = in_sizes[5];         // 1600000

    char* ws = (char*)d_ws;
    size_t padN = (((size_t)N * 4 + 255) / 256) * 256;
    float* nout = (float*)(ws);
    float* nin  = (float*)(ws + padN);
    float* A    = (float*)(ws + 2 * padN);                       // N x 128
    float* B    = (float*)(ws + 2 * padN + (size_t)N * INF * 4); // N x 128

    float* out = (float*)d_out;

    hipMemsetAsync(nout, 0, (size_t)N * sizeof(float), stream);
    hipMemsetAsync(nin,  0, (size_t)N * sizeof(float), stream);
    degree_kernel<<<1024, 256, 0, stream>>>(src, dst, nout, nin, E);
    norm_kernel<<<(N + 255) / 256, 256, 0, stream>>>(nout, nin, N);

    // layer 1: A = (x*nout) @ W1 ; B = scatter(A) ; A = relu(B*nin + b1) * nout
    gemm_kernel<128, 16><<<(N + 15) / 16, 256, 0, stream>>>(x, nout, W1, A, N);
    hipMemsetAsync(B, 0, (size_t)N * INF * sizeof(float), stream);
    scatter_kernel<128><<<(int)(((size_t)E * 32 + 255) / 256), 256, 0, stream>>>(A, src, dst, B, E);
    post_kernel<128><<<(N * 32 + 255) / 256, 256, 0, stream>>>(B, nin, b1, nout, A, N);

    // layer 2: B = A @ W2 ; out = scatter(B) ; out = relu(out*nin + b2)
    gemm_kernel<64, 32><<<(N + 31) / 32, 256, 0, stream>>>(A, nullptr, W2, B, N);
    hipMemsetAsync(out, 0, (size_t)N * HF * sizeof(float), stream);
    scatter_kernel<64><<<(int)(((size_t)E * 16 + 255) / 256), 256, 0, stream>>>(B, src, dst, out, E);
    post_kernel<64><<<(N * 16 + 255) / 256, 256, 0, stream>>>(out, nin, b2, nullptr, out, N);
}

// Round 2
// 1936.594 us; speedup vs baseline: 2.8522x; 2.8522x over previous
//
#include <hip/hip_runtime.h>

#define INF 128
#define HF 64
#define SCAN_T 1024

// ---------------- degree / norm ----------------

__global__ void degree_kernel(const int* __restrict__ src, const int* __restrict__ dst,
                              float* __restrict__ dout, float* __restrict__ din, int E) {
    int i = blockIdx.x * blockDim.x + threadIdx.x;
    int stride = gridDim.x * blockDim.x;
    for (; i < E; i += stride) {
        atomicAdd(&dout[src[i]], 1.0f);
        atomicAdd(&din[dst[i]], 1.0f);
    }
}

__global__ void norm_kernel(float* __restrict__ a, float* __restrict__ b, int N) {
    int i = blockIdx.x * blockDim.x + threadIdx.x;
    if (i < N) {
        float v = a[i]; a[i] = v > 0.f ? rsqrtf(v) : 0.f;
        float w = b[i]; b[i] = w > 0.f ? rsqrtf(w) : 0.f;
    }
}

// ---------------- CSR build ----------------

// single-block exclusive scan of (int)deg[] -> cursor[]
__global__ __launch_bounds__(SCAN_T) void scan_kernel(const float* __restrict__ deg,
                                                      int* __restrict__ cursor, int N) {
    __shared__ int part[SCAN_T];
    const int t = threadIdx.x;
    const int chunk = (N + SCAN_T - 1) / SCAN_T;
    const int beg = t * chunk;
    const int end = min(beg + chunk, N);
    int s = 0;
    for (int i = beg; i < end; ++i) s += (int)deg[i];
    part[t] = s;
    __syncthreads();
    for (int off = 1; off < SCAN_T; off <<= 1) {
        int v = (t >= off) ? part[t - off] : 0;
        __syncthreads();
        part[t] += v;
        __syncthreads();
    }
    int run = (t == 0) ? 0 : part[t - 1];
    for (int i = beg; i < end; ++i) {
        cursor[i] = run;
        run += (int)deg[i];
    }
}

// scatter edges into dst-sorted order; cursor becomes inclusive row-end
__global__ void fill_kernel(const int* __restrict__ src, const int* __restrict__ dst,
                            int* __restrict__ cursor, int* __restrict__ esrc, int E) {
    int i = blockIdx.x * blockDim.x + threadIdx.x;
    int stride = gridDim.x * blockDim.x;
    for (; i < E; i += stride) {
        int pos = atomicAdd(&cursor[dst[i]], 1);
        esrc[pos] = src[i];
    }
}

// ---------------- GEMM: H[N,OUT] = (X * rowscale) @ W[128,OUT] ----------------

__device__ inline void fma4(float4& a, float s, const float4& w) {
    a.x = fmaf(s, w.x, a.x);
    a.y = fmaf(s, w.y, a.y);
    a.z = fmaf(s, w.z, a.z);
    a.w = fmaf(s, w.w, a.w);
}

template<int OUT, int RPB>
__global__ __launch_bounds__(256) void gemm_kernel(const float* __restrict__ X,
        const float* __restrict__ rowscale,   // may be null
        const float* __restrict__ W,
        float* __restrict__ H, int N) {
    constexpr int CQ = OUT / 4;      // float4 columns
    constexpr int RP = 256 / CQ;     // row-pairs per block
    static_assert(RPB == 2 * RP, "rows per block mismatch");

    __shared__ float sW[INF * OUT];
    __shared__ float sX[RPB][INF + 4];

    const int tid = threadIdx.x;
    const int row0 = blockIdx.x * RPB;

    for (int i = tid; i < INF * OUT / 4; i += 256)
        reinterpret_cast<float4*>(sW)[i] = reinterpret_cast<const float4*>(W)[i];

    for (int i = tid; i < RPB * (INF / 4); i += 256) {
        int r  = i >> 5;
        int kc = i & 31;
        int gr = row0 + r;
        float4 v = make_float4(0.f, 0.f, 0.f, 0.f);
        if (gr < N) {
            v = reinterpret_cast<const float4*>(X)[(size_t)gr * (INF / 4) + kc];
            if (rowscale) {
                float s = rowscale[gr];
                v.x *= s; v.y *= s; v.z *= s; v.w *= s;
            }
        }
        *reinterpret_cast<float4*>(&sX[r][kc * 4]) = v;
    }
    __syncthreads();

    const int cq = tid % CQ;
    const int rp = tid / CQ;
    const int r0 = 2 * rp, r1 = 2 * rp + 1;

    float4 acc0 = make_float4(0.f, 0.f, 0.f, 0.f);
    float4 acc1 = make_float4(0.f, 0.f, 0.f, 0.f);

    #pragma unroll
    for (int k4 = 0; k4 < INF / 4; ++k4) {
        float4 xa = *reinterpret_cast<const float4*>(&sX[r0][k4 * 4]);
        float4 xb = *reinterpret_cast<const float4*>(&sX[r1][k4 * 4]);
        const float4* wr = reinterpret_cast<const float4*>(sW + (k4 * 4) * OUT) + cq;
        float4 w0 = wr[0];
        float4 w1 = wr[CQ];
        float4 w2 = wr[2 * CQ];
        float4 w3 = wr[3 * CQ];
        fma4(acc0, xa.x, w0); fma4(acc0, xa.y, w1); fma4(acc0, xa.z, w2); fma4(acc0, xa.w, w3);
        fma4(acc1, xb.x, w0); fma4(acc1, xb.y, w1); fma4(acc1, xb.z, w2); fma4(acc1, xb.w, w3);
    }

    if (row0 + r0 < N)
        reinterpret_cast<float4*>(H)[(size_t)(row0 + r0) * CQ + cq] = acc0;
    if (row0 + r1 < N)
        reinterpret_cast<float4*>(H)[(size_t)(row0 + r1) * CQ + cq] = acc1;
}

// ---------------- CSR gather-aggregate + fused post ----------------

// F=128: one wave per node, float2 per lane. out = relu(acc*nin + b) * nout
__global__ __launch_bounds__(256) void agg128_kernel(const float* __restrict__ H,
        const int* __restrict__ esrc, const int* __restrict__ rowend,
        const float* __restrict__ nin, const float* __restrict__ bias,
        const float* __restrict__ nout, float* __restrict__ out, int N) {
    int wid  = (blockIdx.x * 256 + threadIdx.x) >> 6;
    int lane = threadIdx.x & 63;
    if (wid >= N) return;
    int beg = (wid == 0) ? 0 : rowend[wid - 1];
    int end = rowend[wid];
    const float2* Hp = (const float2*)H;
    float2 a0 = make_float2(0.f, 0.f), a1 = make_float2(0.f, 0.f);
    int j = beg;
    for (; j + 2 <= end; j += 2) {
        int s0 = esrc[j], s1 = esrc[j + 1];
        float2 v0 = Hp[(size_t)s0 * 64 + lane];
        float2 v1 = Hp[(size_t)s1 * 64 + lane];
        a0.x += v0.x; a0.y += v0.y;
        a1.x += v1.x; a1.y += v1.y;
    }
    if (j < end) {
        int s0 = esrc[j];
        float2 v0 = Hp[(size_t)s0 * 64 + lane];
        a0.x += v0.x; a0.y += v0.y;
    }
    a0.x += a1.x; a0.y += a1.y;
    float s = nin[wid];
    float2 b = ((const float2*)bias)[lane];
    float r0 = fmaxf(fmaf(a0.x, s, b.x), 0.f);
    float r1 = fmaxf(fmaf(a0.y, s, b.y), 0.f);
    float t = nout[wid];
    r0 *= t; r1 *= t;
    ((float2*)out)[(size_t)wid * 64 + lane] = make_float2(r0, r1);
}

// F=64: one wave per node, one float per lane. out = relu(acc*nin + b)
__global__ __launch_bounds__(256) void agg64_kernel(const float* __restrict__ H,
        const int* __restrict__ esrc, const int* __restrict__ rowend,
        const float* __restrict__ nin, const float* __restrict__ bias,
        float* __restrict__ out, int N) {
    int wid  = (blockIdx.x * 256 + threadIdx.x) >> 6;
    int lane = threadIdx.x & 63;
    if (wid >= N) return;
    int beg = (wid == 0) ? 0 : rowend[wid - 1];
    int end = rowend[wid];
    float a0 = 0.f, a1 = 0.f, a2 = 0.f, a3 = 0.f;
    int j = beg;
    for (; j + 4 <= end; j += 4) {
        a0 += H[(size_t)esrc[j]     * 64 + lane];
        a1 += H[(size_t)esrc[j + 1] * 64 + lane];
        a2 += H[(size_t)esrc[j + 2] * 64 + lane];
        a3 += H[(size_t)esrc[j + 3] * 64 + lane];
    }
    for (; j < end; ++j) a0 += H[(size_t)esrc[j] * 64 + lane];
    float acc = (a0 + a1) + (a2 + a3);
    float r = fmaxf(fmaf(acc, nin[wid], bias[lane]), 0.f);
    out[(size_t)wid * 64 + lane] = r;
}

// ---------------- fallback atomic scatter path (ws too small) ----------------

template<int F>
__global__ __launch_bounds__(256) void scatter_kernel(const float* __restrict__ H,
        const int* __restrict__ src, const int* __restrict__ dst,
        float* __restrict__ agg, int E) {
    constexpr int LPE = F / 4;
    int gid = blockIdx.x * blockDim.x + threadIdx.x;
    int e = gid / LPE;
    int l = gid % LPE;
    if (e >= E) return;
    int s = src[e], d = dst[e];
    float4 v = reinterpret_cast<const float4*>(H)[(size_t)s * LPE + l];
    float* p = agg + (size_t)d * F + l * 4;
    atomicAdd(p + 0, v.x);
    atomicAdd(p + 1, v.y);
    atomicAdd(p + 2, v.z);
    atomicAdd(p + 3, v.w);
}

template<int F>
__global__ __launch_bounds__(256) void post_kernel(const float* __restrict__ agg,
        const float* __restrict__ nin, const float* __restrict__ bias,
        const float* __restrict__ nout_or_null,
        float* __restrict__ out, int N) {
    constexpr int CQ = F / 4;
    int i = blockIdx.x * blockDim.x + threadIdx.x;
    if (i >= N * CQ) return;
    int row = i / CQ;
    int cq  = i % CQ;
    float4 v = reinterpret_cast<const float4*>(agg)[i];
    float s = nin[row];
    float4 b = reinterpret_cast<const float4*>(bias)[cq];
    float4 r;
    r.x = fmaxf(fmaf(v.x, s, b.x), 0.f);
    r.y = fmaxf(fmaf(v.y, s, b.y), 0.f);
    r.z = fmaxf(fmaf(v.z, s, b.z), 0.f);
    r.w = fmaxf(fmaf(v.w, s, b.w), 0.f);
    if (nout_or_null) {
        float t = nout_or_null[row];
        r.x *= t; r.y *= t; r.z *= t; r.w *= t;
    }
    reinterpret_cast<float4*>(out)[i] = r;
}

// ---------------- launch ----------------

extern "C" void kernel_launch(void* const* d_in, const int* in_sizes, int n_in,
                              void* d_out, int out_size, void* d_ws, size_t ws_size,
                              hipStream_t stream) {
    const float* x  = (const float*)d_in[0];
    const float* W1 = (const float*)d_in[1];
    const float* b1 = (const float*)d_in[2];
    const float* W2 = (const float*)d_in[3];
    const float* b2 = (const float*)d_in[4];
    const int*   src = (const int*)d_in[5];
    const int*   dst = (const int*)d_in[6];

    const int N = in_sizes[0] / INF;   // 100000
    const int E = in_sizes[5];         // 1600000

    char* ws = (char*)d_ws;
    const size_t padN = (((size_t)N * 4 + 255) / 256) * 256;
    const size_t padE = (((size_t)E * 4 + 255) / 256) * 256;
    const size_t matB = (size_t)N * INF * sizeof(float);

    float* out = (float*)d_out;

    const size_t need_csr = 3 * padN + padE + 2 * matB;
    if (ws_size >= need_csr) {
        float* nout   = (float*)(ws);
        float* nin    = (float*)(ws + padN);
        int*   cursor = (int*)  (ws + 2 * padN);
        int*   esrc   = (int*)  (ws + 3 * padN);
        float* A      = (float*)(ws + 3 * padN + padE);
        float* B      = (float*)(ws + 3 * padN + padE + matB);

        hipMemsetAsync(nout, 0, (size_t)N * sizeof(float), stream);
        hipMemsetAsync(nin,  0, (size_t)N * sizeof(float), stream);
        degree_kernel<<<1024, 256, 0, stream>>>(src, dst, nout, nin, E);
        scan_kernel<<<1, SCAN_T, 0, stream>>>(nin, cursor, N);      // reads raw float degrees
        norm_kernel<<<(N + 255) / 256, 256, 0, stream>>>(nout, nin, N);
        fill_kernel<<<1024, 256, 0, stream>>>(src, dst, cursor, esrc, E);

        // layer 1: A = (x*nout) @ W1 ; B = relu(csr_sum(A)*nin + b1) * nout
        gemm_kernel<128, 16><<<(N + 15) / 16, 256, 0, stream>>>(x, nout, W1, A, N);
        agg128_kernel<<<(N * 64 + 255) / 256, 256, 0, stream>>>(A, esrc, cursor, nin, b1, nout, B, N);

        // layer 2: A = B @ W2 ; out = relu(csr_sum(A)*nin + b2)
        gemm_kernel<64, 32><<<(N + 31) / 32, 256, 0, stream>>>(B, nullptr, W2, A, N);
        agg64_kernel<<<(N * 64 + 255) / 256, 256, 0, stream>>>(A, esrc, cursor, nin, b2, out, N);
    } else {
        // fallback: atomic scatter path (round-1 behavior)
        float* nout = (float*)(ws);
        float* nin  = (float*)(ws + padN);
        float* A    = (float*)(ws + 2 * padN);
        float* B    = (float*)(ws + 2 * padN + matB);

        hipMemsetAsync(nout, 0, (size_t)N * sizeof(float), stream);
        hipMemsetAsync(nin,  0, (size_t)N * sizeof(float), stream);
        degree_kernel<<<1024, 256, 0, stream>>>(src, dst, nout, nin, E);
        norm_kernel<<<(N + 255) / 256, 256, 0, stream>>>(nout, nin, N);

        gemm_kernel<128, 16><<<(N + 15) / 16, 256, 0, stream>>>(x, nout, W1, A, N);
        hipMemsetAsync(B, 0, matB, stream);
        scatter_kernel<128><<<(int)(((size_t)E * 32 + 255) / 256), 256, 0, stream>>>(A, src, dst, B, E);
        post_kernel<128><<<(N * 32 + 255) / 256, 256, 0, stream>>>(B, nin, b1, nout, A, N);

        gemm_kernel<64, 32><<<(N + 31) / 32, 256, 0, stream>>>(A, nullptr, W2, B, N);
        hipMemsetAsync(out, 0, (size_t)N * HF * sizeof(float), stream);
        scatter_kernel<64><<<(int)(((size_t)E * 16 + 255) / 256), 256, 0, stream>>>(B, src, dst, out, E);
        post_kernel<64><<<(N * 16 + 255) / 256, 256, 0, stream>>>(out, nin, b2, nullptr, out, N);
    }
}

// Round 5
// 740.876 us; speedup vs baseline: 7.4554x; 2.6139x over previous
//
#include <hip/hip_runtime.h>

#define INF 128
#define HF 64
#define SCAN_T 1024

// ---------------- degree / norm ----------------

__global__ void degree_kernel(const int* __restrict__ src, const int* __restrict__ dst,
                              float* __restrict__ dout, float* __restrict__ din, int E) {
    int i = blockIdx.x * blockDim.x + threadIdx.x;
    int stride = gridDim.x * blockDim.x;
    for (; i < E; i += stride) {
        atomicAdd(&dout[src[i]], 1.0f);
        atomicAdd(&din[dst[i]], 1.0f);
    }
}

__global__ void norm_kernel(float* __restrict__ a, float* __restrict__ b, int N) {
    int i = blockIdx.x * blockDim.x + threadIdx.x;
    if (i < N) {
        float v = a[i]; a[i] = v > 0.f ? rsqrtf(v) : 0.f;
        float w = b[i]; b[i] = w > 0.f ? rsqrtf(w) : 0.f;
    }
}

// ---------------- CSR build ----------------

__global__ __launch_bounds__(SCAN_T) void scan_kernel(const float* __restrict__ deg,
                                                      int* __restrict__ cursor, int N) {
    __shared__ int part[SCAN_T];
    const int t = threadIdx.x;
    const int chunk = (N + SCAN_T - 1) / SCAN_T;
    const int beg = t * chunk;
    const int end = min(beg + chunk, N);
    int s = 0;
    for (int i = beg; i < end; ++i) s += (int)deg[i];
    part[t] = s;
    __syncthreads();
    for (int off = 1; off < SCAN_T; off <<= 1) {
        int v = (t >= off) ? part[t - off] : 0;
        __syncthreads();
        part[t] += v;
        __syncthreads();
    }
    int run = (t == 0) ? 0 : part[t - 1];
    for (int i = beg; i < end; ++i) {
        cursor[i] = run;
        run += (int)deg[i];
    }
}

__global__ void fill_kernel(const int* __restrict__ src, const int* __restrict__ dst,
                            int* __restrict__ cursor, int* __restrict__ esrc, int E) {
    int i = blockIdx.x * blockDim.x + threadIdx.x;
    int stride = gridDim.x * blockDim.x;
    for (; i < E; i += stride) {
        int pos = atomicAdd(&cursor[dst[i]], 1);
        esrc[pos] = src[i];
    }
}

// ---------------- GEMM: H[N,OUT] = (X * rowscale) @ W[128,OUT] ----------------
// 256 threads; thread = 4 rows x 1 float4-col; W staged in K-tiles of 32.

__device__ inline void fma4(float4& a, float s, const float4& w) {
    a.x = fmaf(s, w.x, a.x);
    a.y = fmaf(s, w.y, a.y);
    a.z = fmaf(s, w.z, a.z);
    a.w = fmaf(s, w.w, a.w);
}

template<int OUT, int RPB>
__global__ __launch_bounds__(256) void gemm_kernel(const float* __restrict__ X,
        const float* __restrict__ rowscale,   // may be null
        const float* __restrict__ W,
        float* __restrict__ H, int N) {
    constexpr int CQ = OUT / 4;          // float4 columns (32 or 16)
    constexpr int BK = 32;               // K-tile for W staging
    static_assert(RPB == 4 * (256 / CQ), "rows per block mismatch");

    __shared__ float sW[BK * OUT];       // 16KB (OUT=128) / 8KB (OUT=64)
    __shared__ float sX[RPB][INF + 4];   // +4 pad

    const int tid = threadIdx.x;
    const int row0 = blockIdx.x * RPB;

    // stage RPB rows of X (full K), optionally row-scaled
    for (int i = tid; i < RPB * (INF / 4); i += 256) {
        int r  = i >> 5;        // INF/4 == 32
        int kc = i & 31;
        int gr = row0 + r;
        float4 v = make_float4(0.f, 0.f, 0.f, 0.f);
        if (gr < N) {
            v = reinterpret_cast<const float4*>(X)[(size_t)gr * 32 + kc];
            if (rowscale) {
                float s = rowscale[gr];
                v.x *= s; v.y *= s; v.z *= s; v.w *= s;
            }
        }
        *reinterpret_cast<float4*>(&sX[r][kc * 4]) = v;
    }

    const int cq = tid % CQ;
    const int rp = tid / CQ;
    const int r0 = rp * 4;

    float4 acc0 = make_float4(0.f, 0.f, 0.f, 0.f);
    float4 acc1 = make_float4(0.f, 0.f, 0.f, 0.f);
    float4 acc2 = make_float4(0.f, 0.f, 0.f, 0.f);
    float4 acc3 = make_float4(0.f, 0.f, 0.f, 0.f);

    for (int kt = 0; kt < INF / BK; ++kt) {
        __syncthreads();   // prev-tile reads done (and, at kt=0, orders vs sX/sW stage)
        for (int i = tid; i < BK * CQ; i += 256)
            reinterpret_cast<float4*>(sW)[i] =
                reinterpret_cast<const float4*>(W)[kt * BK * CQ + i];
        __syncthreads();

        #pragma unroll 2
        for (int k4 = 0; k4 < BK / 4; ++k4) {
            const int kk = kt * BK + k4 * 4;
            float4 xa = *reinterpret_cast<const float4*>(&sX[r0 + 0][kk]);
            float4 xb = *reinterpret_cast<const float4*>(&sX[r0 + 1][kk]);
            float4 xc = *reinterpret_cast<const float4*>(&sX[r0 + 2][kk]);
            float4 xd = *reinterpret_cast<const float4*>(&sX[r0 + 3][kk]);
            const float4* wr = reinterpret_cast<const float4*>(sW + (k4 * 4) * OUT) + cq;
            float4 w0 = wr[0];
            float4 w1 = wr[CQ];
            float4 w2 = wr[2 * CQ];
            float4 w3 = wr[3 * CQ];
            fma4(acc0, xa.x, w0); fma4(acc0, xa.y, w1); fma4(acc0, xa.z, w2); fma4(acc0, xa.w, w3);
            fma4(acc1, xb.x, w0); fma4(acc1, xb.y, w1); fma4(acc1, xb.z, w2); fma4(acc1, xb.w, w3);
            fma4(acc2, xc.x, w0); fma4(acc2, xc.y, w1); fma4(acc2, xc.z, w2); fma4(acc2, xc.w, w3);
            fma4(acc3, xd.x, w0); fma4(acc3, xd.y, w1); fma4(acc3, xd.z, w2); fma4(acc3, xd.w, w3);
        }
    }

    if (row0 + r0 + 0 < N) reinterpret_cast<float4*>(H)[(size_t)(row0 + r0 + 0) * CQ + cq] = acc0;
    if (row0 + r0 + 1 < N) reinterpret_cast<float4*>(H)[(size_t)(row0 + r0 + 1) * CQ + cq] = acc1;
    if (row0 + r0 + 2 < N) reinterpret_cast<float4*>(H)[(size_t)(row0 + r0 + 2) * CQ + cq] = acc2;
    if (row0 + r0 + 3 < N) reinterpret_cast<float4*>(H)[(size_t)(row0 + r0 + 3) * CQ + cq] = acc3;
}

// ---------------- CSR gather-aggregate + fused post ----------------

__global__ __launch_bounds__(256) void agg128_kernel(const float* __restrict__ H,
        const int* __restrict__ esrc, const int* __restrict__ rowend,
        const float* __restrict__ nin, const float* __restrict__ bias,
        const float* __restrict__ nout, float* __restrict__ out, int N) {
    int wid  = (blockIdx.x * 256 + threadIdx.x) >> 6;
    int lane = threadIdx.x & 63;
    if (wid >= N) return;
    int beg = (wid == 0) ? 0 : rowend[wid - 1];
    int end = rowend[wid];
    const float2* Hp = (const float2*)H;
    float2 a0 = make_float2(0.f, 0.f), a1 = make_float2(0.f, 0.f);
    int j = beg;
    for (; j + 2 <= end; j += 2) {
        int s0 = esrc[j], s1 = esrc[j + 1];
        float2 v0 = Hp[(size_t)s0 * 64 + lane];
        float2 v1 = Hp[(size_t)s1 * 64 + lane];
        a0.x += v0.x; a0.y += v0.y;
        a1.x += v1.x; a1.y += v1.y;
    }
    if (j < end) {
        int s0 = esrc[j];
        float2 v0 = Hp[(size_t)s0 * 64 + lane];
        a0.x += v0.x; a0.y += v0.y;
    }
    a0.x += a1.x; a0.y += a1.y;
    float s = nin[wid];
    float2 b = ((const float2*)bias)[lane];
    float r0 = fmaxf(fmaf(a0.x, s, b.x), 0.f);
    float r1 = fmaxf(fmaf(a0.y, s, b.y), 0.f);
    float t = nout[wid];
    r0 *= t; r1 *= t;
    ((float2*)out)[(size_t)wid * 64 + lane] = make_float2(r0, r1);
}

__global__ __launch_bounds__(256) void agg64_kernel(const float* __restrict__ H,
        const int* __restrict__ esrc, const int* __restrict__ rowend,
        const float* __restrict__ nin, const float* __restrict__ bias,
        float* __restrict__ out, int N) {
    int wid  = (blockIdx.x * 256 + threadIdx.x) >> 6;
    int lane = threadIdx.x & 63;
    if (wid >= N) return;
    int beg = (wid == 0) ? 0 : rowend[wid - 1];
    int end = rowend[wid];
    float a0 = 0.f, a1 = 0.f, a2 = 0.f, a3 = 0.f;
    int j = beg;
    for (; j + 4 <= end; j += 4) {
        a0 += H[(size_t)esrc[j]     * 64 + lane];
        a1 += H[(size_t)esrc[j + 1] * 64 + lane];
        a2 += H[(size_t)esrc[j + 2] * 64 + lane];
        a3 += H[(size_t)esrc[j + 3] * 64 + lane];
    }
    for (; j < end; ++j) a0 += H[(size_t)esrc[j] * 64 + lane];
    float acc = (a0 + a1) + (a2 + a3);
    float r = fmaxf(fmaf(acc, nin[wid], bias[lane]), 0.f);
    out[(size_t)wid * 64 + lane] = r;
}

// ---------------- launch ----------------

extern "C" void kernel_launch(void* const* d_in, const int* in_sizes, int n_in,
                              void* d_out, int out_size, void* d_ws, size_t ws_size,
                              hipStream_t stream) {
    const float* x  = (const float*)d_in[0];
    const float* W1 = (const float*)d_in[1];
    const float* b1 = (const float*)d_in[2];
    const float* W2 = (const float*)d_in[3];
    const float* b2 = (const float*)d_in[4];
    const int*   src = (const int*)d_in[5];
    const int*   dst = (const int*)d_in[6];

    const int N = in_sizes[0] / INF;   // 100000
    const int E = in_sizes[5];         // 1600000

    char* ws = (char*)d_ws;
    const size_t padN = (((size_t)N * 4 + 255) / 256) * 256;
    const size_t padE = (((size_t)E * 4 + 255) / 256) * 256;
    const size_t matB = (size_t)N * INF * sizeof(float);

    float* out = (float*)d_out;

    float* nout   = (float*)(ws);
    float* nin    = (float*)(ws + padN);
    int*   cursor = (int*)  (ws + 2 * padN);
    int*   esrc   = (int*)  (ws + 3 * padN);
    float* A      = (float*)(ws + 3 * padN + padE);
    float* B      = (float*)(ws + 3 * padN + padE + matB);

    hipMemsetAsync(nout, 0, (size_t)N * sizeof(float), stream);
    hipMemsetAsync(nin,  0, (size_t)N * sizeof(float), stream);
    degree_kernel<<<1024, 256, 0, stream>>>(src, dst, nout, nin, E);
    scan_kernel<<<1, SCAN_T, 0, stream>>>(nin, cursor, N);      // reads raw float degrees
    norm_kernel<<<(N + 255) / 256, 256, 0, stream>>>(nout, nin, N);
    fill_kernel<<<1024, 256, 0, stream>>>(src, dst, cursor, esrc, E);

    // layer 1: A = (x*nout) @ W1 ; B = relu(csr_sum(A)*nin + b1) * nout
    gemm_kernel<128, 32><<<(N + 31) / 32, 256, 0, stream>>>(x, nout, W1, A, N);
    agg128_kernel<<<(N * 64 + 255) / 256, 256, 0, stream>>>(A, esrc, cursor, nin, b1, nout, B, N);

    // layer 2: A = B @ W2 ; out = relu(csr_sum(A)*nin + b2)
    gemm_kernel<64, 64><<<(N + 63) / 64, 256, 0, stream>>>(B, nullptr, W2, A, N);
    agg64_kernel<<<(N * 64 + 255) / 256, 256, 0, stream>>>(A, esrc, cursor, nin, b2, out, N);
}

// Round 7
// 594.282 us; speedup vs baseline: 9.2945x; 1.2467x over previous
//
#include <hip/hip_runtime.h>

#define INF 128
#define HF 64

// ---------------- degree / norm ----------------

__global__ void degree_kernel(const int* __restrict__ src, const int* __restrict__ dst,
                              float* __restrict__ dout, float* __restrict__ din, int E) {
    int i = blockIdx.x * blockDim.x + threadIdx.x;
    int stride = gridDim.x * blockDim.x;
    for (; i < E; i += stride) {
        atomicAdd(&dout[src[i]], 1.0f);
        atomicAdd(&din[dst[i]], 1.0f);
    }
}

__global__ void norm_kernel(float* __restrict__ a, float* __restrict__ b, int N) {
    int i = blockIdx.x * blockDim.x + threadIdx.x;
    if (i < N) {
        float v = a[i]; a[i] = v > 0.f ? rsqrtf(v) : 0.f;
        float w = b[i]; b[i] = w > 0.f ? rsqrtf(w) : 0.f;
    }
}

// ---------------- CSR build: parallel 3-phase exclusive scan ----------------
// phase 1: per-block (1024 elems) local exclusive prefix -> cursor, block total -> bsum
__global__ __launch_bounds__(256) void scan_blocks_kernel(const float* __restrict__ deg,
        int* __restrict__ cursor, int* __restrict__ bsum, int N) {
    __shared__ int sh[256];
    const int b = blockIdx.x, t = threadIdx.x;
    const int base = b * 1024 + t * 4;
    int v0 = (base + 0 < N) ? (int)deg[base + 0] : 0;
    int v1 = (base + 1 < N) ? (int)deg[base + 1] : 0;
    int v2 = (base + 2 < N) ? (int)deg[base + 2] : 0;
    int v3 = (base + 3 < N) ? (int)deg[base + 3] : 0;
    sh[t] = v0 + v1 + v2 + v3;
    __syncthreads();
    for (int off = 1; off < 256; off <<= 1) {
        int x = (t >= off) ? sh[t - off] : 0;
        __syncthreads();
        sh[t] += x;
        __syncthreads();
    }
    if (t == 255) bsum[b] = sh[255];
    int run = (t == 0) ? 0 : sh[t - 1];
    if (base + 0 < N) { cursor[base + 0] = run; run += v0; }
    if (base + 1 < N) { cursor[base + 1] = run; run += v1; }
    if (base + 2 < N) { cursor[base + 2] = run; run += v2; }
    if (base + 3 < N) { cursor[base + 3] = run; }
}

// phase 2: single block scans block totals in place (exclusive)
__global__ __launch_bounds__(1024) void scan_bsums_kernel(int* __restrict__ bsum, int NB) {
    __shared__ int sh[1024];
    const int t = threadIdx.x;
    int v = (t < NB) ? bsum[t] : 0;
    sh[t] = v;
    __syncthreads();
    for (int off = 1; off < 1024; off <<= 1) {
        int x = (t >= off) ? sh[t - off] : 0;
        __syncthreads();
        sh[t] += x;
        __syncthreads();
    }
    if (t < NB) bsum[t] = sh[t] - v;   // exclusive
}

// phase 3: add block offsets
__global__ __launch_bounds__(256) void scan_add_kernel(int* __restrict__ cursor,
        const int* __restrict__ bsum, int N) {
    const int b = blockIdx.x;
    if (b == 0) return;
    const int t = threadIdx.x;
    const int off = bsum[b];
    const int base = b * 1024 + t * 4;
    if (base + 0 < N) cursor[base + 0] += off;
    if (base + 1 < N) cursor[base + 1] += off;
    if (base + 2 < N) cursor[base + 2] += off;
    if (base + 3 < N) cursor[base + 3] += off;
}

// scatter edges into dst-sorted order; cursor becomes inclusive row-end
__global__ void fill_kernel(const int* __restrict__ src, const int* __restrict__ dst,
                            int* __restrict__ cursor, int* __restrict__ esrc, int E) {
    int i = blockIdx.x * blockDim.x + threadIdx.x;
    int stride = gridDim.x * blockDim.x;
    for (; i < E; i += stride) {
        int pos = atomicAdd(&cursor[dst[i]], 1);
        esrc[pos] = src[i];
    }
}

// ---------------- GEMM: H[N,OUT] = (X * rowscale) @ W[128,OUT] ----------------

__device__ inline void fma4(float4& a, float s, const float4& w) {
    a.x = fmaf(s, w.x, a.x);
    a.y = fmaf(s, w.y, a.y);
    a.z = fmaf(s, w.z, a.z);
    a.w = fmaf(s, w.w, a.w);
}

template<int OUT, int RPB>
__global__ __launch_bounds__(256) void gemm_kernel(const float* __restrict__ X,
        const float* __restrict__ rowscale,   // may be null
        const float* __restrict__ W,
        float* __restrict__ H, int N) {
    constexpr int CQ = OUT / 4;          // float4 columns (32 or 16)
    constexpr int BK = 32;               // K-tile for W staging
    static_assert(RPB == 4 * (256 / CQ), "rows per block mismatch");

    __shared__ float sW[BK * OUT];
    __shared__ float sX[RPB][INF + 4];

    const int tid = threadIdx.x;
    const int row0 = blockIdx.x * RPB;

    for (int i = tid; i < RPB * (INF / 4); i += 256) {
        int r  = i >> 5;
        int kc = i & 31;
        int gr = row0 + r;
        float4 v = make_float4(0.f, 0.f, 0.f, 0.f);
        if (gr < N) {
            v = reinterpret_cast<const float4*>(X)[(size_t)gr * 32 + kc];
            if (rowscale) {
                float s = rowscale[gr];
                v.x *= s; v.y *= s; v.z *= s; v.w *= s;
            }
        }
        *reinterpret_cast<float4*>(&sX[r][kc * 4]) = v;
    }

    const int cq = tid % CQ;
    const int rp = tid / CQ;
    const int r0 = rp * 4;

    float4 acc0 = make_float4(0.f, 0.f, 0.f, 0.f);
    float4 acc1 = make_float4(0.f, 0.f, 0.f, 0.f);
    float4 acc2 = make_float4(0.f, 0.f, 0.f, 0.f);
    float4 acc3 = make_float4(0.f, 0.f, 0.f, 0.f);

    for (int kt = 0; kt < INF / BK; ++kt) {
        __syncthreads();
        for (int i = tid; i < BK * CQ; i += 256)
            reinterpret_cast<float4*>(sW)[i] =
                reinterpret_cast<const float4*>(W)[kt * BK * CQ + i];
        __syncthreads();

        #pragma unroll 2
        for (int k4 = 0; k4 < BK / 4; ++k4) {
            const int kk = kt * BK + k4 * 4;
            float4 xa = *reinterpret_cast<const float4*>(&sX[r0 + 0][kk]);
            float4 xb = *reinterpret_cast<const float4*>(&sX[r0 + 1][kk]);
            float4 xc = *reinterpret_cast<const float4*>(&sX[r0 + 2][kk]);
            float4 xd = *reinterpret_cast<const float4*>(&sX[r0 + 3][kk]);
            const float4* wr = reinterpret_cast<const float4*>(sW + (k4 * 4) * OUT) + cq;
            float4 w0 = wr[0];
            float4 w1 = wr[CQ];
            float4 w2 = wr[2 * CQ];
            float4 w3 = wr[3 * CQ];
            fma4(acc0, xa.x, w0); fma4(acc0, xa.y, w1); fma4(acc0, xa.z, w2); fma4(acc0, xa.w, w3);
            fma4(acc1, xb.x, w0); fma4(acc1, xb.y, w1); fma4(acc1, xb.z, w2); fma4(acc1, xb.w, w3);
            fma4(acc2, xc.x, w0); fma4(acc2, xc.y, w1); fma4(acc2, xc.z, w2); fma4(acc2, xc.w, w3);
            fma4(acc3, xd.x, w0); fma4(acc3, xd.y, w1); fma4(acc3, xd.z, w2); fma4(acc3, xd.w, w3);
        }
    }

    if (row0 + r0 + 0 < N) reinterpret_cast<float4*>(H)[(size_t)(row0 + r0 + 0) * CQ + cq] = acc0;
    if (row0 + r0 + 1 < N) reinterpret_cast<float4*>(H)[(size_t)(row0 + r0 + 1) * CQ + cq] = acc1;
    if (row0 + r0 + 2 < N) reinterpret_cast<float4*>(H)[(size_t)(row0 + r0 + 2) * CQ + cq] = acc2;
    if (row0 + r0 + 3 < N) reinterpret_cast<float4*>(H)[(size_t)(row0 + r0 + 3) * CQ + cq] = acc3;
}

// ---------------- CSR gather-aggregate + fused post ----------------

__global__ __launch_bounds__(256) void agg128_kernel(const float* __restrict__ H,
        const int* __restrict__ esrc, const int* __restrict__ rowend,
        const float* __restrict__ nin, const float* __restrict__ bias,
        const float* __restrict__ nout, float* __restrict__ out, int N) {
    int wid  = (blockIdx.x * 256 + threadIdx.x) >> 6;
    int lane = threadIdx.x & 63;
    if (wid >= N) return;
    int beg = (wid == 0) ? 0 : rowend[wid - 1];
    int end = rowend[wid];
    const float2* Hp = (const float2*)H;
    float2 a0 = make_float2(0.f, 0.f), a1 = make_float2(0.f, 0.f);
    int j = beg;
    for (; j + 2 <= end; j += 2) {
        int s0 = esrc[j], s1 = esrc[j + 1];
        float2 v0 = Hp[(size_t)s0 * 64 + lane];
        float2 v1 = Hp[(size_t)s1 * 64 + lane];
        a0.x += v0.x; a0.y += v0.y;
        a1.x += v1.x; a1.y += v1.y;
    }
    if (j < end) {
        int s0 = esrc[j];
        float2 v0 = Hp[(size_t)s0 * 64 + lane];
        a0.x += v0.x; a0.y += v0.y;
    }
    a0.x += a1.x; a0.y += a1.y;
    float s = nin[wid];
    float2 b = ((const float2*)bias)[lane];
    float r0 = fmaxf(fmaf(a0.x, s, b.x), 0.f);
    float r1 = fmaxf(fmaf(a0.y, s, b.y), 0.f);
    float t = nout[wid];
    r0 *= t; r1 *= t;
    ((float2*)out)[(size_t)wid * 64 + lane] = make_float2(r0, r1);
}

__global__ __launch_bounds__(256) void agg64_kernel(const float* __restrict__ H,
        const int* __restrict__ esrc, const int* __restrict__ rowend,
        const float* __restrict__ nin, const float* __restrict__ bias,
        float* __restrict__ out, int N) {
    int wid  = (blockIdx.x * 256 + threadIdx.x) >> 6;
    int lane = threadIdx.x & 63;
    if (wid >= N) return;
    int beg = (wid == 0) ? 0 : rowend[wid - 1];
    int end = rowend[wid];
    float a0 = 0.f, a1 = 0.f, a2 = 0.f, a3 = 0.f;
    int j = beg;
    for (; j + 4 <= end; j += 4) {
        a0 += H[(size_t)esrc[j]     * 64 + lane];
        a1 += H[(size_t)esrc[j + 1] * 64 + lane];
        a2 += H[(size_t)esrc[j + 2] * 64 + lane];
        a3 += H[(size_t)esrc[j + 3] * 64 + lane];
    }
    for (; j < end; ++j) a0 += H[(size_t)esrc[j] * 64 + lane];
    float acc = (a0 + a1) + (a2 + a3);
    float r = fmaxf(fmaf(acc, nin[wid], bias[lane]), 0.f);
    out[(size_t)wid * 64 + lane] = r;
}

// ---------------- launch ----------------

extern "C" void kernel_launch(void* const* d_in, const int* in_sizes, int n_in,
                              void* d_out, int out_size, void* d_ws, size_t ws_size,
                              hipStream_t stream) {
    const float* x  = (const float*)d_in[0];
    const float* W1 = (const float*)d_in[1];
    const float* b1 = (const float*)d_in[2];
    const float* W2 = (const float*)d_in[3];
    const float* b2 = (const float*)d_in[4];
    const int*   src = (const int*)d_in[5];
    const int*   dst = (const int*)d_in[6];

    const int N = in_sizes[0] / INF;   // 100000
    const int E = in_sizes[5];         // 1600000

    char* ws = (char*)d_ws;
    const size_t padN = (((size_t)N * 4 + 255) / 256) * 256;
    const size_t padE = (((size_t)E * 4 + 255) / 256) * 256;
    const size_t matB = (size_t)N * INF * sizeof(float);

    float* out = (float*)d_out;

    float* nout   = (float*)(ws);
    float* nin    = (float*)(ws + padN);
    int*   cursor = (int*)  (ws + 2 * padN);
    int*   esrc   = (int*)  (ws + 3 * padN);
    float* A      = (float*)(ws + 3 * padN + padE);
    float* B      = (float*)(ws + 3 * padN + padE + matB);
    int*   bsum   = (int*)A;   // A is unused until gemm1; stream order makes this safe

    const int NB = (N + 1023) / 1024;

    hipMemsetAsync(nout, 0, (size_t)N * sizeof(float), stream);
    hipMemsetAsync(nin,  0, (size_t)N * sizeof(float), stream);
    degree_kernel<<<1024, 256, 0, stream>>>(src, dst, nout, nin, E);

    // exclusive scan of (int)nin -> cursor (parallel, 3 phases)
    scan_blocks_kernel<<<NB, 256, 0, stream>>>(nin, cursor, bsum, N);
    scan_bsums_kernel<<<1, 1024, 0, stream>>>(bsum, NB);
    scan_add_kernel<<<NB, 256, 0, stream>>>(cursor, bsum, N);

    norm_kernel<<<(N + 255) / 256, 256, 0, stream>>>(nout, nin, N);
    fill_kernel<<<1024, 256, 0, stream>>>(src, dst, cursor, esrc, E);

    // layer 1: A = (x*nout) @ W1 ; B = relu(csr_sum(A)*nin + b1) * nout
    gemm_kernel<128, 32><<<(N + 31) / 32, 256, 0, stream>>>(x, nout, W1, A, N);
    agg128_kernel<<<(N * 64 + 255) / 256, 256, 0, stream>>>(A, esrc, cursor, nin, b1, nout, B, N);

    // layer 2: A = B @ W2 ; out = relu(csr_sum(A)*nin + b2)
    gemm_kernel<64, 64><<<(N + 63) / 64, 256, 0, stream>>>(B, nullptr, W2, A, N);
    agg64_kernel<<<(N * 64 + 255) / 256, 256, 0, stream>>>(A, esrc, cursor, nin, b2, out, N);
}

// Round 8
// 460.600 us; speedup vs baseline: 11.9921x; 1.2902x over previous
//
#include <hip/hip_runtime.h>

#define INF 128
#define HF 64

// ---------------- count: per-edge ordinals + degree histograms ----------------
// one thread per edge; eord[i] = slot of edge i within its dst row
__global__ __launch_bounds__(256) void count_kernel(const int* __restrict__ src,
        const int* __restrict__ dst, int* __restrict__ cnt_src,
        int* __restrict__ cnt_dst, int* __restrict__ eord, int E) {
    int i = blockIdx.x * 256 + threadIdx.x;
    if (i >= E) return;
    int s = src[i], d = dst[i];
    eord[i] = atomicAdd(&cnt_dst[d], 1);
    atomicAdd(&cnt_src[s], 1);
}

// norms from int degree counts
__global__ void norm_kernel(const int* __restrict__ cs, const int* __restrict__ cd,
                            float* __restrict__ nout, float* __restrict__ nin, int N) {
    int i = blockIdx.x * blockDim.x + threadIdx.x;
    if (i < N) {
        int a = cs[i]; nout[i] = a > 0 ? rsqrtf((float)a) : 0.f;
        int b = cd[i]; nin[i]  = b > 0 ? rsqrtf((float)b) : 0.f;
    }
}

// ---------------- parallel 3-phase exclusive scan (int input) ----------------
__global__ __launch_bounds__(256) void scan_blocks_kernel(const int* __restrict__ deg,
        int* __restrict__ rowstart, int* __restrict__ bsum, int N) {
    __shared__ int sh[256];
    const int b = blockIdx.x, t = threadIdx.x;
    const int base = b * 1024 + t * 4;
    int v0 = (base + 0 < N) ? deg[base + 0] : 0;
    int v1 = (base + 1 < N) ? deg[base + 1] : 0;
    int v2 = (base + 2 < N) ? deg[base + 2] : 0;
    int v3 = (base + 3 < N) ? deg[base + 3] : 0;
    sh[t] = v0 + v1 + v2 + v3;
    __syncthreads();
    for (int off = 1; off < 256; off <<= 1) {
        int x = (t >= off) ? sh[t - off] : 0;
        __syncthreads();
        sh[t] += x;
        __syncthreads();
    }
    if (t == 255) bsum[b] = sh[255];
    int run = (t == 0) ? 0 : sh[t - 1];
    if (base + 0 < N) { rowstart[base + 0] = run; run += v0; }
    if (base + 1 < N) { rowstart[base + 1] = run; run += v1; }
    if (base + 2 < N) { rowstart[base + 2] = run; run += v2; }
    if (base + 3 < N) { rowstart[base + 3] = run; }
}

__global__ __launch_bounds__(1024) void scan_bsums_kernel(int* __restrict__ bsum, int NB) {
    __shared__ int sh[1024];
    const int t = threadIdx.x;
    int v = (t < NB) ? bsum[t] : 0;
    sh[t] = v;
    __syncthreads();
    for (int off = 1; off < 1024; off <<= 1) {
        int x = (t >= off) ? sh[t - off] : 0;
        __syncthreads();
        sh[t] += x;
        __syncthreads();
    }
    if (t < NB) bsum[t] = sh[t] - v;   // exclusive
}

__global__ __launch_bounds__(256) void scan_add_kernel(int* __restrict__ rowstart,
        const int* __restrict__ bsum, int N) {
    const int b = blockIdx.x;
    if (b == 0) return;
    const int t = threadIdx.x;
    const int off = bsum[b];
    const int base = b * 1024 + t * 4;
    if (base + 0 < N) rowstart[base + 0] += off;
    if (base + 1 < N) rowstart[base + 1] += off;
    if (base + 2 < N) rowstart[base + 2] += off;
    if (base + 3 < N) rowstart[base + 3] += off;
}

// ---------------- fill: atomic-free dst-sorted edge array ----------------
__global__ __launch_bounds__(256) void fill_kernel(const int* __restrict__ src,
        const int* __restrict__ dst, const int* __restrict__ rowstart,
        const int* __restrict__ eord, int* __restrict__ esrc, int E) {
    int i = blockIdx.x * 256 + threadIdx.x;
    if (i >= E) return;
    esrc[rowstart[dst[i]] + eord[i]] = src[i];
}

// ---------------- GEMM: H[N,OUT] = (X * rowscale) @ W[128,OUT] ----------------

__device__ inline void fma4(float4& a, float s, const float4& w) {
    a.x = fmaf(s, w.x, a.x);
    a.y = fmaf(s, w.y, a.y);
    a.z = fmaf(s, w.z, a.z);
    a.w = fmaf(s, w.w, a.w);
}

template<int OUT, int RPB>
__global__ __launch_bounds__(256) void gemm_kernel(const float* __restrict__ X,
        const float* __restrict__ rowscale,   // may be null
        const float* __restrict__ W,
        float* __restrict__ H, int N) {
    constexpr int CQ = OUT / 4;          // float4 columns (32 or 16)
    constexpr int BK = 32;               // K-tile for W staging
    static_assert(RPB == 4 * (256 / CQ), "rows per block mismatch");

    __shared__ float sW[BK * OUT];
    __shared__ float sX[RPB][INF + 4];

    const int tid = threadIdx.x;
    const int row0 = blockIdx.x * RPB;

    for (int i = tid; i < RPB * (INF / 4); i += 256) {
        int r  = i >> 5;
        int kc = i & 31;
        int gr = row0 + r;
        float4 v = make_float4(0.f, 0.f, 0.f, 0.f);
        if (gr < N) {
            v = reinterpret_cast<const float4*>(X)[(size_t)gr * 32 + kc];
            if (rowscale) {
                float s = rowscale[gr];
                v.x *= s; v.y *= s; v.z *= s; v.w *= s;
            }
        }
        *reinterpret_cast<float4*>(&sX[r][kc * 4]) = v;
    }

    const int cq = tid % CQ;
    const int rp = tid / CQ;
    const int r0 = rp * 4;

    float4 acc0 = make_float4(0.f, 0.f, 0.f, 0.f);
    float4 acc1 = make_float4(0.f, 0.f, 0.f, 0.f);
    float4 acc2 = make_float4(0.f, 0.f, 0.f, 0.f);
    float4 acc3 = make_float4(0.f, 0.f, 0.f, 0.f);

    for (int kt = 0; kt < INF / BK; ++kt) {
        __syncthreads();
        for (int i = tid; i < BK * CQ; i += 256)
            reinterpret_cast<float4*>(sW)[i] =
                reinterpret_cast<const float4*>(W)[kt * BK * CQ + i];
        __syncthreads();

        #pragma unroll 2
        for (int k4 = 0; k4 < BK / 4; ++k4) {
            const int kk = kt * BK + k4 * 4;
            float4 xa = *reinterpret_cast<const float4*>(&sX[r0 + 0][kk]);
            float4 xb = *reinterpret_cast<const float4*>(&sX[r0 + 1][kk]);
            float4 xc = *reinterpret_cast<const float4*>(&sX[r0 + 2][kk]);
            float4 xd = *reinterpret_cast<const float4*>(&sX[r0 + 3][kk]);
            const float4* wr = reinterpret_cast<const float4*>(sW + (k4 * 4) * OUT) + cq;
            float4 w0 = wr[0];
            float4 w1 = wr[CQ];
            float4 w2 = wr[2 * CQ];
            float4 w3 = wr[3 * CQ];
            fma4(acc0, xa.x, w0); fma4(acc0, xa.y, w1); fma4(acc0, xa.z, w2); fma4(acc0, xa.w, w3);
            fma4(acc1, xb.x, w0); fma4(acc1, xb.y, w1); fma4(acc1, xb.z, w2); fma4(acc1, xb.w, w3);
            fma4(acc2, xc.x, w0); fma4(acc2, xc.y, w1); fma4(acc2, xc.z, w2); fma4(acc2, xc.w, w3);
            fma4(acc3, xd.x, w0); fma4(acc3, xd.y, w1); fma4(acc3, xd.z, w2); fma4(acc3, xd.w, w3);
        }
    }

    if (row0 + r0 + 0 < N) reinterpret_cast<float4*>(H)[(size_t)(row0 + r0 + 0) * CQ + cq] = acc0;
    if (row0 + r0 + 1 < N) reinterpret_cast<float4*>(H)[(size_t)(row0 + r0 + 1) * CQ + cq] = acc1;
    if (row0 + r0 + 2 < N) reinterpret_cast<float4*>(H)[(size_t)(row0 + r0 + 2) * CQ + cq] = acc2;
    if (row0 + r0 + 3 < N) reinterpret_cast<float4*>(H)[(size_t)(row0 + r0 + 3) * CQ + cq] = acc3;
}

// ---------------- CSR gather-aggregate + fused post ----------------

__global__ __launch_bounds__(256) void agg128_kernel(const float* __restrict__ H,
        const int* __restrict__ esrc, const int* __restrict__ rowstart,
        const int* __restrict__ cnt,
        const float* __restrict__ nin, const float* __restrict__ bias,
        const float* __restrict__ nout, float* __restrict__ out, int N) {
    int wid  = (blockIdx.x * 256 + threadIdx.x) >> 6;
    int lane = threadIdx.x & 63;
    if (wid >= N) return;
    int beg = rowstart[wid];
    int end = beg + cnt[wid];
    const float2* Hp = (const float2*)H;
    float2 a0 = make_float2(0.f, 0.f), a1 = make_float2(0.f, 0.f);
    int j = beg;
    for (; j + 2 <= end; j += 2) {
        int s0 = esrc[j], s1 = esrc[j + 1];
        float2 v0 = Hp[(size_t)s0 * 64 + lane];
        float2 v1 = Hp[(size_t)s1 * 64 + lane];
        a0.x += v0.x; a0.y += v0.y;
        a1.x += v1.x; a1.y += v1.y;
    }
    if (j < end) {
        int s0 = esrc[j];
        float2 v0 = Hp[(size_t)s0 * 64 + lane];
        a0.x += v0.x; a0.y += v0.y;
    }
    a0.x += a1.x; a0.y += a1.y;
    float s = nin[wid];
    float2 b = ((const float2*)bias)[lane];
    float r0 = fmaxf(fmaf(a0.x, s, b.x), 0.f);
    float r1 = fmaxf(fmaf(a0.y, s, b.y), 0.f);
    float t = nout[wid];
    r0 *= t; r1 *= t;
    ((float2*)out)[(size_t)wid * 64 + lane] = make_float2(r0, r1);
}

__global__ __launch_bounds__(256) void agg64_kernel(const float* __restrict__ H,
        const int* __restrict__ esrc, const int* __restrict__ rowstart,
        const int* __restrict__ cnt,
        const float* __restrict__ nin, const float* __restrict__ bias,
        float* __restrict__ out, int N) {
    int wid  = (blockIdx.x * 256 + threadIdx.x) >> 6;
    int lane = threadIdx.x & 63;
    if (wid >= N) return;
    int beg = rowstart[wid];
    int end = beg + cnt[wid];
    float a0 = 0.f, a1 = 0.f, a2 = 0.f, a3 = 0.f;
    int j = beg;
    for (; j + 4 <= end; j += 4) {
        a0 += H[(size_t)esrc[j]     * 64 + lane];
        a1 += H[(size_t)esrc[j + 1] * 64 + lane];
        a2 += H[(size_t)esrc[j + 2] * 64 + lane];
        a3 += H[(size_t)esrc[j + 3] * 64 + lane];
    }
    for (; j < end; ++j) a0 += H[(size_t)esrc[j] * 64 + lane];
    float acc = (a0 + a1) + (a2 + a3);
    float r = fmaxf(fmaf(acc, nin[wid], bias[lane]), 0.f);
    out[(size_t)wid * 64 + lane] = r;
}

// ---------------- launch ----------------

extern "C" void kernel_launch(void* const* d_in, const int* in_sizes, int n_in,
                              void* d_out, int out_size, void* d_ws, size_t ws_size,
                              hipStream_t stream) {
    const float* x  = (const float*)d_in[0];
    const float* W1 = (const float*)d_in[1];
    const float* b1 = (const float*)d_in[2];
    const float* W2 = (const float*)d_in[3];
    const float* b2 = (const float*)d_in[4];
    const int*   src = (const int*)d_in[5];
    const int*   dst = (const int*)d_in[6];

    const int N = in_sizes[0] / INF;   // 100000
    const int E = in_sizes[5];         // 1600000

    char* ws = (char*)d_ws;
    const size_t padN = (((size_t)N * 4 + 255) / 256) * 256;
    const size_t padE = (((size_t)E * 4 + 255) / 256) * 256;
    const size_t matB = (size_t)N * INF * sizeof(float);

    float* out = (float*)d_out;

    int*   cnt_src  = (int*)  (ws);
    int*   cnt_dst  = (int*)  (ws + padN);
    int*   rowstart = (int*)  (ws + 2 * padN);
    float* nout     = (float*)(ws + 3 * padN);
    float* nin      = (float*)(ws + 4 * padN);
    int*   esrc     = (int*)  (ws + 5 * padN);
    float* A        = (float*)(ws + 5 * padN + padE);
    float* B        = (float*)(ws + 5 * padN + padE + matB);
    int*   eord     = (int*)A;   // clobbered by gemm1 (after fill reads it)
    int*   bsum     = (int*)B;   // clobbered by agg128 (after scan reads it)

    const int NB  = (N + 1023) / 1024;
    const int NBE = (E + 255) / 256;

    hipMemsetAsync(cnt_src, 0, (size_t)N * sizeof(int), stream);
    hipMemsetAsync(cnt_dst, 0, (size_t)N * sizeof(int), stream);

    // per-edge ordinals + degree histograms (one thread per edge)
    count_kernel<<<NBE, 256, 0, stream>>>(src, dst, cnt_src, cnt_dst, eord, E);

    // exclusive scan of cnt_dst -> rowstart
    scan_blocks_kernel<<<NB, 256, 0, stream>>>(cnt_dst, rowstart, bsum, N);
    scan_bsums_kernel<<<1, 1024, 0, stream>>>(bsum, NB);
    scan_add_kernel<<<NB, 256, 0, stream>>>(rowstart, bsum, N);

    norm_kernel<<<(N + 255) / 256, 256, 0, stream>>>(cnt_src, cnt_dst, nout, nin, N);

    // atomic-free dst-sorted edge fill
    fill_kernel<<<NBE, 256, 0, stream>>>(src, dst, rowstart, eord, esrc, E);

    // layer 1: A = (x*nout) @ W1 ; B = relu(csr_sum(A)*nin + b1) * nout
    gemm_kernel<128, 32><<<(N + 31) / 32, 256, 0, stream>>>(x, nout, W1, A, N);
    agg128_kernel<<<(N * 64 + 255) / 256, 256, 0, stream>>>(A, esrc, rowstart, cnt_dst, nin, b1, nout, B, N);

    // layer 2: A = B @ W2 ; out = relu(csr_sum(A)*nin + b2)
    gemm_kernel<64, 64><<<(N + 63) / 64, 256, 0, stream>>>(B, nullptr, W2, A, N);
    agg64_kernel<<<(N * 64 + 255) / 256, 256, 0, stream>>>(A, esrc, rowstart, cnt_dst, nin, b2, out, N);
}

// Round 9
// 436.400 us; speedup vs baseline: 12.6571x; 1.0555x over previous
//
#include <hip/hip_runtime.h>
#include <hip/hip_bf16.h>

#define INF 128
#define HF 64

// ---------------- count: per-edge ordinals + degree histograms ----------------
__global__ __launch_bounds__(256) void count_kernel(const int* __restrict__ src,
        const int* __restrict__ dst, int* __restrict__ cnt_src,
        int* __restrict__ cnt_dst, int* __restrict__ eord, int E) {
    int i = blockIdx.x * 256 + threadIdx.x;
    if (i >= E) return;
    int s = src[i], d = dst[i];
    eord[i] = atomicAdd(&cnt_dst[d], 1);
    atomicAdd(&cnt_src[s], 1);
}

__global__ void norm_kernel(const int* __restrict__ cs, const int* __restrict__ cd,
                            float* __restrict__ nout, float* __restrict__ nin, int N) {
    int i = blockIdx.x * blockDim.x + threadIdx.x;
    if (i < N) {
        int a = cs[i]; nout[i] = a > 0 ? rsqrtf((float)a) : 0.f;
        int b = cd[i]; nin[i]  = b > 0 ? rsqrtf((float)b) : 0.f;
    }
}

// ---------------- parallel 3-phase exclusive scan (int input) ----------------
__global__ __launch_bounds__(256) void scan_blocks_kernel(const int* __restrict__ deg,
        int* __restrict__ rowstart, int* __restrict__ bsum, int N) {
    __shared__ int sh[256];
    const int b = blockIdx.x, t = threadIdx.x;
    const int base = b * 1024 + t * 4;
    int v0 = (base + 0 < N) ? deg[base + 0] : 0;
    int v1 = (base + 1 < N) ? deg[base + 1] : 0;
    int v2 = (base + 2 < N) ? deg[base + 2] : 0;
    int v3 = (base + 3 < N) ? deg[base + 3] : 0;
    sh[t] = v0 + v1 + v2 + v3;
    __syncthreads();
    for (int off = 1; off < 256; off <<= 1) {
        int x = (t >= off) ? sh[t - off] : 0;
        __syncthreads();
        sh[t] += x;
        __syncthreads();
    }
    if (t == 255) bsum[b] = sh[255];
    int run = (t == 0) ? 0 : sh[t - 1];
    if (base + 0 < N) { rowstart[base + 0] = run; run += v0; }
    if (base + 1 < N) { rowstart[base + 1] = run; run += v1; }
    if (base + 2 < N) { rowstart[base + 2] = run; run += v2; }
    if (base + 3 < N) { rowstart[base + 3] = run; }
}

__global__ __launch_bounds__(1024) void scan_bsums_kernel(int* __restrict__ bsum, int NB) {
    __shared__ int sh[1024];
    const int t = threadIdx.x;
    int v = (t < NB) ? bsum[t] : 0;
    sh[t] = v;
    __syncthreads();
    for (int off = 1; off < 1024; off <<= 1) {
        int x = (t >= off) ? sh[t - off] : 0;
        __syncthreads();
        sh[t] += x;
        __syncthreads();
    }
    if (t < NB) bsum[t] = sh[t] - v;   // exclusive
}

__global__ __launch_bounds__(256) void scan_add_kernel(int* __restrict__ rowstart,
        const int* __restrict__ bsum, int N) {
    const int b = blockIdx.x;
    if (b == 0) return;
    const int t = threadIdx.x;
    const int off = bsum[b];
    const int base = b * 1024 + t * 4;
    if (base + 0 < N) rowstart[base + 0] += off;
    if (base + 1 < N) rowstart[base + 1] += off;
    if (base + 2 < N) rowstart[base + 2] += off;
    if (base + 3 < N) rowstart[base + 3] += off;
}

// ---------------- fill: atomic-free dst-sorted edge array ----------------
__global__ __launch_bounds__(256) void fill_kernel(const int* __restrict__ src,
        const int* __restrict__ dst, const int* __restrict__ rowstart,
        const int* __restrict__ eord, int* __restrict__ esrc, int E) {
    int i = blockIdx.x * 256 + threadIdx.x;
    if (i >= E) return;
    esrc[rowstart[dst[i]] + eord[i]] = src[i];
}

// ---------------- GEMM: H[N,OUT] = (X * rowscale) @ W[128,OUT], bf16 out ----------------

__device__ inline void fma4(float4& a, float s, const float4& w) {
    a.x = fmaf(s, w.x, a.x);
    a.y = fmaf(s, w.y, a.y);
    a.z = fmaf(s, w.z, a.z);
    a.w = fmaf(s, w.w, a.w);
}

__device__ inline uint2 pack_bf16x4(float4 a) {
    __hip_bfloat162 lo = __float22bfloat162_rn(make_float2(a.x, a.y));
    __hip_bfloat162 hi = __float22bfloat162_rn(make_float2(a.z, a.w));
    uint2 r;
    r.x = *reinterpret_cast<unsigned*>(&lo);
    r.y = *reinterpret_cast<unsigned*>(&hi);
    return r;
}

template<int OUT, int RPB>
__global__ __launch_bounds__(256) void gemm_kernel(const float* __restrict__ X,
        const float* __restrict__ rowscale,   // may be null
        const float* __restrict__ W,
        unsigned short* __restrict__ H,       // bf16 out, row stride OUT
        int N) {
    constexpr int CQ = OUT / 4;          // float4 columns (32 or 16)
    constexpr int BK = 32;               // K-tile for W staging
    static_assert(RPB == 4 * (256 / CQ), "rows per block mismatch");

    __shared__ float sW[BK * OUT];
    __shared__ float sX[RPB][INF + 4];

    const int tid = threadIdx.x;
    const int row0 = blockIdx.x * RPB;

    for (int i = tid; i < RPB * (INF / 4); i += 256) {
        int r  = i >> 5;
        int kc = i & 31;
        int gr = row0 + r;
        float4 v = make_float4(0.f, 0.f, 0.f, 0.f);
        if (gr < N) {
            v = reinterpret_cast<const float4*>(X)[(size_t)gr * 32 + kc];
            if (rowscale) {
                float s = rowscale[gr];
                v.x *= s; v.y *= s; v.z *= s; v.w *= s;
            }
        }
        *reinterpret_cast<float4*>(&sX[r][kc * 4]) = v;
    }

    const int cq = tid % CQ;
    const int rp = tid / CQ;
    const int r0 = rp * 4;

    float4 acc0 = make_float4(0.f, 0.f, 0.f, 0.f);
    float4 acc1 = make_float4(0.f, 0.f, 0.f, 0.f);
    float4 acc2 = make_float4(0.f, 0.f, 0.f, 0.f);
    float4 acc3 = make_float4(0.f, 0.f, 0.f, 0.f);

    for (int kt = 0; kt < INF / BK; ++kt) {
        __syncthreads();
        for (int i = tid; i < BK * CQ; i += 256)
            reinterpret_cast<float4*>(sW)[i] =
                reinterpret_cast<const float4*>(W)[kt * BK * CQ + i];
        __syncthreads();

        #pragma unroll 2
        for (int k4 = 0; k4 < BK / 4; ++k4) {
            const int kk = kt * BK + k4 * 4;
            float4 xa = *reinterpret_cast<const float4*>(&sX[r0 + 0][kk]);
            float4 xb = *reinterpret_cast<const float4*>(&sX[r0 + 1][kk]);
            float4 xc = *reinterpret_cast<const float4*>(&sX[r0 + 2][kk]);
            float4 xd = *reinterpret_cast<const float4*>(&sX[r0 + 3][kk]);
            const float4* wr = reinterpret_cast<const float4*>(sW + (k4 * 4) * OUT) + cq;
            float4 w0 = wr[0];
            float4 w1 = wr[CQ];
            float4 w2 = wr[2 * CQ];
            float4 w3 = wr[3 * CQ];
            fma4(acc0, xa.x, w0); fma4(acc0, xa.y, w1); fma4(acc0, xa.z, w2); fma4(acc0, xa.w, w3);
            fma4(acc1, xb.x, w0); fma4(acc1, xb.y, w1); fma4(acc1, xb.z, w2); fma4(acc1, xb.w, w3);
            fma4(acc2, xc.x, w0); fma4(acc2, xc.y, w1); fma4(acc2, xc.z, w2); fma4(acc2, xc.w, w3);
            fma4(acc3, xd.x, w0); fma4(acc3, xd.y, w1); fma4(acc3, xd.z, w2); fma4(acc3, xd.w, w3);
        }
    }

    uint2* Hb = reinterpret_cast<uint2*>(H);
    if (row0 + r0 + 0 < N) Hb[(size_t)(row0 + r0 + 0) * CQ + cq] = pack_bf16x4(acc0);
    if (row0 + r0 + 1 < N) Hb[(size_t)(row0 + r0 + 1) * CQ + cq] = pack_bf16x4(acc1);
    if (row0 + r0 + 2 < N) Hb[(size_t)(row0 + r0 + 2) * CQ + cq] = pack_bf16x4(acc2);
    if (row0 + r0 + 3 < N) Hb[(size_t)(row0 + r0 + 3) * CQ + cq] = pack_bf16x4(acc3);
}

// ---------------- CSR gather-aggregate (bf16 in) + fused post (fp32) ----------------

__global__ __launch_bounds__(256) void agg128_kernel(const __hip_bfloat162* __restrict__ H,
        const int* __restrict__ esrc, const int* __restrict__ rowstart,
        const int* __restrict__ cnt,
        const float* __restrict__ nin, const float* __restrict__ bias,
        const float* __restrict__ nout, float* __restrict__ out, int N) {
    int wid  = (blockIdx.x * 256 + threadIdx.x) >> 6;
    int lane = threadIdx.x & 63;
    if (wid >= N) return;
    int beg = rowstart[wid];
    int end = beg + cnt[wid];
    float2 a0 = make_float2(0.f, 0.f), a1 = make_float2(0.f, 0.f);
    int j = beg;
    for (; j + 2 <= end; j += 2) {
        int s0 = esrc[j], s1 = esrc[j + 1];
        float2 v0 = __bfloat1622float2(H[(size_t)s0 * 64 + lane]);
        float2 v1 = __bfloat1622float2(H[(size_t)s1 * 64 + lane]);
        a0.x += v0.x; a0.y += v0.y;
        a1.x += v1.x; a1.y += v1.y;
    }
    if (j < end) {
        float2 v0 = __bfloat1622float2(H[(size_t)esrc[j] * 64 + lane]);
        a0.x += v0.x; a0.y += v0.y;
    }
    a0.x += a1.x; a0.y += a1.y;
    float s = nin[wid];
    float2 b = ((const float2*)bias)[lane];
    float r0 = fmaxf(fmaf(a0.x, s, b.x), 0.f);
    float r1 = fmaxf(fmaf(a0.y, s, b.y), 0.f);
    float t = nout[wid];
    r0 *= t; r1 *= t;
    ((float2*)out)[(size_t)wid * 64 + lane] = make_float2(r0, r1);
}

__global__ __launch_bounds__(256) void agg64_kernel(const __hip_bfloat16* __restrict__ H,
        const int* __restrict__ esrc, const int* __restrict__ rowstart,
        const int* __restrict__ cnt,
        const float* __restrict__ nin, const float* __restrict__ bias,
        float* __restrict__ out, int N) {
    int wid  = (blockIdx.x * 256 + threadIdx.x) >> 6;
    int lane = threadIdx.x & 63;
    if (wid >= N) return;
    int beg = rowstart[wid];
    int end = beg + cnt[wid];
    float a0 = 0.f, a1 = 0.f, a2 = 0.f, a3 = 0.f;
    int j = beg;
    for (; j + 4 <= end; j += 4) {
        a0 += __bfloat162float(H[(size_t)esrc[j]     * 64 + lane]);
        a1 += __bfloat162float(H[(size_t)esrc[j + 1] * 64 + lane]);
        a2 += __bfloat162float(H[(size_t)esrc[j + 2] * 64 + lane]);
        a3 += __bfloat162float(H[(size_t)esrc[j + 3] * 64 + lane]);
    }
    for (; j < end; ++j) a0 += __bfloat162float(H[(size_t)esrc[j] * 64 + lane]);
    float acc = (a0 + a1) + (a2 + a3);
    float r = fmaxf(fmaf(acc, nin[wid], bias[lane]), 0.f);
    out[(size_t)wid * 64 + lane] = r;
}

// ---------------- launch ----------------

extern "C" void kernel_launch(void* const* d_in, const int* in_sizes, int n_in,
                              void* d_out, int out_size, void* d_ws, size_t ws_size,
                              hipStream_t stream) {
    const float* x  = (const float*)d_in[0];
    const float* W1 = (const float*)d_in[1];
    const float* b1 = (const float*)d_in[2];
    const float* W2 = (const float*)d_in[3];
    const float* b2 = (const float*)d_in[4];
    const int*   src = (const int*)d_in[5];
    const int*   dst = (const int*)d_in[6];

    const int N = in_sizes[0] / INF;   // 100000
    const int E = in_sizes[5];         // 1600000

    char* ws = (char*)d_ws;
    const size_t padN   = (((size_t)N * 4 + 255) / 256) * 256;
    const size_t padE   = (((size_t)E * 4 + 255) / 256) * 256;
    const size_t padAbf = (((size_t)N * INF * 2 + 255) / 256) * 256;   // bf16 N x 128
    const size_t matB   = (size_t)N * INF * sizeof(float);             // fp32 N x 128

    float* out = (float*)d_out;

    int*   cnt_src  = (int*)  (ws);
    int*   cnt_dst  = (int*)  (ws + padN);
    int*   rowstart = (int*)  (ws + 2 * padN);
    float* nout     = (float*)(ws + 3 * padN);
    float* nin      = (float*)(ws + 4 * padN);
    int*   esrc     = (int*)  (ws + 5 * padN);
    unsigned short* Abf = (unsigned short*)(ws + 5 * padN + padE);     // bf16 h (layer1: Nx128, layer2: Nx64)
    float* B        = (float*)(ws + 5 * padN + padE + padAbf);         // fp32 layer1 output, Nx128

    int* eord = (int*)B;                         // dead until agg128 writes B (fill reads first)
    int* bsum = (int*)((char*)B + (matB / 2));   // dead region of B until agg128; scan-only use

    const int NB  = (N + 1023) / 1024;
    const int NBE = (E + 255) / 256;

    hipMemsetAsync(cnt_src, 0, (size_t)N * sizeof(int), stream);
    hipMemsetAsync(cnt_dst, 0, (size_t)N * sizeof(int), stream);

    // per-edge ordinals + degree histograms
    count_kernel<<<NBE, 256, 0, stream>>>(src, dst, cnt_src, cnt_dst, eord, E);

    // exclusive scan of cnt_dst -> rowstart
    scan_blocks_kernel<<<NB, 256, 0, stream>>>(cnt_dst, rowstart, bsum, N);
    scan_bsums_kernel<<<1, 1024, 0, stream>>>(bsum, NB);
    scan_add_kernel<<<NB, 256, 0, stream>>>(rowstart, bsum, N);

    norm_kernel<<<(N + 255) / 256, 256, 0, stream>>>(cnt_src, cnt_dst, nout, nin, N);

    // atomic-free dst-sorted edge fill
    fill_kernel<<<NBE, 256, 0, stream>>>(src, dst, rowstart, eord, esrc, E);

    // layer 1: Abf = bf16((x*nout) @ W1) ; B = relu(csr_sum(Abf)*nin + b1) * nout
    gemm_kernel<128, 32><<<(N + 31) / 32, 256, 0, stream>>>(x, nout, W1, Abf, N);
    agg128_kernel<<<(N * 64 + 255) / 256, 256, 0, stream>>>(
        (const __hip_bfloat162*)Abf, esrc, rowstart, cnt_dst, nin, b1, nout, B, N);

    // layer 2: Abf = bf16(B @ W2) ; out = relu(csr_sum(Abf)*nin + b2)
    gemm_kernel<64, 64><<<(N + 63) / 64, 256, 0, stream>>>(B, nullptr, W2, Abf, N);
    agg64_kernel<<<(N * 64 + 255) / 256, 256, 0, stream>>>(
        (const __hip_bfloat16*)Abf, esrc, rowstart, cnt_dst, nin, b2, out, N);
}

// Round 10
// 402.894 us; speedup vs baseline: 13.7097x; 1.0832x over previous
//
#include <hip/hip_runtime.h>
#include <hip/hip_bf16.h>

#define INF 128
#define HF 64

// src-degree histogram partition params
#define HR_RANGE 16000     // nodes per range (62.5 KB LDS)
#define HR_NR    7         // ranges: 7*16000 = 112000 >= N
#define HR_S     64        // edge slices

// ---------------- src-degree histogram: LDS-privatized, no global atomics ----------------
// grid = HR_NR * HR_S blocks; block (r = bx/HR_S, s = bx%HR_S) histograms slice s of src
// for node range r into LDS, writes 16000-int partial coalesced to H[(r*HR_S+s)*HR_RANGE].
__global__ __launch_bounds__(256) void srchist_partial_kernel(const int* __restrict__ src,
        int* __restrict__ H, int E, int SL) {
    __shared__ int h[HR_RANGE];
    const int t = threadIdx.x;
    const int r = blockIdx.x / HR_S;
    const int s = blockIdx.x % HR_S;
    const int base = r * HR_RANGE;
    for (int i = t; i < HR_RANGE; i += 256) h[i] = 0;
    __syncthreads();
    const int e0 = s * SL;
    const int e1 = min(e0 + SL, E);
    for (int e = e0 + t; e < e1; e += 256) {
        unsigned v = (unsigned)(src[e] - base);
        if (v < HR_RANGE) atomicAdd(&h[v], 1);
    }
    __syncthreads();
    int* Hp = H + (size_t)(r * HR_S + s) * HR_RANGE;
    for (int i = t; i < HR_RANGE; i += 256) Hp[i] = h[i];
}

// cnt_src[bin] = sum over slices of partials
__global__ __launch_bounds__(256) void srchist_merge_kernel(const int* __restrict__ H,
        int* __restrict__ cnt_src, int N) {
    int bin = blockIdx.x * 256 + threadIdx.x;
    if (bin >= N) return;
    int r = bin / HR_RANGE;
    int local = bin - r * HR_RANGE;
    const int* Hp = H + (size_t)r * HR_S * HR_RANGE + local;
    int sum = 0;
    #pragma unroll 8
    for (int s = 0; s < HR_S; ++s) sum += Hp[(size_t)s * HR_RANGE];
    cnt_src[bin] = sum;
}

// ---------------- eord: per-edge dst ordinals (the one returning atomic) ----------------
__global__ __launch_bounds__(256) void eord_kernel(const int* __restrict__ dst,
        int* __restrict__ cnt_dst, int* __restrict__ eord, int E) {
    int i = blockIdx.x * 256 + threadIdx.x;
    if (i >= E) return;
    eord[i] = atomicAdd(&cnt_dst[dst[i]], 1);
}

__global__ void norm_kernel(const int* __restrict__ cs, const int* __restrict__ cd,
                            float* __restrict__ nout, float* __restrict__ nin, int N) {
    int i = blockIdx.x * blockDim.x + threadIdx.x;
    if (i < N) {
        int a = cs[i]; nout[i] = a > 0 ? rsqrtf((float)a) : 0.f;
        int b = cd[i]; nin[i]  = b > 0 ? rsqrtf((float)b) : 0.f;
    }
}

// ---------------- parallel 3-phase exclusive scan (int input) ----------------
__global__ __launch_bounds__(256) void scan_blocks_kernel(const int* __restrict__ deg,
        int* __restrict__ rowstart, int* __restrict__ bsum, int N) {
    __shared__ int sh[256];
    const int b = blockIdx.x, t = threadIdx.x;
    const int base = b * 1024 + t * 4;
    int v0 = (base + 0 < N) ? deg[base + 0] : 0;
    int v1 = (base + 1 < N) ? deg[base + 1] : 0;
    int v2 = (base + 2 < N) ? deg[base + 2] : 0;
    int v3 = (base + 3 < N) ? deg[base + 3] : 0;
    sh[t] = v0 + v1 + v2 + v3;
    __syncthreads();
    for (int off = 1; off < 256; off <<= 1) {
        int x = (t >= off) ? sh[t - off] : 0;
        __syncthreads();
        sh[t] += x;
        __syncthreads();
    }
    if (t == 255) bsum[b] = sh[255];
    int run = (t == 0) ? 0 : sh[t - 1];
    if (base + 0 < N) { rowstart[base + 0] = run; run += v0; }
    if (base + 1 < N) { rowstart[base + 1] = run; run += v1; }
    if (base + 2 < N) { rowstart[base + 2] = run; run += v2; }
    if (base + 3 < N) { rowstart[base + 3] = run; }
}

__global__ __launch_bounds__(1024) void scan_bsums_kernel(int* __restrict__ bsum, int NB) {
    __shared__ int sh[1024];
    const int t = threadIdx.x;
    int v = (t < NB) ? bsum[t] : 0;
    sh[t] = v;
    __syncthreads();
    for (int off = 1; off < 1024; off <<= 1) {
        int x = (t >= off) ? sh[t - off] : 0;
        __syncthreads();
        sh[t] += x;
        __syncthreads();
    }
    if (t < NB) bsum[t] = sh[t] - v;   // exclusive
}

__global__ __launch_bounds__(256) void scan_add_kernel(int* __restrict__ rowstart,
        const int* __restrict__ bsum, int N) {
    const int b = blockIdx.x;
    if (b == 0) return;
    const int t = threadIdx.x;
    const int off = bsum[b];
    const int base = b * 1024 + t * 4;
    if (base + 0 < N) rowstart[base + 0] += off;
    if (base + 1 < N) rowstart[base + 1] += off;
    if (base + 2 < N) rowstart[base + 2] += off;
    if (base + 3 < N) rowstart[base + 3] += off;
}

// ---------------- fill: atomic-free dst-sorted edge array ----------------
__global__ __launch_bounds__(256) void fill_kernel(const int* __restrict__ src,
        const int* __restrict__ dst, const int* __restrict__ rowstart,
        const int* __restrict__ eord, int* __restrict__ esrc, int E) {
    int i = blockIdx.x * 256 + threadIdx.x;
    if (i >= E) return;
    esrc[rowstart[dst[i]] + eord[i]] = src[i];
}

// ---------------- GEMM: H[N,OUT] = (X * rowscale) @ W[128,OUT], bf16 out ----------------

__device__ inline void fma4(float4& a, float s, const float4& w) {
    a.x = fmaf(s, w.x, a.x);
    a.y = fmaf(s, w.y, a.y);
    a.z = fmaf(s, w.z, a.z);
    a.w = fmaf(s, w.w, a.w);
}

__device__ inline uint2 pack_bf16x4(float4 a) {
    __hip_bfloat162 lo = __float22bfloat162_rn(make_float2(a.x, a.y));
    __hip_bfloat162 hi = __float22bfloat162_rn(make_float2(a.z, a.w));
    uint2 r;
    r.x = *reinterpret_cast<unsigned*>(&lo);
    r.y = *reinterpret_cast<unsigned*>(&hi);
    return r;
}

template<int OUT, int RPB>
__global__ __launch_bounds__(256) void gemm_kernel(const float* __restrict__ X,
        const float* __restrict__ rowscale,   // may be null
        const float* __restrict__ W,
        unsigned short* __restrict__ H,       // bf16 out, row stride OUT
        int N) {
    constexpr int CQ = OUT / 4;          // float4 columns (32 or 16)
    constexpr int BK = 32;               // K-tile for W staging
    static_assert(RPB == 4 * (256 / CQ), "rows per block mismatch");

    __shared__ float sW[BK * OUT];
    __shared__ float sX[RPB][INF + 4];

    const int tid = threadIdx.x;
    const int row0 = blockIdx.x * RPB;

    for (int i = tid; i < RPB * (INF / 4); i += 256) {
        int r  = i >> 5;
        int kc = i & 31;
        int gr = row0 + r;
        float4 v = make_float4(0.f, 0.f, 0.f, 0.f);
        if (gr < N) {
            v = reinterpret_cast<const float4*>(X)[(size_t)gr * 32 + kc];
            if (rowscale) {
                float s = rowscale[gr];
                v.x *= s; v.y *= s; v.z *= s; v.w *= s;
            }
        }
        *reinterpret_cast<float4*>(&sX[r][kc * 4]) = v;
    }

    const int cq = tid % CQ;
    const int rp = tid / CQ;
    const int r0 = rp * 4;

    float4 acc0 = make_float4(0.f, 0.f, 0.f, 0.f);
    float4 acc1 = make_float4(0.f, 0.f, 0.f, 0.f);
    float4 acc2 = make_float4(0.f, 0.f, 0.f, 0.f);
    float4 acc3 = make_float4(0.f, 0.f, 0.f, 0.f);

    for (int kt = 0; kt < INF / BK; ++kt) {
        __syncthreads();
        for (int i = tid; i < BK * CQ; i += 256)
            reinterpret_cast<float4*>(sW)[i] =
                reinterpret_cast<const float4*>(W)[kt * BK * CQ + i];
        __syncthreads();

        #pragma unroll 2
        for (int k4 = 0; k4 < BK / 4; ++k4) {
            const int kk = kt * BK + k4 * 4;
            float4 xa = *reinterpret_cast<const float4*>(&sX[r0 + 0][kk]);
            float4 xb = *reinterpret_cast<const float4*>(&sX[r0 + 1][kk]);
            float4 xc = *reinterpret_cast<const float4*>(&sX[r0 + 2][kk]);
            float4 xd = *reinterpret_cast<const float4*>(&sX[r0 + 3][kk]);
            const float4* wr = reinterpret_cast<const float4*>(sW + (k4 * 4) * OUT) + cq;
            float4 w0 = wr[0];
            float4 w1 = wr[CQ];
            float4 w2 = wr[2 * CQ];
            float4 w3 = wr[3 * CQ];
            fma4(acc0, xa.x, w0); fma4(acc0, xa.y, w1); fma4(acc0, xa.z, w2); fma4(acc0, xa.w, w3);
            fma4(acc1, xb.x, w0); fma4(acc1, xb.y, w1); fma4(acc1, xb.z, w2); fma4(acc1, xb.w, w3);
            fma4(acc2, xc.x, w0); fma4(acc2, xc.y, w1); fma4(acc2, xc.z, w2); fma4(acc2, xc.w, w3);
            fma4(acc3, xd.x, w0); fma4(acc3, xd.y, w1); fma4(acc3, xd.z, w2); fma4(acc3, xd.w, w3);
        }
    }

    uint2* Hb = reinterpret_cast<uint2*>(H);
    if (row0 + r0 + 0 < N) Hb[(size_t)(row0 + r0 + 0) * CQ + cq] = pack_bf16x4(acc0);
    if (row0 + r0 + 1 < N) Hb[(size_t)(row0 + r0 + 1) * CQ + cq] = pack_bf16x4(acc1);
    if (row0 + r0 + 2 < N) Hb[(size_t)(row0 + r0 + 2) * CQ + cq] = pack_bf16x4(acc2);
    if (row0 + r0 + 3 < N) Hb[(size_t)(row0 + r0 + 3) * CQ + cq] = pack_bf16x4(acc3);
}

// ---------------- CSR gather-aggregate (bf16 in) + fused post (fp32) ----------------

__global__ __launch_bounds__(256) void agg128_kernel(const __hip_bfloat162* __restrict__ H,
        const int* __restrict__ esrc, const int* __restrict__ rowstart,
        const int* __restrict__ cnt,
        const float* __restrict__ nin, const float* __restrict__ bias,
        const float* __restrict__ nout, float* __restrict__ out, int N) {
    int wid  = (blockIdx.x * 256 + threadIdx.x) >> 6;
    int lane = threadIdx.x & 63;
    if (wid >= N) return;
    int beg = rowstart[wid];
    int end = beg + cnt[wid];
    float2 a0 = make_float2(0.f, 0.f), a1 = make_float2(0.f, 0.f);
    int j = beg;
    for (; j + 2 <= end; j += 2) {
        int s0 = esrc[j], s1 = esrc[j + 1];
        float2 v0 = __bfloat1622float2(H[(size_t)s0 * 64 + lane]);
        float2 v1 = __bfloat1622float2(H[(size_t)s1 * 64 + lane]);
        a0.x += v0.x; a0.y += v0.y;
        a1.x += v1.x; a1.y += v1.y;
    }
    if (j < end) {
        float2 v0 = __bfloat1622float2(H[(size_t)esrc[j] * 64 + lane]);
        a0.x += v0.x; a0.y += v0.y;
    }
    a0.x += a1.x; a0.y += a1.y;
    float s = nin[wid];
    float2 b = ((const float2*)bias)[lane];
    float r0 = fmaxf(fmaf(a0.x, s, b.x), 0.f);
    float r1 = fmaxf(fmaf(a0.y, s, b.y), 0.f);
    float t = nout[wid];
    r0 *= t; r1 *= t;
    ((float2*)out)[(size_t)wid * 64 + lane] = make_float2(r0, r1);
}

__global__ __launch_bounds__(256) void agg64_kernel(const __hip_bfloat16* __restrict__ H,
        const int* __restrict__ esrc, const int* __restrict__ rowstart,
        const int* __restrict__ cnt,
        const float* __restrict__ nin, const float* __restrict__ bias,
        float* __restrict__ out, int N) {
    int wid  = (blockIdx.x * 256 + threadIdx.x) >> 6;
    int lane = threadIdx.x & 63;
    if (wid >= N) return;
    int beg = rowstart[wid];
    int end = beg + cnt[wid];
    float a0 = 0.f, a1 = 0.f, a2 = 0.f, a3 = 0.f;
    int j = beg;
    for (; j + 4 <= end; j += 4) {
        a0 += __bfloat162float(H[(size_t)esrc[j]     * 64 + lane]);
        a1 += __bfloat162float(H[(size_t)esrc[j + 1] * 64 + lane]);
        a2 += __bfloat162float(H[(size_t)esrc[j + 2] * 64 + lane]);
        a3 += __bfloat162float(H[(size_t)esrc[j + 3] * 64 + lane]);
    }
    for (; j < end; ++j) a0 += __bfloat162float(H[(size_t)esrc[j] * 64 + lane]);
    float acc = (a0 + a1) + (a2 + a3);
    float r = fmaxf(fmaf(acc, nin[wid], bias[lane]), 0.f);
    out[(size_t)wid * 64 + lane] = r;
}

// ---------------- launch ----------------

extern "C" void kernel_launch(void* const* d_in, const int* in_sizes, int n_in,
                              void* d_out, int out_size, void* d_ws, size_t ws_size,
                              hipStream_t stream) {
    const float* x  = (const float*)d_in[0];
    const float* W1 = (const float*)d_in[1];
    const float* b1 = (const float*)d_in[2];
    const float* W2 = (const float*)d_in[3];
    const float* b2 = (const float*)d_in[4];
    const int*   src = (const int*)d_in[5];
    const int*   dst = (const int*)d_in[6];

    const int N = in_sizes[0] / INF;   // 100000
    const int E = in_sizes[5];         // 1600000

    char* ws = (char*)d_ws;
    const size_t padN   = (((size_t)N * 4 + 255) / 256) * 256;
    const size_t padE   = (((size_t)E * 4 + 255) / 256) * 256;
    const size_t padAbf = (((size_t)N * INF * 2 + 255) / 256) * 256;   // bf16 N x 128
    const size_t matB   = (size_t)N * INF * sizeof(float);             // fp32 N x 128

    float* out = (float*)d_out;

    int*   cnt_src  = (int*)  (ws);
    int*   cnt_dst  = (int*)  (ws + padN);
    int*   rowstart = (int*)  (ws + 2 * padN);
    float* nout     = (float*)(ws + 3 * padN);
    float* nin      = (float*)(ws + 4 * padN);
    int*   esrc     = (int*)  (ws + 5 * padN);
    unsigned short* Abf = (unsigned short*)(ws + 5 * padN + padE);     // bf16 h (layer1: Nx128, layer2: Nx64)
    float* B        = (float*)(ws + 5 * padN + padE + padAbf);         // fp32 layer1 output, Nx128

    // overlays (stream-ordered lifetimes):
    int* Hpart = (int*)Abf;                      // 28.7 MB partials; dead before gemm1 writes Abf
    int* eord  = (int*)B;                        // written after Hpart's last read; dead after fill
    int* bsum  = (int*)((char*)B + (matB / 2));  // outside Hpart span; dead after scan_add

    const int NB  = (N + 1023) / 1024;
    const int NBE = (E + 255) / 256;
    const int SL  = (E + HR_S - 1) / HR_S;       // edges per slice

    hipMemsetAsync(cnt_dst, 0, (size_t)N * sizeof(int), stream);

    // cnt_src via LDS-privatized partitioned histogram (no global atomics)
    srchist_partial_kernel<<<HR_NR * HR_S, 256, 0, stream>>>(src, Hpart, E, SL);
    srchist_merge_kernel<<<(N + 255) / 256, 256, 0, stream>>>(Hpart, cnt_src, N);

    // per-edge dst ordinals (1.6M returning atomics) — cnt_dst is the byproduct
    eord_kernel<<<NBE, 256, 0, stream>>>(dst, cnt_dst, eord, E);

    // exclusive scan of cnt_dst -> rowstart
    scan_blocks_kernel<<<NB, 256, 0, stream>>>(cnt_dst, rowstart, bsum, N);
    scan_bsums_kernel<<<1, 1024, 0, stream>>>(bsum, NB);
    scan_add_kernel<<<NB, 256, 0, stream>>>(rowstart, bsum, N);

    norm_kernel<<<(N + 255) / 256, 256, 0, stream>>>(cnt_src, cnt_dst, nout, nin, N);

    // atomic-free dst-sorted edge fill
    fill_kernel<<<NBE, 256, 0, stream>>>(src, dst, rowstart, eord, esrc, E);

    // layer 1: Abf = bf16((x*nout) @ W1) ; B = relu(csr_sum(Abf)*nin + b1) * nout
    gemm_kernel<128, 32><<<(N + 31) / 32, 256, 0, stream>>>(x, nout, W1, Abf, N);
    agg128_kernel<<<(N * 64 + 255) / 256, 256, 0, stream>>>(
        (const __hip_bfloat162*)Abf, esrc, rowstart, cnt_dst, nin, b1, nout, B, N);

    // layer 2: Abf = bf16(B @ W2) ; out = relu(csr_sum(Abf)*nin + b2)
    gemm_kernel<64, 64><<<(N + 63) / 64, 256, 0, stream>>>(B, nullptr, W2, Abf, N);
    agg64_kernel<<<(N * 64 + 255) / 256, 256, 0, stream>>>(
        (const __hip_bfloat16*)Abf, esrc, rowstart, cnt_dst, nin, b2, out, N);
}

// Round 11
// 380.752 us; speedup vs baseline: 14.5069x; 1.0582x over previous
//
#include <hip/hip_runtime.h>
#include <hip/hip_bf16.h>

#define INF 128
#define HF 64

// node-range / edge-slice partition for LDS histograms
#define HR_RANGE 16000     // nodes per range -> 62.5 KB LDS
#define HR_S     64        // edge slices

// ---------------- src-degree histogram (no global atomics) ----------------
__global__ __launch_bounds__(256) void srchist_partial_kernel(const int* __restrict__ src,
        int* __restrict__ H, int E, int SL) {
    __shared__ int h[HR_RANGE];
    const int t = threadIdx.x;
    const int r = blockIdx.x / HR_S;
    const int s = blockIdx.x % HR_S;
    const int base = r * HR_RANGE;
    for (int i = t; i < HR_RANGE; i += 256) h[i] = 0;
    __syncthreads();
    const int e0 = s * SL;
    const int e1 = min(e0 + SL, E);
    for (int e = e0 + t; e < e1; e += 256) {
        unsigned v = (unsigned)(src[e] - base);
        if (v < HR_RANGE) atomicAdd(&h[v], 1);
    }
    __syncthreads();
    int* Hp = H + (size_t)(r * HR_S + s) * HR_RANGE;
    for (int i = t; i < HR_RANGE; i += 256) Hp[i] = h[i];
}

__global__ __launch_bounds__(256) void srchist_merge_kernel(const int* __restrict__ H,
        int* __restrict__ cnt_src, int N) {
    int bin = blockIdx.x * 256 + threadIdx.x;
    if (bin >= N) return;
    int r = bin / HR_RANGE;
    int local = bin - r * HR_RANGE;
    const int* Hp = H + (size_t)r * HR_S * HR_RANGE + local;
    int sum = 0;
    #pragma unroll 8
    for (int s = 0; s < HR_S; ++s) sum += Hp[(size_t)s * HR_RANGE];
    cnt_src[bin] = sum;
}

// ---------------- dst histogram partials (same structure) ----------------
__global__ __launch_bounds__(256) void dsthist_partial_kernel(const int* __restrict__ dst,
        int* __restrict__ H, int E, int SL) {
    __shared__ int h[HR_RANGE];
    const int t = threadIdx.x;
    const int r = blockIdx.x / HR_S;
    const int s = blockIdx.x % HR_S;
    const int base = r * HR_RANGE;
    for (int i = t; i < HR_RANGE; i += 256) h[i] = 0;
    __syncthreads();
    const int e0 = s * SL;
    const int e1 = min(e0 + SL, E);
    for (int e = e0 + t; e < e1; e += 256) {
        unsigned v = (unsigned)(dst[e] - base);
        if (v < HR_RANGE) atomicAdd(&h[v], 1);
    }
    __syncthreads();
    int* Hp = H + (size_t)(r * HR_S + s) * HR_RANGE;
    for (int i = t; i < HR_RANGE; i += 256) Hp[i] = h[i];
}

// per-bin: exclusive prefix over slices in place; total -> cnt_dst
__global__ __launch_bounds__(256) void dsthist_scan_kernel(int* __restrict__ Hpart,
        int* __restrict__ cnt_dst, int N) {
    int n = blockIdx.x * 256 + threadIdx.x;
    if (n >= N) return;
    int r = n / HR_RANGE;
    int local = n - r * HR_RANGE;
    int* Hp = Hpart + (size_t)r * HR_S * HR_RANGE + local;
    int run = 0;
    for (int s = 0; s < HR_S; ++s) {
        int v = Hp[(size_t)s * HR_RANGE];
        Hp[(size_t)s * HR_RANGE] = run;
        run += v;
    }
    cnt_dst[n] = run;
}

__global__ void norm_kernel(const int* __restrict__ cs, const int* __restrict__ cd,
                            float* __restrict__ nout, float* __restrict__ nin, int N) {
    int i = blockIdx.x * blockDim.x + threadIdx.x;
    if (i < N) {
        int a = cs[i]; nout[i] = a > 0 ? rsqrtf((float)a) : 0.f;
        int b = cd[i]; nin[i]  = b > 0 ? rsqrtf((float)b) : 0.f;
    }
}

// ---------------- parallel 3-phase exclusive scan: cnt_dst -> rowstart ----------------
__global__ __launch_bounds__(256) void scan_blocks_kernel(const int* __restrict__ deg,
        int* __restrict__ rowstart, int* __restrict__ bsum, int N) {
    __shared__ int sh[256];
    const int b = blockIdx.x, t = threadIdx.x;
    const int base = b * 1024 + t * 4;
    int v0 = (base + 0 < N) ? deg[base + 0] : 0;
    int v1 = (base + 1 < N) ? deg[base + 1] : 0;
    int v2 = (base + 2 < N) ? deg[base + 2] : 0;
    int v3 = (base + 3 < N) ? deg[base + 3] : 0;
    sh[t] = v0 + v1 + v2 + v3;
    __syncthreads();
    for (int off = 1; off < 256; off <<= 1) {
        int x = (t >= off) ? sh[t - off] : 0;
        __syncthreads();
        sh[t] += x;
        __syncthreads();
    }
    if (t == 255) bsum[b] = sh[255];
    int run = (t == 0) ? 0 : sh[t - 1];
    if (base + 0 < N) { rowstart[base + 0] = run; run += v0; }
    if (base + 1 < N) { rowstart[base + 1] = run; run += v1; }
    if (base + 2 < N) { rowstart[base + 2] = run; run += v2; }
    if (base + 3 < N) { rowstart[base + 3] = run; }
}

__global__ __launch_bounds__(1024) void scan_bsums_kernel(int* __restrict__ bsum, int NB) {
    __shared__ int sh[1024];
    const int t = threadIdx.x;
    int v = (t < NB) ? bsum[t] : 0;
    sh[t] = v;
    __syncthreads();
    for (int off = 1; off < 1024; off <<= 1) {
        int x = (t >= off) ? sh[t - off] : 0;
        __syncthreads();
        sh[t] += x;
        __syncthreads();
    }
    if (t < NB) bsum[t] = sh[t] - v;   // exclusive
}

__global__ __launch_bounds__(256) void scan_add_kernel(int* __restrict__ rowstart,
        const int* __restrict__ bsum, int N) {
    const int b = blockIdx.x;
    if (b == 0) return;
    const int t = threadIdx.x;
    const int off = bsum[b];
    const int base = b * 1024 + t * 4;
    if (base + 0 < N) rowstart[base + 0] += off;
    if (base + 1 < N) rowstart[base + 1] += off;
    if (base + 2 < N) rowstart[base + 2] += off;
    if (base + 3 < N) rowstart[base + 3] += off;
}

// ---------------- fillp: LDS counting-sort scatter (no global atomics) ----------------
// h[bin] seeded with rowstart[bin] + slice-base; atomicAdd on LDS gives global slot.
__global__ __launch_bounds__(256) void fillp_kernel(const int* __restrict__ src,
        const int* __restrict__ dst, const int* __restrict__ rowstart,
        const int* __restrict__ Hpart, int* __restrict__ esrc, int E, int N, int SL) {
    __shared__ int h[HR_RANGE];
    const int t = threadIdx.x;
    const int r = blockIdx.x / HR_S;
    const int s = blockIdx.x % HR_S;
    const int base = r * HR_RANGE;
    const int* Hp = Hpart + (size_t)(r * HR_S + s) * HR_RANGE;
    for (int i = t; i < HR_RANGE; i += 256) {
        int rs = (base + i < N) ? rowstart[base + i] : 0;
        h[i] = rs + Hp[i];
    }
    __syncthreads();
    const int e0 = s * SL;
    const int e1 = min(e0 + SL, E);
    for (int e = e0 + t; e < e1; e += 256) {
        int d = dst[e];
        unsigned v = (unsigned)(d - base);
        if (v < HR_RANGE) {
            int pos = atomicAdd(&h[v], 1);
            esrc[pos] = src[e];
        }
    }
}

// ---------------- GEMM: H[N,OUT] = (X * rowscale) @ W[128,OUT], bf16 out ----------------

__device__ inline void fma4(float4& a, float s, const float4& w) {
    a.x = fmaf(s, w.x, a.x);
    a.y = fmaf(s, w.y, a.y);
    a.z = fmaf(s, w.z, a.z);
    a.w = fmaf(s, w.w, a.w);
}

__device__ inline uint2 pack_bf16x4(float4 a) {
    __hip_bfloat162 lo = __float22bfloat162_rn(make_float2(a.x, a.y));
    __hip_bfloat162 hi = __float22bfloat162_rn(make_float2(a.z, a.w));
    uint2 r;
    r.x = *reinterpret_cast<unsigned*>(&lo);
    r.y = *reinterpret_cast<unsigned*>(&hi);
    return r;
}

template<int OUT, int RPB>
__global__ __launch_bounds__(256) void gemm_kernel(const float* __restrict__ X,
        const float* __restrict__ rowscale,   // may be null
        const float* __restrict__ W,
        unsigned short* __restrict__ H,       // bf16 out, row stride OUT
        int N) {
    constexpr int CQ = OUT / 4;
    constexpr int BK = 32;
    static_assert(RPB == 4 * (256 / CQ), "rows per block mismatch");

    __shared__ float sW[BK * OUT];
    __shared__ float sX[RPB][INF + 4];

    const int tid = threadIdx.x;
    const int row0 = blockIdx.x * RPB;

    for (int i = tid; i < RPB * (INF / 4); i += 256) {
        int r  = i >> 5;
        int kc = i & 31;
        int gr = row0 + r;
        float4 v = make_float4(0.f, 0.f, 0.f, 0.f);
        if (gr < N) {
            v = reinterpret_cast<const float4*>(X)[(size_t)gr * 32 + kc];
            if (rowscale) {
                float s = rowscale[gr];
                v.x *= s; v.y *= s; v.z *= s; v.w *= s;
            }
        }
        *reinterpret_cast<float4*>(&sX[r][kc * 4]) = v;
    }

    const int cq = tid % CQ;
    const int rp = tid / CQ;
    const int r0 = rp * 4;

    float4 acc0 = make_float4(0.f, 0.f, 0.f, 0.f);
    float4 acc1 = make_float4(0.f, 0.f, 0.f, 0.f);
    float4 acc2 = make_float4(0.f, 0.f, 0.f, 0.f);
    float4 acc3 = make_float4(0.f, 0.f, 0.f, 0.f);

    for (int kt = 0; kt < INF / BK; ++kt) {
        __syncthreads();
        for (int i = tid; i < BK * CQ; i += 256)
            reinterpret_cast<float4*>(sW)[i] =
                reinterpret_cast<const float4*>(W)[kt * BK * CQ + i];
        __syncthreads();

        #pragma unroll 2
        for (int k4 = 0; k4 < BK / 4; ++k4) {
            const int kk = kt * BK + k4 * 4;
            float4 xa = *reinterpret_cast<const float4*>(&sX[r0 + 0][kk]);
            float4 xb = *reinterpret_cast<const float4*>(&sX[r0 + 1][kk]);
            float4 xc = *reinterpret_cast<const float4*>(&sX[r0 + 2][kk]);
            float4 xd = *reinterpret_cast<const float4*>(&sX[r0 + 3][kk]);
            const float4* wr = reinterpret_cast<const float4*>(sW + (k4 * 4) * OUT) + cq;
            float4 w0 = wr[0];
            float4 w1 = wr[CQ];
            float4 w2 = wr[2 * CQ];
            float4 w3 = wr[3 * CQ];
            fma4(acc0, xa.x, w0); fma4(acc0, xa.y, w1); fma4(acc0, xa.z, w2); fma4(acc0, xa.w, w3);
            fma4(acc1, xb.x, w0); fma4(acc1, xb.y, w1); fma4(acc1, xb.z, w2); fma4(acc1, xb.w, w3);
            fma4(acc2, xc.x, w0); fma4(acc2, xc.y, w1); fma4(acc2, xc.z, w2); fma4(acc2, xc.w, w3);
            fma4(acc3, xd.x, w0); fma4(acc3, xd.y, w1); fma4(acc3, xd.z, w2); fma4(acc3, xd.w, w3);
        }
    }

    uint2* Hb = reinterpret_cast<uint2*>(H);
    if (row0 + r0 + 0 < N) Hb[(size_t)(row0 + r0 + 0) * CQ + cq] = pack_bf16x4(acc0);
    if (row0 + r0 + 1 < N) Hb[(size_t)(row0 + r0 + 1) * CQ + cq] = pack_bf16x4(acc1);
    if (row0 + r0 + 2 < N) Hb[(size_t)(row0 + r0 + 2) * CQ + cq] = pack_bf16x4(acc2);
    if (row0 + r0 + 3 < N) Hb[(size_t)(row0 + r0 + 3) * CQ + cq] = pack_bf16x4(acc3);
}

// ---------------- CSR gather-aggregate: shfl-prefetched indices, 4-way MLP ----------------

__global__ __launch_bounds__(256) void agg128_kernel(const __hip_bfloat162* __restrict__ H,
        const int* __restrict__ esrc, const int* __restrict__ rowstart,
        const int* __restrict__ cnt,
        const float* __restrict__ nin, const float* __restrict__ bias,
        const float* __restrict__ nout, float* __restrict__ out, int N) {
    int wid  = (blockIdx.x * 256 + threadIdx.x) >> 6;
    int lane = threadIdx.x & 63;
    if (wid >= N) return;
    int beg = rowstart[wid];
    int cw  = cnt[wid];
    float2 a0 = make_float2(0.f, 0.f), a1 = make_float2(0.f, 0.f);
    float2 a2 = make_float2(0.f, 0.f), a3 = make_float2(0.f, 0.f);
    for (int j0 = 0; j0 < cw; j0 += 64) {
        int m = min(64, cw - j0);
        int idx = (lane < m) ? esrc[beg + j0 + lane] : 0;
        int jj = 0;
        for (; jj + 4 <= m; jj += 4) {
            int s0 = __shfl(idx, jj + 0);
            int s1 = __shfl(idx, jj + 1);
            int s2 = __shfl(idx, jj + 2);
            int s3 = __shfl(idx, jj + 3);
            float2 v0 = __bfloat1622float2(H[(size_t)s0 * 64 + lane]);
            float2 v1 = __bfloat1622float2(H[(size_t)s1 * 64 + lane]);
            float2 v2 = __bfloat1622float2(H[(size_t)s2 * 64 + lane]);
            float2 v3 = __bfloat1622float2(H[(size_t)s3 * 64 + lane]);
            a0.x += v0.x; a0.y += v0.y;
            a1.x += v1.x; a1.y += v1.y;
            a2.x += v2.x; a2.y += v2.y;
            a3.x += v3.x; a3.y += v3.y;
        }
        for (; jj < m; ++jj) {
            int s0 = __shfl(idx, jj);
            float2 v0 = __bfloat1622float2(H[(size_t)s0 * 64 + lane]);
            a0.x += v0.x; a0.y += v0.y;
        }
    }
    a0.x += a1.x + a2.x + a3.x;
    a0.y += a1.y + a2.y + a3.y;
    float s = nin[wid];
    float2 b = ((const float2*)bias)[lane];
    float r0 = fmaxf(fmaf(a0.x, s, b.x), 0.f);
    float r1 = fmaxf(fmaf(a0.y, s, b.y), 0.f);
    float t = nout[wid];
    r0 *= t; r1 *= t;
    ((float2*)out)[(size_t)wid * 64 + lane] = make_float2(r0, r1);
}

__global__ __launch_bounds__(256) void agg64_kernel(const __hip_bfloat16* __restrict__ H,
        const int* __restrict__ esrc, const int* __restrict__ rowstart,
        const int* __restrict__ cnt,
        const float* __restrict__ nin, const float* __restrict__ bias,
        float* __restrict__ out, int N) {
    int wid  = (blockIdx.x * 256 + threadIdx.x) >> 6;
    int lane = threadIdx.x & 63;
    if (wid >= N) return;
    int beg = rowstart[wid];
    int cw  = cnt[wid];
    float a0 = 0.f, a1 = 0.f, a2 = 0.f, a3 = 0.f;
    for (int j0 = 0; j0 < cw; j0 += 64) {
        int m = min(64, cw - j0);
        int idx = (lane < m) ? esrc[beg + j0 + lane] : 0;
        int jj = 0;
        for (; jj + 4 <= m; jj += 4) {
            int s0 = __shfl(idx, jj + 0);
            int s1 = __shfl(idx, jj + 1);
            int s2 = __shfl(idx, jj + 2);
            int s3 = __shfl(idx, jj + 3);
            a0 += __bfloat162float(H[(size_t)s0 * 64 + lane]);
            a1 += __bfloat162float(H[(size_t)s1 * 64 + lane]);
            a2 += __bfloat162float(H[(size_t)s2 * 64 + lane]);
            a3 += __bfloat162float(H[(size_t)s3 * 64 + lane]);
        }
        for (; jj < m; ++jj) {
            int s0 = __shfl(idx, jj);
            a0 += __bfloat162float(H[(size_t)s0 * 64 + lane]);
        }
    }
    float acc = (a0 + a1) + (a2 + a3);
    float r = fmaxf(fmaf(acc, nin[wid], bias[lane]), 0.f);
    out[(size_t)wid * 64 + lane] = r;
}

// ---------------- launch ----------------

extern "C" void kernel_launch(void* const* d_in, const int* in_sizes, int n_in,
                              void* d_out, int out_size, void* d_ws, size_t ws_size,
                              hipStream_t stream) {
    const float* x  = (const float*)d_in[0];
    const float* W1 = (const float*)d_in[1];
    const float* b1 = (const float*)d_in[2];
    const float* W2 = (const float*)d_in[3];
    const float* b2 = (const float*)d_in[4];
    const int*   src = (const int*)d_in[5];
    const int*   dst = (const int*)d_in[6];

    const int N = in_sizes[0] / INF;   // 100000
    const int E = in_sizes[5];         // 1600000

    char* ws = (char*)d_ws;
    const size_t padN   = (((size_t)N * 4 + 255) / 256) * 256;
    const size_t padE   = (((size_t)E * 4 + 255) / 256) * 256;
    const size_t padAbf = (((size_t)N * INF * 2 + 255) / 256) * 256;   // bf16 N x 128

    float* out = (float*)d_out;

    int*   cnt_src  = (int*)  (ws);
    int*   cnt_dst  = (int*)  (ws + padN);
    int*   rowstart = (int*)  (ws + 2 * padN);
    float* nout     = (float*)(ws + 3 * padN);
    float* nin      = (float*)(ws + 4 * padN);
    int*   bsum     = (int*)  (ws + 5 * padN);
    int*   esrc     = (int*)  (ws + 6 * padN);
    unsigned short* Abf = (unsigned short*)(ws + 6 * padN + padE);     // bf16 h
    float* B        = (float*)(ws + 6 * padN + padE + padAbf);         // fp32 layer1 out

    // overlays (stream-ordered lifetimes):
    //  Hpart_src @ Abf: 28.7MB (spills ~3.1MB into B head) — dead before gemm1
    //  Hpart_dst @ B+4MB: 28.7MB — last read by fillp, before agg128 writes B
    int* Hpart_src = (int*)Abf;
    int* Hpart_dst = (int*)((char*)B + (size_t)4 * 1024 * 1024);

    const int NR  = (N + HR_RANGE - 1) / HR_RANGE;        // node ranges (7)
    const int NB  = (N + 1023) / 1024;
    const int SL  = (E + HR_S - 1) / HR_S;                // edges per slice

    // degree histograms via LDS partials (zero global atomics)
    srchist_partial_kernel<<<NR * HR_S, 256, 0, stream>>>(src, Hpart_src, E, SL);
    srchist_merge_kernel<<<(N + 255) / 256, 256, 0, stream>>>(Hpart_src, cnt_src, N);
    dsthist_partial_kernel<<<NR * HR_S, 256, 0, stream>>>(dst, Hpart_dst, E, SL);
    dsthist_scan_kernel<<<(N + 255) / 256, 256, 0, stream>>>(Hpart_dst, cnt_dst, N);

    // rowstart = exclusive scan of cnt_dst
    scan_blocks_kernel<<<NB, 256, 0, stream>>>(cnt_dst, rowstart, bsum, N);
    scan_bsums_kernel<<<1, 1024, 0, stream>>>(bsum, NB);
    scan_add_kernel<<<NB, 256, 0, stream>>>(rowstart, bsum, N);

    norm_kernel<<<(N + 255) / 256, 256, 0, stream>>>(cnt_src, cnt_dst, nout, nin, N);

    // dst-sorted edge fill via LDS counting sort
    fillp_kernel<<<NR * HR_S, 256, 0, stream>>>(src, dst, rowstart, Hpart_dst, esrc, E, N, SL);

    // layer 1: Abf = bf16((x*nout) @ W1) ; B = relu(csr_sum(Abf)*nin + b1) * nout
    gemm_kernel<128, 32><<<(N + 31) / 32, 256, 0, stream>>>(x, nout, W1, Abf, N);
    agg128_kernel<<<(N * 64 + 255) / 256, 256, 0, stream>>>(
        (const __hip_bfloat162*)Abf, esrc, rowstart, cnt_dst, nin, b1, nout, B, N);

    // layer 2: Abf = bf16(B @ W2) ; out = relu(csr_sum(Abf)*nin + b2)
    gemm_kernel<64, 64><<<(N + 63) / 64, 256, 0, stream>>>(B, nullptr, W2, Abf, N);
    agg64_kernel<<<(N * 64 + 255) / 256, 256, 0, stream>>>(
        (const __hip_bfloat16*)Abf, esrc, rowstart, cnt_dst, nin, b2, out, N);
}

// Round 12
// 311.294 us; speedup vs baseline: 17.7438x; 1.2231x over previous
//
#include <hip/hip_runtime.h>
#include <hip/hip_bf16.h>

#define INF 128
#define HF 64

// node-range / edge-slice partition for LDS histograms
#define HR_RANGE 8192      // nodes per range -> 32 KB LDS (4-5 blocks/CU)
#define HR_S     64        // edge slices

// ---------------- generic key histogram partials (no global atomics) ----------------
__global__ __launch_bounds__(256) void hist_partial_kernel(const int* __restrict__ key,
        int* __restrict__ H, int E, int SL) {
    __shared__ int h[HR_RANGE];
    const int t = threadIdx.x;
    const int r = blockIdx.x / HR_S;
    const int s = blockIdx.x % HR_S;
    const int base = r * HR_RANGE;
    for (int i = t; i < HR_RANGE; i += 256) h[i] = 0;
    __syncthreads();
    const int e0 = s * SL;
    const int e1 = min(e0 + SL, E);
    const int nq = (e1 > e0) ? (e1 - e0) >> 2 : 0;   // complete int4 groups
    for (int g = t; g < nq; g += 256) {
        int4 k4 = *reinterpret_cast<const int4*>(key + e0 + 4 * g);
        unsigned v0 = (unsigned)(k4.x - base);
        unsigned v1 = (unsigned)(k4.y - base);
        unsigned v2 = (unsigned)(k4.z - base);
        unsigned v3 = (unsigned)(k4.w - base);
        if (v0 < HR_RANGE) atomicAdd(&h[v0], 1);
        if (v1 < HR_RANGE) atomicAdd(&h[v1], 1);
        if (v2 < HR_RANGE) atomicAdd(&h[v2], 1);
        if (v3 < HR_RANGE) atomicAdd(&h[v3], 1);
    }
    for (int e = e0 + 4 * nq + t; e < e1; e += 256) {   // tail (none when SL%4==0)
        unsigned v = (unsigned)(key[e] - base);
        if (v < HR_RANGE) atomicAdd(&h[v], 1);
    }
    __syncthreads();
    int* Hp = H + (size_t)(r * HR_S + s) * HR_RANGE;
    for (int i = t; i < HR_RANGE; i += 256) Hp[i] = h[i];
}

__global__ __launch_bounds__(256) void srchist_merge_kernel(const int* __restrict__ H,
        int* __restrict__ cnt_src, int N) {
    int bin = blockIdx.x * 256 + threadIdx.x;
    if (bin >= N) return;
    int r = bin / HR_RANGE;
    int local = bin - r * HR_RANGE;
    const int* Hp = H + (size_t)r * HR_S * HR_RANGE + local;
    int sum = 0;
    #pragma unroll 8
    for (int s = 0; s < HR_S; ++s) sum += Hp[(size_t)s * HR_RANGE];
    cnt_src[bin] = sum;
}

// per-bin: exclusive prefix over slices in place; total -> cnt_dst
__global__ __launch_bounds__(256) void dsthist_scan_kernel(int* __restrict__ Hpart,
        int* __restrict__ cnt_dst, int N) {
    int n = blockIdx.x * 256 + threadIdx.x;
    if (n >= N) return;
    int r = n / HR_RANGE;
    int local = n - r * HR_RANGE;
    int* Hp = Hpart + (size_t)r * HR_S * HR_RANGE + local;
    int run = 0;
    for (int s = 0; s < HR_S; ++s) {
        int v = Hp[(size_t)s * HR_RANGE];
        Hp[(size_t)s * HR_RANGE] = run;
        run += v;
    }
    cnt_dst[n] = run;
}

__global__ void norm_kernel(const int* __restrict__ cs, const int* __restrict__ cd,
                            float* __restrict__ nout, float* __restrict__ nin, int N) {
    int i = blockIdx.x * blockDim.x + threadIdx.x;
    if (i < N) {
        int a = cs[i]; nout[i] = a > 0 ? rsqrtf((float)a) : 0.f;
        int b = cd[i]; nin[i]  = b > 0 ? rsqrtf((float)b) : 0.f;
    }
}

// ---------------- parallel 3-phase exclusive scan: cnt_dst -> rowstart ----------------
__global__ __launch_bounds__(256) void scan_blocks_kernel(const int* __restrict__ deg,
        int* __restrict__ rowstart, int* __restrict__ bsum, int N) {
    __shared__ int sh[256];
    const int b = blockIdx.x, t = threadIdx.x;
    const int base = b * 1024 + t * 4;
    int v0 = (base + 0 < N) ? deg[base + 0] : 0;
    int v1 = (base + 1 < N) ? deg[base + 1] : 0;
    int v2 = (base + 2 < N) ? deg[base + 2] : 0;
    int v3 = (base + 3 < N) ? deg[base + 3] : 0;
    sh[t] = v0 + v1 + v2 + v3;
    __syncthreads();
    for (int off = 1; off < 256; off <<= 1) {
        int x = (t >= off) ? sh[t - off] : 0;
        __syncthreads();
        sh[t] += x;
        __syncthreads();
    }
    if (t == 255) bsum[b] = sh[255];
    int run = (t == 0) ? 0 : sh[t - 1];
    if (base + 0 < N) { rowstart[base + 0] = run; run += v0; }
    if (base + 1 < N) { rowstart[base + 1] = run; run += v1; }
    if (base + 2 < N) { rowstart[base + 2] = run; run += v2; }
    if (base + 3 < N) { rowstart[base + 3] = run; }
}

__global__ __launch_bounds__(1024) void scan_bsums_kernel(int* __restrict__ bsum, int NB) {
    __shared__ int sh[1024];
    const int t = threadIdx.x;
    int v = (t < NB) ? bsum[t] : 0;
    sh[t] = v;
    __syncthreads();
    for (int off = 1; off < 1024; off <<= 1) {
        int x = (t >= off) ? sh[t - off] : 0;
        __syncthreads();
        sh[t] += x;
        __syncthreads();
    }
    if (t < NB) bsum[t] = sh[t] - v;   // exclusive
}

__global__ __launch_bounds__(256) void scan_add_kernel(int* __restrict__ rowstart,
        const int* __restrict__ bsum, int N) {
    const int b = blockIdx.x;
    if (b == 0) return;
    const int t = threadIdx.x;
    const int off = bsum[b];
    const int base = b * 1024 + t * 4;
    if (base + 0 < N) rowstart[base + 0] += off;
    if (base + 1 < N) rowstart[base + 1] += off;
    if (base + 2 < N) rowstart[base + 2] += off;
    if (base + 3 < N) rowstart[base + 3] += off;
}

// ---------------- fillp: LDS counting-sort scatter (no global atomics) ----------------
__global__ __launch_bounds__(256) void fillp_kernel(const int* __restrict__ src,
        const int* __restrict__ dst, const int* __restrict__ rowstart,
        const int* __restrict__ Hpart, int* __restrict__ esrc, int E, int N, int SL) {
    __shared__ int h[HR_RANGE];
    const int t = threadIdx.x;
    const int r = blockIdx.x / HR_S;
    const int s = blockIdx.x % HR_S;
    const int base = r * HR_RANGE;
    const int* Hp = Hpart + (size_t)(r * HR_S + s) * HR_RANGE;
    for (int i = t; i < HR_RANGE; i += 256) {
        int rs = (base + i < N) ? rowstart[base + i] : 0;
        h[i] = rs + Hp[i];
    }
    __syncthreads();
    const int e0 = s * SL;
    const int e1 = min(e0 + SL, E);
    const int nq = (e1 > e0) ? (e1 - e0) >> 2 : 0;
    for (int g = t; g < nq; g += 256) {
        const int e = e0 + 4 * g;
        int4 d4 = *reinterpret_cast<const int4*>(dst + e);
        int4 s4 = *reinterpret_cast<const int4*>(src + e);
        unsigned v0 = (unsigned)(d4.x - base);
        unsigned v1 = (unsigned)(d4.y - base);
        unsigned v2 = (unsigned)(d4.z - base);
        unsigned v3 = (unsigned)(d4.w - base);
        if (v0 < HR_RANGE) esrc[atomicAdd(&h[v0], 1)] = s4.x;
        if (v1 < HR_RANGE) esrc[atomicAdd(&h[v1], 1)] = s4.y;
        if (v2 < HR_RANGE) esrc[atomicAdd(&h[v2], 1)] = s4.z;
        if (v3 < HR_RANGE) esrc[atomicAdd(&h[v3], 1)] = s4.w;
    }
    for (int e = e0 + 4 * nq + t; e < e1; e += 256) {   // tail
        unsigned v = (unsigned)(dst[e] - base);
        if (v < HR_RANGE) esrc[atomicAdd(&h[v], 1)] = src[e];
    }
}

// ---------------- GEMM: H[N,OUT] = (X * rowscale) @ W[128,OUT], bf16 out ----------------

__device__ inline void fma4(float4& a, float s, const float4& w) {
    a.x = fmaf(s, w.x, a.x);
    a.y = fmaf(s, w.y, a.y);
    a.z = fmaf(s, w.z, a.z);
    a.w = fmaf(s, w.w, a.w);
}

__device__ inline uint2 pack_bf16x4(float4 a) {
    __hip_bfloat162 lo = __float22bfloat162_rn(make_float2(a.x, a.y));
    __hip_bfloat162 hi = __float22bfloat162_rn(make_float2(a.z, a.w));
    uint2 r;
    r.x = *reinterpret_cast<unsigned*>(&lo);
    r.y = *reinterpret_cast<unsigned*>(&hi);
    return r;
}

template<int OUT, int RPB>
__global__ __launch_bounds__(256) void gemm_kernel(const float* __restrict__ X,
        const float* __restrict__ rowscale,   // may be null
        const float* __restrict__ W,
        unsigned short* __restrict__ H,       // bf16 out, row stride OUT
        int N) {
    constexpr int CQ = OUT / 4;
    constexpr int BK = 32;
    static_assert(RPB == 4 * (256 / CQ), "rows per block mismatch");

    __shared__ float sW[BK * OUT];
    __shared__ float sX[RPB][INF + 4];

    const int tid = threadIdx.x;
    const int row0 = blockIdx.x * RPB;

    for (int i = tid; i < RPB * (INF / 4); i += 256) {
        int r  = i >> 5;
        int kc = i & 31;
        int gr = row0 + r;
        float4 v = make_float4(0.f, 0.f, 0.f, 0.f);
        if (gr < N) {
            v = reinterpret_cast<const float4*>(X)[(size_t)gr * 32 + kc];
            if (rowscale) {
                float s = rowscale[gr];
                v.x *= s; v.y *= s; v.z *= s; v.w *= s;
            }
        }
        *reinterpret_cast<float4*>(&sX[r][kc * 4]) = v;
    }

    const int cq = tid % CQ;
    const int rp = tid / CQ;
    const int r0 = rp * 4;

    float4 acc0 = make_float4(0.f, 0.f, 0.f, 0.f);
    float4 acc1 = make_float4(0.f, 0.f, 0.f, 0.f);
    float4 acc2 = make_float4(0.f, 0.f, 0.f, 0.f);
    float4 acc3 = make_float4(0.f, 0.f, 0.f, 0.f);

    for (int kt = 0; kt < INF / BK; ++kt) {
        __syncthreads();
        for (int i = tid; i < BK * CQ; i += 256)
            reinterpret_cast<float4*>(sW)[i] =
                reinterpret_cast<const float4*>(W)[kt * BK * CQ + i];
        __syncthreads();

        #pragma unroll 2
        for (int k4 = 0; k4 < BK / 4; ++k4) {
            const int kk = kt * BK + k4 * 4;
            float4 xa = *reinterpret_cast<const float4*>(&sX[r0 + 0][kk]);
            float4 xb = *reinterpret_cast<const float4*>(&sX[r0 + 1][kk]);
            float4 xc = *reinterpret_cast<const float4*>(&sX[r0 + 2][kk]);
            float4 xd = *reinterpret_cast<const float4*>(&sX[r0 + 3][kk]);
            const float4* wr = reinterpret_cast<const float4*>(sW + (k4 * 4) * OUT) + cq;
            float4 w0 = wr[0];
            float4 w1 = wr[CQ];
            float4 w2 = wr[2 * CQ];
            float4 w3 = wr[3 * CQ];
            fma4(acc0, xa.x, w0); fma4(acc0, xa.y, w1); fma4(acc0, xa.z, w2); fma4(acc0, xa.w, w3);
            fma4(acc1, xb.x, w0); fma4(acc1, xb.y, w1); fma4(acc1, xb.z, w2); fma4(acc1, xb.w, w3);
            fma4(acc2, xc.x, w0); fma4(acc2, xc.y, w1); fma4(acc2, xc.z, w2); fma4(acc2, xc.w, w3);
            fma4(acc3, xd.x, w0); fma4(acc3, xd.y, w1); fma4(acc3, xd.z, w2); fma4(acc3, xd.w, w3);
        }
    }

    uint2* Hb = reinterpret_cast<uint2*>(H);
    if (row0 + r0 + 0 < N) Hb[(size_t)(row0 + r0 + 0) * CQ + cq] = pack_bf16x4(acc0);
    if (row0 + r0 + 1 < N) Hb[(size_t)(row0 + r0 + 1) * CQ + cq] = pack_bf16x4(acc1);
    if (row0 + r0 + 2 < N) Hb[(size_t)(row0 + r0 + 2) * CQ + cq] = pack_bf16x4(acc2);
    if (row0 + r0 + 3 < N) Hb[(size_t)(row0 + r0 + 3) * CQ + cq] = pack_bf16x4(acc3);
}

// ---------------- CSR gather-aggregate: shfl-prefetched indices, 4-way MLP ----------------

__global__ __launch_bounds__(256) void agg128_kernel(const __hip_bfloat162* __restrict__ H,
        const int* __restrict__ esrc, const int* __restrict__ rowstart,
        const int* __restrict__ cnt,
        const float* __restrict__ nin, const float* __restrict__ bias,
        const float* __restrict__ nout, float* __restrict__ out, int N) {
    int wid  = (blockIdx.x * 256 + threadIdx.x) >> 6;
    int lane = threadIdx.x & 63;
    if (wid >= N) return;
    int beg = rowstart[wid];
    int cw  = cnt[wid];
    float2 a0 = make_float2(0.f, 0.f), a1 = make_float2(0.f, 0.f);
    float2 a2 = make_float2(0.f, 0.f), a3 = make_float2(0.f, 0.f);
    for (int j0 = 0; j0 < cw; j0 += 64) {
        int m = min(64, cw - j0);
        int idx = (lane < m) ? esrc[beg + j0 + lane] : 0;
        int jj = 0;
        for (; jj + 4 <= m; jj += 4) {
            int s0 = __shfl(idx, jj + 0);
            int s1 = __shfl(idx, jj + 1);
            int s2 = __shfl(idx, jj + 2);
            int s3 = __shfl(idx, jj + 3);
            float2 v0 = __bfloat1622float2(H[(size_t)s0 * 64 + lane]);
            float2 v1 = __bfloat1622float2(H[(size_t)s1 * 64 + lane]);
            float2 v2 = __bfloat1622float2(H[(size_t)s2 * 64 + lane]);
            float2 v3 = __bfloat1622float2(H[(size_t)s3 * 64 + lane]);
            a0.x += v0.x; a0.y += v0.y;
            a1.x += v1.x; a1.y += v1.y;
            a2.x += v2.x; a2.y += v2.y;
            a3.x += v3.x; a3.y += v3.y;
        }
        for (; jj < m; ++jj) {
            int s0 = __shfl(idx, jj);
            float2 v0 = __bfloat1622float2(H[(size_t)s0 * 64 + lane]);
            a0.x += v0.x; a0.y += v0.y;
        }
    }
    a0.x += a1.x + a2.x + a3.x;
    a0.y += a1.y + a2.y + a3.y;
    float s = nin[wid];
    float2 b = ((const float2*)bias)[lane];
    float r0 = fmaxf(fmaf(a0.x, s, b.x), 0.f);
    float r1 = fmaxf(fmaf(a0.y, s, b.y), 0.f);
    float t = nout[wid];
    r0 *= t; r1 *= t;
    ((float2*)out)[(size_t)wid * 64 + lane] = make_float2(r0, r1);
}

__global__ __launch_bounds__(256) void agg64_kernel(const __hip_bfloat16* __restrict__ H,
        const int* __restrict__ esrc, const int* __restrict__ rowstart,
        const int* __restrict__ cnt,
        const float* __restrict__ nin, const float* __restrict__ bias,
        float* __restrict__ out, int N) {
    int wid  = (blockIdx.x * 256 + threadIdx.x) >> 6;
    int lane = threadIdx.x & 63;
    if (wid >= N) return;
    int beg = rowstart[wid];
    int cw  = cnt[wid];
    float a0 = 0.f, a1 = 0.f, a2 = 0.f, a3 = 0.f;
    for (int j0 = 0; j0 < cw; j0 += 64) {
        int m = min(64, cw - j0);
        int idx = (lane < m) ? esrc[beg + j0 + lane] : 0;
        int jj = 0;
        for (; jj + 4 <= m; jj += 4) {
            int s0 = __shfl(idx, jj + 0);
            int s1 = __shfl(idx, jj + 1);
            int s2 = __shfl(idx, jj + 2);
            int s3 = __shfl(idx, jj + 3);
            a0 += __bfloat162float(H[(size_t)s0 * 64 + lane]);
            a1 += __bfloat162float(H[(size_t)s1 * 64 + lane]);
            a2 += __bfloat162float(H[(size_t)s2 * 64 + lane]);
            a3 += __bfloat162float(H[(size_t)s3 * 64 + lane]);
        }
        for (; jj < m; ++jj) {
            int s0 = __shfl(idx, jj);
            a0 += __bfloat162float(H[(size_t)s0 * 64 + lane]);
        }
    }
    float acc = (a0 + a1) + (a2 + a3);
    float r = fmaxf(fmaf(acc, nin[wid], bias[lane]), 0.f);
    out[(size_t)wid * 64 + lane] = r;
}

// ---------------- launch ----------------

extern "C" void kernel_launch(void* const* d_in, const int* in_sizes, int n_in,
                              void* d_out, int out_size, void* d_ws, size_t ws_size,
                              hipStream_t stream) {
    const float* x  = (const float*)d_in[0];
    const float* W1 = (const float*)d_in[1];
    const float* b1 = (const float*)d_in[2];
    const float* W2 = (const float*)d_in[3];
    const float* b2 = (const float*)d_in[4];
    const int*   src = (const int*)d_in[5];
    const int*   dst = (const int*)d_in[6];

    const int N = in_sizes[0] / INF;   // 100000
    const int E = in_sizes[5];         // 1600000

    char* ws = (char*)d_ws;
    const size_t padN   = (((size_t)N * 4 + 255) / 256) * 256;
    const size_t padE   = (((size_t)E * 4 + 255) / 256) * 256;
    const size_t padAbf = (((size_t)N * INF * 2 + 255) / 256) * 256;   // bf16 N x 128

    float* out = (float*)d_out;

    int*   cnt_src  = (int*)  (ws);
    int*   cnt_dst  = (int*)  (ws + padN);
    int*   rowstart = (int*)  (ws + 2 * padN);
    float* nout     = (float*)(ws + 3 * padN);
    float* nin      = (float*)(ws + 4 * padN);
    int*   bsum     = (int*)  (ws + 5 * padN);
    int*   esrc     = (int*)  (ws + 6 * padN);
    unsigned short* Abf = (unsigned short*)(ws + 6 * padN + padE);     // bf16 h
    float* B        = (float*)(ws + 6 * padN + padE + padAbf);         // fp32 layer1 out

    // overlays (stream-ordered lifetimes):
    //  Hpart_src @ Abf: 26MB (spills ~0.4MB into B head) — dead before gemm1
    //  Hpart_dst @ B+4MB: 26MB — last read by fillp, before agg128 writes B
    int* Hpart_src = (int*)Abf;
    int* Hpart_dst = (int*)((char*)B + (size_t)4 * 1024 * 1024);

    const int NR  = (N + HR_RANGE - 1) / HR_RANGE;            // node ranges (13)
    const int NB  = (N + 1023) / 1024;
    const int SL  = ((((E + HR_S - 1) / HR_S) + 3) / 4) * 4;  // edges per slice, mult of 4

    // degree histograms via LDS partials (zero global atomics)
    hist_partial_kernel<<<NR * HR_S, 256, 0, stream>>>(src, Hpart_src, E, SL);
    srchist_merge_kernel<<<(N + 255) / 256, 256, 0, stream>>>(Hpart_src, cnt_src, N);
    hist_partial_kernel<<<NR * HR_S, 256, 0, stream>>>(dst, Hpart_dst, E, SL);
    dsthist_scan_kernel<<<(N + 255) / 256, 256, 0, stream>>>(Hpart_dst, cnt_dst, N);

    // rowstart = exclusive scan of cnt_dst
    scan_blocks_kernel<<<NB, 256, 0, stream>>>(cnt_dst, rowstart, bsum, N);
    scan_bsums_kernel<<<1, 1024, 0, stream>>>(bsum, NB);
    scan_add_kernel<<<NB, 256, 0, stream>>>(rowstart, bsum, N);

    norm_kernel<<<(N + 255) / 256, 256, 0, stream>>>(cnt_src, cnt_dst, nout, nin, N);

    // dst-sorted edge fill via LDS counting sort
    fillp_kernel<<<NR * HR_S, 256, 0, stream>>>(src, dst, rowstart, Hpart_dst, esrc, E, N, SL);

    // layer 1: Abf = bf16((x*nout) @ W1) ; B = relu(csr_sum(Abf)*nin + b1) * nout
    gemm_kernel<128, 32><<<(N + 31) / 32, 256, 0, stream>>>(x, nout, W1, Abf, N);
    agg128_kernel<<<(N * 64 + 255) / 256, 256, 0, stream>>>(
        (const __hip_bfloat162*)Abf, esrc, rowstart, cnt_dst, nin, b1, nout, B, N);

    // layer 2: Abf = bf16(B @ W2) ; out = relu(csr_sum(Abf)*nin + b2)
    gemm_kernel<64, 64><<<(N + 63) / 64, 256, 0, stream>>>(B, nullptr, W2, Abf, N);
    agg64_kernel<<<(N * 64 + 255) / 256, 256, 0, stream>>>(
        (const __hip_bfloat16*)Abf, esrc, rowstart, cnt_dst, nin, b2, out, N);
}

// Round 13
// 264.076 us; speedup vs baseline: 20.9165x; 1.1788x over previous
//
#include <hip/hip_runtime.h>
#include <hip/hip_bf16.h>

#define INF 128
#define HF 64

// node-range / edge-slice partition for LDS histograms
#define HR_RANGE 8192      // nodes per range -> 32 KB LDS
#define HR_S     64        // edge slices

typedef __attribute__((ext_vector_type(8))) short short8v;   // 8 bf16 (4 VGPRs)
typedef __attribute__((ext_vector_type(4))) float f32x4;

__device__ inline unsigned short bf16r(float f) {
    __hip_bfloat16 h = __float2bfloat16(f);
    return *reinterpret_cast<unsigned short*>(&h);
}

// ---------------- generic key histogram partials (no global atomics) ----------------
__global__ __launch_bounds__(256) void hist_partial_kernel(const int* __restrict__ key,
        int* __restrict__ H, int E, int SL) {
    __shared__ int h[HR_RANGE];
    const int t = threadIdx.x;
    const int r = blockIdx.x / HR_S;
    const int s = blockIdx.x % HR_S;
    const int base = r * HR_RANGE;
    for (int i = t; i < HR_RANGE; i += 256) h[i] = 0;
    __syncthreads();
    const int e0 = s * SL;
    const int e1 = min(e0 + SL, E);
    const int nq = (e1 > e0) ? (e1 - e0) >> 2 : 0;
    for (int g = t; g < nq; g += 256) {
        int4 k4 = *reinterpret_cast<const int4*>(key + e0 + 4 * g);
        unsigned v0 = (unsigned)(k4.x - base);
        unsigned v1 = (unsigned)(k4.y - base);
        unsigned v2 = (unsigned)(k4.z - base);
        unsigned v3 = (unsigned)(k4.w - base);
        if (v0 < HR_RANGE) atomicAdd(&h[v0], 1);
        if (v1 < HR_RANGE) atomicAdd(&h[v1], 1);
        if (v2 < HR_RANGE) atomicAdd(&h[v2], 1);
        if (v3 < HR_RANGE) atomicAdd(&h[v3], 1);
    }
    for (int e = e0 + 4 * nq + t; e < e1; e += 256) {
        unsigned v = (unsigned)(key[e] - base);
        if (v < HR_RANGE) atomicAdd(&h[v], 1);
    }
    __syncthreads();
    int* Hp = H + (size_t)(r * HR_S + s) * HR_RANGE;
    for (int i = t; i < HR_RANGE; i += 256) Hp[i] = h[i];
}

__global__ __launch_bounds__(256) void srchist_merge_kernel(const int* __restrict__ H,
        int* __restrict__ cnt_src, int N) {
    int bin = blockIdx.x * 256 + threadIdx.x;
    if (bin >= N) return;
    int r = bin / HR_RANGE;
    int local = bin - r * HR_RANGE;
    const int* Hp = H + (size_t)r * HR_S * HR_RANGE + local;
    int sum = 0;
    #pragma unroll 8
    for (int s = 0; s < HR_S; ++s) sum += Hp[(size_t)s * HR_RANGE];
    cnt_src[bin] = sum;
}

__global__ __launch_bounds__(256) void dsthist_scan_kernel(int* __restrict__ Hpart,
        int* __restrict__ cnt_dst, int N) {
    int n = blockIdx.x * 256 + threadIdx.x;
    if (n >= N) return;
    int r = n / HR_RANGE;
    int local = n - r * HR_RANGE;
    int* Hp = Hpart + (size_t)r * HR_S * HR_RANGE + local;
    int run = 0;
    for (int s = 0; s < HR_S; ++s) {
        int v = Hp[(size_t)s * HR_RANGE];
        Hp[(size_t)s * HR_RANGE] = run;
        run += v;
    }
    cnt_dst[n] = run;
}

__global__ void norm_kernel(const int* __restrict__ cs, const int* __restrict__ cd,
                            float* __restrict__ nout, float* __restrict__ nin, int N) {
    int i = blockIdx.x * blockDim.x + threadIdx.x;
    if (i < N) {
        int a = cs[i]; nout[i] = a > 0 ? rsqrtf((float)a) : 0.f;
        int b = cd[i]; nin[i]  = b > 0 ? rsqrtf((float)b) : 0.f;
    }
}

// ---------------- parallel 3-phase exclusive scan: cnt_dst -> rowstart ----------------
__global__ __launch_bounds__(256) void scan_blocks_kernel(const int* __restrict__ deg,
        int* __restrict__ rowstart, int* __restrict__ bsum, int N) {
    __shared__ int sh[256];
    const int b = blockIdx.x, t = threadIdx.x;
    const int base = b * 1024 + t * 4;
    int v0 = (base + 0 < N) ? deg[base + 0] : 0;
    int v1 = (base + 1 < N) ? deg[base + 1] : 0;
    int v2 = (base + 2 < N) ? deg[base + 2] : 0;
    int v3 = (base + 3 < N) ? deg[base + 3] : 0;
    sh[t] = v0 + v1 + v2 + v3;
    __syncthreads();
    for (int off = 1; off < 256; off <<= 1) {
        int x = (t >= off) ? sh[t - off] : 0;
        __syncthreads();
        sh[t] += x;
        __syncthreads();
    }
    if (t == 255) bsum[b] = sh[255];
    int run = (t == 0) ? 0 : sh[t - 1];
    if (base + 0 < N) { rowstart[base + 0] = run; run += v0; }
    if (base + 1 < N) { rowstart[base + 1] = run; run += v1; }
    if (base + 2 < N) { rowstart[base + 2] = run; run += v2; }
    if (base + 3 < N) { rowstart[base + 3] = run; }
}

__global__ __launch_bounds__(1024) void scan_bsums_kernel(int* __restrict__ bsum, int NB) {
    __shared__ int sh[1024];
    const int t = threadIdx.x;
    int v = (t < NB) ? bsum[t] : 0;
    sh[t] = v;
    __syncthreads();
    for (int off = 1; off < 1024; off <<= 1) {
        int x = (t >= off) ? sh[t - off] : 0;
        __syncthreads();
        sh[t] += x;
        __syncthreads();
    }
    if (t < NB) bsum[t] = sh[t] - v;   // exclusive
}

__global__ __launch_bounds__(256) void scan_add_kernel(int* __restrict__ rowstart,
        const int* __restrict__ bsum, int N) {
    const int b = blockIdx.x;
    if (b == 0) return;
    const int t = threadIdx.x;
    const int off = bsum[b];
    const int base = b * 1024 + t * 4;
    if (base + 0 < N) rowstart[base + 0] += off;
    if (base + 1 < N) rowstart[base + 1] += off;
    if (base + 2 < N) rowstart[base + 2] += off;
    if (base + 3 < N) rowstart[base + 3] += off;
}

// ---------------- fillp: LDS counting-sort scatter (no global atomics) ----------------
__global__ __launch_bounds__(256) void fillp_kernel(const int* __restrict__ src,
        const int* __restrict__ dst, const int* __restrict__ rowstart,
        const int* __restrict__ Hpart, int* __restrict__ esrc, int E, int N, int SL) {
    __shared__ int h[HR_RANGE];
    const int t = threadIdx.x;
    const int r = blockIdx.x / HR_S;
    const int s = blockIdx.x % HR_S;
    const int base = r * HR_RANGE;
    const int* Hp = Hpart + (size_t)(r * HR_S + s) * HR_RANGE;
    for (int i = t; i < HR_RANGE; i += 256) {
        int rs = (base + i < N) ? rowstart[base + i] : 0;
        h[i] = rs + Hp[i];
    }
    __syncthreads();
    const int e0 = s * SL;
    const int e1 = min(e0 + SL, E);
    const int nq = (e1 > e0) ? (e1 - e0) >> 2 : 0;
    for (int g = t; g < nq; g += 256) {
        const int e = e0 + 4 * g;
        int4 d4 = *reinterpret_cast<const int4*>(dst + e);
        int4 s4 = *reinterpret_cast<const int4*>(src + e);
        unsigned v0 = (unsigned)(d4.x - base);
        unsigned v1 = (unsigned)(d4.y - base);
        unsigned v2 = (unsigned)(d4.z - base);
        unsigned v3 = (unsigned)(d4.w - base);
        if (v0 < HR_RANGE) esrc[atomicAdd(&h[v0], 1)] = s4.x;
        if (v1 < HR_RANGE) esrc[atomicAdd(&h[v1], 1)] = s4.y;
        if (v2 < HR_RANGE) esrc[atomicAdd(&h[v2], 1)] = s4.z;
        if (v3 < HR_RANGE) esrc[atomicAdd(&h[v3], 1)] = s4.w;
    }
    for (int e = e0 + 4 * nq + t; e < e1; e += 256) {
        unsigned v = (unsigned)(dst[e] - base);
        if (v < HR_RANGE) esrc[atomicAdd(&h[v], 1)] = src[e];
    }
}

// ---------------- W transpose to bf16: WT[o][k] = bf16(W[k][o]) ----------------
__global__ __launch_bounds__(256) void wt_kernel(const float* __restrict__ W1,
        const float* __restrict__ W2, unsigned short* __restrict__ W1T,
        unsigned short* __restrict__ W2T) {
    int i = blockIdx.x * 256 + threadIdx.x;
    if (i < 128 * 128) {               // W1: [128][128] -> W1T [o][k]
        int o = i >> 7, k = i & 127;
        W1T[i] = bf16r(W1[k * 128 + o]);
    }
    if (i < 64 * 128) {                // W2: [128][64] -> W2T [o][k]
        int o = i >> 7, k = i & 127;
        W2T[i] = bf16r(W2[k * 64 + o]);
    }
}

// ---------------- MFMA GEMM: H[N,OUT] = bf16( (X*rowscale) @ W ), bf16 out ----------------
// 4 waves/block, 64 rows/block. Wave w: rows 16w..16w+15, all OUT cols.
// Frags: A[l&15][(l>>4)*8+j] ; B[(l>>4)*8+j][l&15] ; C col=l&15,row=(l>>4)*4+j.
template<int OUT>
__global__ __launch_bounds__(256) void gemm_mfma_kernel(const float* __restrict__ X,
        const float* __restrict__ rowscale,            // may be null
        const unsigned short* __restrict__ WT,         // bf16 [OUT][128]
        unsigned short* __restrict__ H, int N) {
    constexpr int K   = 128;
    constexpr int LDP = K + 8;        // padded row in ushorts (272 B, 16B-aligned)
    constexpr int NT  = OUT / 16;     // 16x16 col tiles per wave (8 or 4)

    __shared__ unsigned short sX[64 * LDP];
    __shared__ unsigned short sWT[OUT * LDP];

    const int tid  = threadIdx.x;
    const int row0 = blockIdx.x * 64;

    // stage X rows -> bf16 (optional rowscale); coalesced read, linear LDS write
    for (int i = tid; i < 64 * 32; i += 256) {
        int rr = i >> 5, kq = i & 31;
        int gr = row0 + rr;
        float4 v = make_float4(0.f, 0.f, 0.f, 0.f);
        if (gr < N) {
            v = reinterpret_cast<const float4*>(X)[(size_t)gr * 32 + kq];
            if (rowscale) { float s = rowscale[gr]; v.x *= s; v.y *= s; v.z *= s; v.w *= s; }
        }
        ushort4 u;
        u.x = bf16r(v.x); u.y = bf16r(v.y); u.z = bf16r(v.z); u.w = bf16r(v.w);
        *reinterpret_cast<ushort4*>(&sX[rr * LDP + kq * 4]) = u;
    }
    // stage W^T (already bf16); 16B copies, conflict-free
    for (int i = tid; i < OUT * (K / 8); i += 256) {
        int o = i >> 4, kq = i & 15;
        *reinterpret_cast<int4*>(&sWT[o * LDP + kq * 8]) =
            *reinterpret_cast<const int4*>(&WT[o * K + kq * 8]);
    }
    __syncthreads();

    const int w  = tid >> 6;
    const int l  = tid & 63;
    const int lr = l & 15;
    const int lk = (l >> 4) * 8;

    f32x4 acc[NT];
    #pragma unroll
    for (int n = 0; n < NT; ++n) acc[n] = (f32x4){0.f, 0.f, 0.f, 0.f};

    #pragma unroll
    for (int k0 = 0; k0 < K; k0 += 32) {
        short8v a = *reinterpret_cast<const short8v*>(&sX[(w * 16 + lr) * LDP + k0 + lk]);
        #pragma unroll
        for (int n = 0; n < NT; ++n) {
            short8v b = *reinterpret_cast<const short8v*>(&sWT[(n * 16 + lr) * LDP + k0 + lk]);
            acc[n] = __builtin_amdgcn_mfma_f32_16x16x32_bf16(a, b, acc[n], 0, 0, 0);
        }
    }

    const int rbase = row0 + w * 16 + (l >> 4) * 4;
    #pragma unroll
    for (int j = 0; j < 4; ++j) {
        int gr = rbase + j;
        if (gr < N) {
            #pragma unroll
            for (int n = 0; n < NT; ++n)
                H[(size_t)gr * OUT + n * 16 + lr] = bf16r(acc[n][j]);
        }
    }
}

// ---------------- CSR gather-aggregate: shfl-prefetched indices, 4-way MLP ----------------

__global__ __launch_bounds__(256) void agg128_kernel(const __hip_bfloat162* __restrict__ H,
        const int* __restrict__ esrc, const int* __restrict__ rowstart,
        const int* __restrict__ cnt,
        const float* __restrict__ nin, const float* __restrict__ bias,
        const float* __restrict__ nout, float* __restrict__ out, int N) {
    int wid  = (blockIdx.x * 256 + threadIdx.x) >> 6;
    int lane = threadIdx.x & 63;
    if (wid >= N) return;
    int beg = rowstart[wid];
    int cw  = cnt[wid];
    float2 a0 = make_float2(0.f, 0.f), a1 = make_float2(0.f, 0.f);
    float2 a2 = make_float2(0.f, 0.f), a3 = make_float2(0.f, 0.f);
    for (int j0 = 0; j0 < cw; j0 += 64) {
        int m = min(64, cw - j0);
        int idx = (lane < m) ? esrc[beg + j0 + lane] : 0;
        int jj = 0;
        for (; jj + 4 <= m; jj += 4) {
            int s0 = __shfl(idx, jj + 0);
            int s1 = __shfl(idx, jj + 1);
            int s2 = __shfl(idx, jj + 2);
            int s3 = __shfl(idx, jj + 3);
            float2 v0 = __bfloat1622float2(H[(size_t)s0 * 64 + lane]);
            float2 v1 = __bfloat1622float2(H[(size_t)s1 * 64 + lane]);
            float2 v2 = __bfloat1622float2(H[(size_t)s2 * 64 + lane]);
            float2 v3 = __bfloat1622float2(H[(size_t)s3 * 64 + lane]);
            a0.x += v0.x; a0.y += v0.y;
            a1.x += v1.x; a1.y += v1.y;
            a2.x += v2.x; a2.y += v2.y;
            a3.x += v3.x; a3.y += v3.y;
        }
        for (; jj < m; ++jj) {
            int s0 = __shfl(idx, jj);
            float2 v0 = __bfloat1622float2(H[(size_t)s0 * 64 + lane]);
            a0.x += v0.x; a0.y += v0.y;
        }
    }
    a0.x += a1.x + a2.x + a3.x;
    a0.y += a1.y + a2.y + a3.y;
    float s = nin[wid];
    float2 b = ((const float2*)bias)[lane];
    float r0 = fmaxf(fmaf(a0.x, s, b.x), 0.f);
    float r1 = fmaxf(fmaf(a0.y, s, b.y), 0.f);
    float t = nout[wid];
    r0 *= t; r1 *= t;
    ((float2*)out)[(size_t)wid * 64 + lane] = make_float2(r0, r1);
}

__global__ __launch_bounds__(256) void agg64_kernel(const __hip_bfloat16* __restrict__ H,
        const int* __restrict__ esrc, const int* __restrict__ rowstart,
        const int* __restrict__ cnt,
        const float* __restrict__ nin, const float* __restrict__ bias,
        float* __restrict__ out, int N) {
    int wid  = (blockIdx.x * 256 + threadIdx.x) >> 6;
    int lane = threadIdx.x & 63;
    if (wid >= N) return;
    int beg = rowstart[wid];
    int cw  = cnt[wid];
    float a0 = 0.f, a1 = 0.f, a2 = 0.f, a3 = 0.f;
    for (int j0 = 0; j0 < cw; j0 += 64) {
        int m = min(64, cw - j0);
        int idx = (lane < m) ? esrc[beg + j0 + lane] : 0;
        int jj = 0;
        for (; jj + 4 <= m; jj += 4) {
            int s0 = __shfl(idx, jj + 0);
            int s1 = __shfl(idx, jj + 1);
            int s2 = __shfl(idx, jj + 2);
            int s3 = __shfl(idx, jj + 3);
            a0 += __bfloat162float(H[(size_t)s0 * 64 + lane]);
            a1 += __bfloat162float(H[(size_t)s1 * 64 + lane]);
            a2 += __bfloat162float(H[(size_t)s2 * 64 + lane]);
            a3 += __bfloat162float(H[(size_t)s3 * 64 + lane]);
        }
        for (; jj < m; ++jj) {
            int s0 = __shfl(idx, jj);
            a0 += __bfloat162float(H[(size_t)s0 * 64 + lane]);
        }
    }
    float acc = (a0 + a1) + (a2 + a3);
    float r = fmaxf(fmaf(acc, nin[wid], bias[lane]), 0.f);
    out[(size_t)wid * 64 + lane] = r;
}

// ---------------- launch ----------------

extern "C" void kernel_launch(void* const* d_in, const int* in_sizes, int n_in,
                              void* d_out, int out_size, void* d_ws, size_t ws_size,
                              hipStream_t stream) {
    const float* x  = (const float*)d_in[0];
    const float* W1 = (const float*)d_in[1];
    const float* b1 = (const float*)d_in[2];
    const float* W2 = (const float*)d_in[3];
    const float* b2 = (const float*)d_in[4];
    const int*   src = (const int*)d_in[5];
    const int*   dst = (const int*)d_in[6];

    const int N = in_sizes[0] / INF;   // 100000
    const int E = in_sizes[5];         // 1600000

    char* ws = (char*)d_ws;
    const size_t padN   = (((size_t)N * 4 + 255) / 256) * 256;
    const size_t padE   = (((size_t)E * 4 + 255) / 256) * 256;
    const size_t padAbf = (((size_t)N * INF * 2 + 255) / 256) * 256;   // bf16 N x 128
    const size_t padWT  = 49152;       // W1T 32KB + W2T 16KB

    float* out = (float*)d_out;

    int*   cnt_src  = (int*)  (ws);
    int*   cnt_dst  = (int*)  (ws + padN);
    int*   rowstart = (int*)  (ws + 2 * padN);
    float* nout     = (float*)(ws + 3 * padN);
    float* nin      = (float*)(ws + 4 * padN);
    int*   bsum     = (int*)  (ws + 5 * padN);
    unsigned short* W1T = (unsigned short*)(ws + 6 * padN);
    unsigned short* W2T = (unsigned short*)(ws + 6 * padN + 32768);
    int*   esrc     = (int*)  (ws + 6 * padN + padWT);
    unsigned short* Abf = (unsigned short*)(ws + 6 * padN + padWT + padE);   // bf16 h
    float* B        = (float*)(ws + 6 * padN + padWT + padE + padAbf);       // fp32 layer1 out

    // overlays (stream-ordered lifetimes):
    //  Hpart_src @ Abf: 26MB — dead before gemm1 writes Abf
    //  Hpart_dst @ B+4MB: 26MB — last read by fillp, before agg128 writes B
    int* Hpart_src = (int*)Abf;
    int* Hpart_dst = (int*)((char*)B + (size_t)4 * 1024 * 1024);

    const int NR  = (N + HR_RANGE - 1) / HR_RANGE;            // 13
    const int NB  = (N + 1023) / 1024;
    const int SL  = ((((E + HR_S - 1) / HR_S) + 3) / 4) * 4;  // edges/slice, mult of 4

    // W transposes (tiny)
    wt_kernel<<<64, 256, 0, stream>>>(W1, W2, W1T, W2T);

    // degree histograms via LDS partials (zero global atomics)
    hist_partial_kernel<<<NR * HR_S, 256, 0, stream>>>(src, Hpart_src, E, SL);
    srchist_merge_kernel<<<(N + 255) / 256, 256, 0, stream>>>(Hpart_src, cnt_src, N);
    hist_partial_kernel<<<NR * HR_S, 256, 0, stream>>>(dst, Hpart_dst, E, SL);
    dsthist_scan_kernel<<<(N + 255) / 256, 256, 0, stream>>>(Hpart_dst, cnt_dst, N);

    // rowstart = exclusive scan of cnt_dst
    scan_blocks_kernel<<<NB, 256, 0, stream>>>(cnt_dst, rowstart, bsum, N);
    scan_bsums_kernel<<<1, 1024, 0, stream>>>(bsum, NB);
    scan_add_kernel<<<NB, 256, 0, stream>>>(rowstart, bsum, N);

    norm_kernel<<<(N + 255) / 256, 256, 0, stream>>>(cnt_src, cnt_dst, nout, nin, N);

    // dst-sorted edge fill via LDS counting sort
    fillp_kernel<<<NR * HR_S, 256, 0, stream>>>(src, dst, rowstart, Hpart_dst, esrc, E, N, SL);

    const int GB = (N + 63) / 64;   // gemm blocks

    // layer 1: Abf = bf16((x*nout) @ W1) ; B = relu(csr_sum(Abf)*nin + b1) * nout
    gemm_mfma_kernel<128><<<GB, 256, 0, stream>>>(x, nout, W1T, Abf, N);
    agg128_kernel<<<(N * 64 + 255) / 256, 256, 0, stream>>>(
        (const __hip_bfloat162*)Abf, esrc, rowstart, cnt_dst, nin, b1, nout, B, N);

    // layer 2: Abf = bf16(B @ W2) ; out = relu(csr_sum(Abf)*nin + b2)
    gemm_mfma_kernel<64><<<GB, 256, 0, stream>>>(B, nullptr, W2T, Abf, N);
    agg64_kernel<<<(N * 64 + 255) / 256, 256, 0, stream>>>(
        (const __hip_bfloat16*)Abf, esrc, rowstart, cnt_dst, nin, b2, out, N);
}

// Round 14
// 257.023 us; speedup vs baseline: 21.4904x; 1.0274x over previous
//
#include <hip/hip_runtime.h>
#include <hip/hip_bf16.h>

#define INF 128
#define HF 64

// node-range / edge-slice partition for LDS histograms
#define HR_RANGE 8192      // nodes per range -> 32 KB LDS
#define HR_S     64        // edge slices

typedef __attribute__((ext_vector_type(8))) short short8v;   // 8 bf16 (4 VGPRs)
typedef __attribute__((ext_vector_type(4))) float f32x4;

__device__ inline unsigned short bf16r(float f) {
    __hip_bfloat16 h = __float2bfloat16(f);
    return *reinterpret_cast<unsigned short*>(&h);
}

// ---------------- generic key histogram partials (no global atomics) ----------------
__global__ __launch_bounds__(256) void hist_partial_kernel(const int* __restrict__ key,
        int* __restrict__ H, int E, int SL) {
    __shared__ int h[HR_RANGE];
    const int t = threadIdx.x;
    const int r = blockIdx.x / HR_S;
    const int s = blockIdx.x % HR_S;
    const int base = r * HR_RANGE;
    for (int i = t; i < HR_RANGE; i += 256) h[i] = 0;
    __syncthreads();
    const int e0 = s * SL;
    const int e1 = min(e0 + SL, E);
    const int nq = (e1 > e0) ? (e1 - e0) >> 2 : 0;
    for (int g = t; g < nq; g += 256) {
        int4 k4 = *reinterpret_cast<const int4*>(key + e0 + 4 * g);
        unsigned v0 = (unsigned)(k4.x - base);
        unsigned v1 = (unsigned)(k4.y - base);
        unsigned v2 = (unsigned)(k4.z - base);
        unsigned v3 = (unsigned)(k4.w - base);
        if (v0 < HR_RANGE) atomicAdd(&h[v0], 1);
        if (v1 < HR_RANGE) atomicAdd(&h[v1], 1);
        if (v2 < HR_RANGE) atomicAdd(&h[v2], 1);
        if (v3 < HR_RANGE) atomicAdd(&h[v3], 1);
    }
    for (int e = e0 + 4 * nq + t; e < e1; e += 256) {
        unsigned v = (unsigned)(key[e] - base);
        if (v < HR_RANGE) atomicAdd(&h[v], 1);
    }
    __syncthreads();
    int* Hp = H + (size_t)(r * HR_S + s) * HR_RANGE;
    for (int i = t; i < HR_RANGE; i += 256) Hp[i] = h[i];
}

// ---------------- prep: merge src partials, prefix dst partials, norms ----------------
__global__ __launch_bounds__(256) void prep_kernel(const int* __restrict__ Hs,
        int* __restrict__ Hd, int* __restrict__ cnt_src, int* __restrict__ cnt_dst,
        float* __restrict__ nout, float* __restrict__ nin, int N) {
    int n = blockIdx.x * 256 + threadIdx.x;
    if (n >= N) return;
    int r = n / HR_RANGE;
    int local = n - r * HR_RANGE;
    const int* ps = Hs + (size_t)r * HR_S * HR_RANGE + local;
    int ssum = 0;
    #pragma unroll 8
    for (int s = 0; s < HR_S; ++s) ssum += ps[(size_t)s * HR_RANGE];
    int* pd = Hd + (size_t)r * HR_S * HR_RANGE + local;
    int run = 0;
    for (int s = 0; s < HR_S; ++s) {
        int v = pd[(size_t)s * HR_RANGE];
        pd[(size_t)s * HR_RANGE] = run;
        run += v;
    }
    cnt_src[n] = ssum;
    cnt_dst[n] = run;
    nout[n] = ssum > 0 ? rsqrtf((float)ssum) : 0.f;
    nin[n]  = run  > 0 ? rsqrtf((float)run)  : 0.f;
}

// ---------------- parallel 3-phase exclusive scan: cnt_dst -> rowstart ----------------
__global__ __launch_bounds__(256) void scan_blocks_kernel(const int* __restrict__ deg,
        int* __restrict__ rowstart, int* __restrict__ bsum, int N) {
    __shared__ int sh[256];
    const int b = blockIdx.x, t = threadIdx.x;
    const int base = b * 1024 + t * 4;
    int v0 = (base + 0 < N) ? deg[base + 0] : 0;
    int v1 = (base + 1 < N) ? deg[base + 1] : 0;
    int v2 = (base + 2 < N) ? deg[base + 2] : 0;
    int v3 = (base + 3 < N) ? deg[base + 3] : 0;
    sh[t] = v0 + v1 + v2 + v3;
    __syncthreads();
    for (int off = 1; off < 256; off <<= 1) {
        int x = (t >= off) ? sh[t - off] : 0;
        __syncthreads();
        sh[t] += x;
        __syncthreads();
    }
    if (t == 255) bsum[b] = sh[255];
    int run = (t == 0) ? 0 : sh[t - 1];
    if (base + 0 < N) { rowstart[base + 0] = run; run += v0; }
    if (base + 1 < N) { rowstart[base + 1] = run; run += v1; }
    if (base + 2 < N) { rowstart[base + 2] = run; run += v2; }
    if (base + 3 < N) { rowstart[base + 3] = run; }
}

__global__ __launch_bounds__(1024) void scan_bsums_kernel(int* __restrict__ bsum, int NB) {
    __shared__ int sh[1024];
    const int t = threadIdx.x;
    int v = (t < NB) ? bsum[t] : 0;
    sh[t] = v;
    __syncthreads();
    for (int off = 1; off < 1024; off <<= 1) {
        int x = (t >= off) ? sh[t - off] : 0;
        __syncthreads();
        sh[t] += x;
        __syncthreads();
    }
    if (t < NB) bsum[t] = sh[t] - v;   // exclusive
}

__global__ __launch_bounds__(256) void scan_add_kernel(int* __restrict__ rowstart,
        const int* __restrict__ bsum, int N) {
    const int b = blockIdx.x;
    if (b == 0) return;
    const int t = threadIdx.x;
    const int off = bsum[b];
    const int base = b * 1024 + t * 4;
    if (base + 0 < N) rowstart[base + 0] += off;
    if (base + 1 < N) rowstart[base + 1] += off;
    if (base + 2 < N) rowstart[base + 2] += off;
    if (base + 3 < N) rowstart[base + 3] += off;
}

// ---------------- fillp: LDS counting-sort scatter (no global atomics) ----------------
__global__ __launch_bounds__(256) void fillp_kernel(const int* __restrict__ src,
        const int* __restrict__ dst, const int* __restrict__ rowstart,
        const int* __restrict__ Hpart, int* __restrict__ esrc, int E, int N, int SL) {
    __shared__ int h[HR_RANGE];
    const int t = threadIdx.x;
    const int r = blockIdx.x / HR_S;
    const int s = blockIdx.x % HR_S;
    const int base = r * HR_RANGE;
    const int* Hp = Hpart + (size_t)(r * HR_S + s) * HR_RANGE;
    for (int i = t; i < HR_RANGE; i += 256) {
        int rs = (base + i < N) ? rowstart[base + i] : 0;
        h[i] = rs + Hp[i];
    }
    __syncthreads();
    const int e0 = s * SL;
    const int e1 = min(e0 + SL, E);
    const int nq = (e1 > e0) ? (e1 - e0) >> 2 : 0;
    for (int g = t; g < nq; g += 256) {
        const int e = e0 + 4 * g;
        int4 d4 = *reinterpret_cast<const int4*>(dst + e);
        int4 s4 = *reinterpret_cast<const int4*>(src + e);
        unsigned v0 = (unsigned)(d4.x - base);
        unsigned v1 = (unsigned)(d4.y - base);
        unsigned v2 = (unsigned)(d4.z - base);
        unsigned v3 = (unsigned)(d4.w - base);
        if (v0 < HR_RANGE) esrc[atomicAdd(&h[v0], 1)] = s4.x;
        if (v1 < HR_RANGE) esrc[atomicAdd(&h[v1], 1)] = s4.y;
        if (v2 < HR_RANGE) esrc[atomicAdd(&h[v2], 1)] = s4.z;
        if (v3 < HR_RANGE) esrc[atomicAdd(&h[v3], 1)] = s4.w;
    }
    for (int e = e0 + 4 * nq + t; e < e1; e += 256) {
        unsigned v = (unsigned)(dst[e] - base);
        if (v < HR_RANGE) esrc[atomicAdd(&h[v], 1)] = src[e];
    }
}

// ---------------- W transpose to bf16: WT[o][k] = bf16(W[k][o]) ----------------
__global__ __launch_bounds__(256) void wt_kernel(const float* __restrict__ W1,
        const float* __restrict__ W2, unsigned short* __restrict__ W1T,
        unsigned short* __restrict__ W2T) {
    int i = blockIdx.x * 256 + threadIdx.x;
    if (i < 128 * 128) {
        int o = i >> 7, k = i & 127;
        W1T[i] = bf16r(W1[k * 128 + o]);
    }
    if (i < 64 * 128) {
        int o = i >> 7, k = i & 127;
        W2T[i] = bf16r(W2[k * 64 + o]);
    }
}

// ---------------- MFMA GEMM: H[N,OUT] = bf16( (X*rowscale) @ W ), bf16 out ----------------
// 4 waves/block, 64 rows/block. Frags: A[l&15][(l>>4)*8+j]; B[(l>>4)*8+j][l&15];
// C col=l&15, row=(l>>4)*4+j.
template<int OUT, bool BF16IN>
__global__ __launch_bounds__(256) void gemm_mfma_kernel(const void* __restrict__ Xv,
        const float* __restrict__ rowscale,            // may be null (fp32 path only)
        const unsigned short* __restrict__ WT,         // bf16 [OUT][128]
        unsigned short* __restrict__ H, int N) {
    constexpr int K   = 128;
    constexpr int LDP = K + 8;        // padded row in ushorts
    constexpr int NT  = OUT / 16;

    __shared__ unsigned short sX[64 * LDP];
    __shared__ unsigned short sWT[OUT * LDP];

    const int tid  = threadIdx.x;
    const int row0 = blockIdx.x * 64;

    if constexpr (BF16IN) {
        const unsigned short* X = (const unsigned short*)Xv;
        for (int i = tid; i < 64 * 16; i += 256) {
            int rr = i >> 4, kq = i & 15;
            int gr = row0 + rr;
            int4 u = make_int4(0, 0, 0, 0);
            if (gr < N)
                u = *reinterpret_cast<const int4*>(&X[(size_t)gr * K + kq * 8]);
            *reinterpret_cast<int4*>(&sX[rr * LDP + kq * 8]) = u;
        }
    } else {
        const float* X = (const float*)Xv;
        for (int i = tid; i < 64 * 32; i += 256) {
            int rr = i >> 5, kq = i & 31;
            int gr = row0 + rr;
            float4 v = make_float4(0.f, 0.f, 0.f, 0.f);
            if (gr < N) {
                v = reinterpret_cast<const float4*>(X)[(size_t)gr * 32 + kq];
                if (rowscale) { float s = rowscale[gr]; v.x *= s; v.y *= s; v.z *= s; v.w *= s; }
            }
            ushort4 u;
            u.x = bf16r(v.x); u.y = bf16r(v.y); u.z = bf16r(v.z); u.w = bf16r(v.w);
            *reinterpret_cast<ushort4*>(&sX[rr * LDP + kq * 4]) = u;
        }
    }
    for (int i = tid; i < OUT * (K / 8); i += 256) {
        int o = i >> 4, kq = i & 15;
        *reinterpret_cast<int4*>(&sWT[o * LDP + kq * 8]) =
            *reinterpret_cast<const int4*>(&WT[o * K + kq * 8]);
    }
    __syncthreads();

    const int w  = tid >> 6;
    const int l  = tid & 63;
    const int lr = l & 15;
    const int lk = (l >> 4) * 8;

    f32x4 acc[NT];
    #pragma unroll
    for (int n = 0; n < NT; ++n) acc[n] = (f32x4){0.f, 0.f, 0.f, 0.f};

    #pragma unroll
    for (int k0 = 0; k0 < K; k0 += 32) {
        short8v a = *reinterpret_cast<const short8v*>(&sX[(w * 16 + lr) * LDP + k0 + lk]);
        #pragma unroll
        for (int n = 0; n < NT; ++n) {
            short8v b = *reinterpret_cast<const short8v*>(&sWT[(n * 16 + lr) * LDP + k0 + lk]);
            acc[n] = __builtin_amdgcn_mfma_f32_16x16x32_bf16(a, b, acc[n], 0, 0, 0);
        }
    }

    const int rbase = row0 + w * 16 + (l >> 4) * 4;
    #pragma unroll
    for (int j = 0; j < 4; ++j) {
        int gr = rbase + j;
        if (gr < N) {
            #pragma unroll
            for (int n = 0; n < NT; ++n)
                H[(size_t)gr * OUT + n * 16 + lr] = bf16r(acc[n][j]);
        }
    }
}

// ---------------- CSR gather-aggregate: shfl-prefetched indices, 8-way MLP ----------------

// layer 1: bf16 in (N x 128), bf16 out (relu(acc*nin+b)*nout)
__global__ __launch_bounds__(256) void agg128_kernel(const __hip_bfloat162* __restrict__ H,
        const int* __restrict__ esrc, const int* __restrict__ rowstart,
        const int* __restrict__ cnt,
        const float* __restrict__ nin, const float* __restrict__ bias,
        const float* __restrict__ nout, unsigned int* __restrict__ outb, int N) {
    int wid  = (blockIdx.x * 256 + threadIdx.x) >> 6;
    int lane = threadIdx.x & 63;
    if (wid >= N) return;
    int beg = rowstart[wid];
    int cw  = cnt[wid];
    float2 a0 = make_float2(0.f, 0.f), a1 = make_float2(0.f, 0.f);
    float2 a2 = make_float2(0.f, 0.f), a3 = make_float2(0.f, 0.f);
    float2 a4 = make_float2(0.f, 0.f), a5 = make_float2(0.f, 0.f);
    float2 a6 = make_float2(0.f, 0.f), a7 = make_float2(0.f, 0.f);
    for (int j0 = 0; j0 < cw; j0 += 64) {
        int m = min(64, cw - j0);
        int idx = (lane < m) ? esrc[beg + j0 + lane] : 0;
        int jj = 0;
        for (; jj + 8 <= m; jj += 8) {
            int s0 = __shfl(idx, jj + 0);
            int s1 = __shfl(idx, jj + 1);
            int s2 = __shfl(idx, jj + 2);
            int s3 = __shfl(idx, jj + 3);
            int s4 = __shfl(idx, jj + 4);
            int s5 = __shfl(idx, jj + 5);
            int s6 = __shfl(idx, jj + 6);
            int s7 = __shfl(idx, jj + 7);
            float2 v0 = __bfloat1622float2(H[(size_t)s0 * 64 + lane]);
            float2 v1 = __bfloat1622float2(H[(size_t)s1 * 64 + lane]);
            float2 v2 = __bfloat1622float2(H[(size_t)s2 * 64 + lane]);
            float2 v3 = __bfloat1622float2(H[(size_t)s3 * 64 + lane]);
            float2 v4 = __bfloat1622float2(H[(size_t)s4 * 64 + lane]);
            float2 v5 = __bfloat1622float2(H[(size_t)s5 * 64 + lane]);
            float2 v6 = __bfloat1622float2(H[(size_t)s6 * 64 + lane]);
            float2 v7 = __bfloat1622float2(H[(size_t)s7 * 64 + lane]);
            a0.x += v0.x; a0.y += v0.y;  a1.x += v1.x; a1.y += v1.y;
            a2.x += v2.x; a2.y += v2.y;  a3.x += v3.x; a3.y += v3.y;
            a4.x += v4.x; a4.y += v4.y;  a5.x += v5.x; a5.y += v5.y;
            a6.x += v6.x; a6.y += v6.y;  a7.x += v7.x; a7.y += v7.y;
        }
        for (; jj < m; ++jj) {
            int s0 = __shfl(idx, jj);
            float2 v0 = __bfloat1622float2(H[(size_t)s0 * 64 + lane]);
            a0.x += v0.x; a0.y += v0.y;
        }
    }
    a0.x += a1.x + a2.x + a3.x + a4.x + a5.x + a6.x + a7.x;
    a0.y += a1.y + a2.y + a3.y + a4.y + a5.y + a6.y + a7.y;
    float s = nin[wid];
    float2 b = ((const float2*)bias)[lane];
    float r0 = fmaxf(fmaf(a0.x, s, b.x), 0.f);
    float r1 = fmaxf(fmaf(a0.y, s, b.y), 0.f);
    float t = nout[wid];
    r0 *= t; r1 *= t;
    __hip_bfloat162 p = __float22bfloat162_rn(make_float2(r0, r1));
    outb[(size_t)wid * 64 + lane] = *reinterpret_cast<unsigned int*>(&p);
}

// layer 2: bf16 in (N x 64), fp32 out
__global__ __launch_bounds__(256) void agg64_kernel(const __hip_bfloat16* __restrict__ H,
        const int* __restrict__ esrc, const int* __restrict__ rowstart,
        const int* __restrict__ cnt,
        const float* __restrict__ nin, const float* __restrict__ bias,
        float* __restrict__ out, int N) {
    int wid  = (blockIdx.x * 256 + threadIdx.x) >> 6;
    int lane = threadIdx.x & 63;
    if (wid >= N) return;
    int beg = rowstart[wid];
    int cw  = cnt[wid];
    float a0 = 0.f, a1 = 0.f, a2 = 0.f, a3 = 0.f;
    float a4 = 0.f, a5 = 0.f, a6 = 0.f, a7 = 0.f;
    for (int j0 = 0; j0 < cw; j0 += 64) {
        int m = min(64, cw - j0);
        int idx = (lane < m) ? esrc[beg + j0 + lane] : 0;
        int jj = 0;
        for (; jj + 8 <= m; jj += 8) {
            int s0 = __shfl(idx, jj + 0);
            int s1 = __shfl(idx, jj + 1);
            int s2 = __shfl(idx, jj + 2);
            int s3 = __shfl(idx, jj + 3);
            int s4 = __shfl(idx, jj + 4);
            int s5 = __shfl(idx, jj + 5);
            int s6 = __shfl(idx, jj + 6);
            int s7 = __shfl(idx, jj + 7);
            a0 += __bfloat162float(H[(size_t)s0 * 64 + lane]);
            a1 += __bfloat162float(H[(size_t)s1 * 64 + lane]);
            a2 += __bfloat162float(H[(size_t)s2 * 64 + lane]);
            a3 += __bfloat162float(H[(size_t)s3 * 64 + lane]);
            a4 += __bfloat162float(H[(size_t)s4 * 64 + lane]);
            a5 += __bfloat162float(H[(size_t)s5 * 64 + lane]);
            a6 += __bfloat162float(H[(size_t)s6 * 64 + lane]);
            a7 += __bfloat162float(H[(size_t)s7 * 64 + lane]);
        }
        for (; jj < m; ++jj) {
            int s0 = __shfl(idx, jj);
            a0 += __bfloat162float(H[(size_t)s0 * 64 + lane]);
        }
    }
    float acc = ((a0 + a1) + (a2 + a3)) + ((a4 + a5) + (a6 + a7));
    float r = fmaxf(fmaf(acc, nin[wid], bias[lane]), 0.f);
    out[(size_t)wid * 64 + lane] = r;
}

// ---------------- launch ----------------

extern "C" void kernel_launch(void* const* d_in, const int* in_sizes, int n_in,
                              void* d_out, int out_size, void* d_ws, size_t ws_size,
                              hipStream_t stream) {
    const float* x  = (const float*)d_in[0];
    const float* W1 = (const float*)d_in[1];
    const float* b1 = (const float*)d_in[2];
    const float* W2 = (const float*)d_in[3];
    const float* b2 = (const float*)d_in[4];
    const int*   src = (const int*)d_in[5];
    const int*   dst = (const int*)d_in[6];

    const int N = in_sizes[0] / INF;   // 100000
    const int E = in_sizes[5];         // 1600000

    char* ws = (char*)d_ws;
    const size_t padN   = (((size_t)N * 4 + 255) / 256) * 256;
    const size_t padE   = (((size_t)E * 4 + 255) / 256) * 256;
    const int    NR     = (N + HR_RANGE - 1) / HR_RANGE;                  // 13
    const size_t HPbytes = (size_t)NR * HR_S * HR_RANGE * sizeof(int);    // 27.3 MB
    const size_t padAbf  = (((size_t)N * INF * 2 + 255) / 256) * 256;     // 25.6 MB
    const size_t regA    = (HPbytes > padAbf ? HPbytes : padAbf);
    const size_t padWT   = 49152;

    float* out = (float*)d_out;

    int*   cnt_src  = (int*)  (ws);
    int*   cnt_dst  = (int*)  (ws + padN);
    int*   rowstart = (int*)  (ws + 2 * padN);
    float* nout     = (float*)(ws + 3 * padN);
    float* nin      = (float*)(ws + 4 * padN);
    int*   bsum     = (int*)  (ws + 5 * padN);
    unsigned short* W1T = (unsigned short*)(ws + 6 * padN);
    unsigned short* W2T = (unsigned short*)(ws + 6 * padN + 32768);
    int*   esrc     = (int*)  (ws + 6 * padN + padWT);
    char*  regionA  = ws + 6 * padN + padWT + padE;          // Hpart_src, then Abf1/Abf2
    unsigned short* Bbf = (unsigned short*)(regionA + regA); // bf16 N x 128
    int*   Hpart_dst = (int*)(regionA + regA + padAbf);      // own region

    int* Hpart_src = (int*)regionA;             // dead after prep; gemm1 then reuses regionA
    unsigned short* Abf = (unsigned short*)regionA;          // layer1 h / layer2 h

    const int NB  = (N + 1023) / 1024;
    const int SL  = ((((E + HR_S - 1) / HR_S) + 3) / 4) * 4;

    // W transposes (tiny)
    wt_kernel<<<64, 256, 0, stream>>>(W1, W2, W1T, W2T);

    // degree histograms via LDS partials (zero global atomics)
    hist_partial_kernel<<<NR * HR_S, 256, 0, stream>>>(src, Hpart_src, E, SL);
    hist_partial_kernel<<<NR * HR_S, 256, 0, stream>>>(dst, Hpart_dst, E, SL);

    // fused: merge src partials -> cnt_src; prefix dst partials -> cnt_dst; norms
    prep_kernel<<<(N + 255) / 256, 256, 0, stream>>>(Hpart_src, Hpart_dst,
                                                     cnt_src, cnt_dst, nout, nin, N);

    // rowstart = exclusive scan of cnt_dst
    scan_blocks_kernel<<<NB, 256, 0, stream>>>(cnt_dst, rowstart, bsum, N);
    scan_bsums_kernel<<<1, 1024, 0, stream>>>(bsum, NB);
    scan_add_kernel<<<NB, 256, 0, stream>>>(rowstart, bsum, N);

    // dst-sorted edge fill via LDS counting sort
    fillp_kernel<<<NR * HR_S, 256, 0, stream>>>(src, dst, rowstart, Hpart_dst, esrc, E, N, SL);

    const int GB = (N + 63) / 64;

    // layer 1: Abf = bf16((x*nout) @ W1) ; Bbf = bf16(relu(csr_sum(Abf)*nin + b1) * nout)
    gemm_mfma_kernel<128, false><<<GB, 256, 0, stream>>>(x, nout, W1T, Abf, N);
    agg128_kernel<<<(N * 64 + 255) / 256, 256, 0, stream>>>(
        (const __hip_bfloat162*)Abf, esrc, rowstart, cnt_dst, nin, b1, nout,
        (unsigned int*)Bbf, N);

    // layer 2: Abf = bf16(Bbf @ W2) ; out = relu(csr_sum(Abf)*nin + b2)
    gemm_mfma_kernel<64, true><<<GB, 256, 0, stream>>>(Bbf, nullptr, W2T, Abf, N);
    agg64_kernel<<<(N * 64 + 255) / 256, 256, 0, stream>>>(
        (const __hip_bfloat16*)Abf, esrc, rowstart, cnt_dst, nin, b2, out, N);
}

// Round 15
// 226.409 us; speedup vs baseline: 24.3963x; 1.1352x over previous
//
#include <hip/hip_runtime.h>
#include <hip/hip_bf16.h>

#define INF 128
#define HF 64

#define HS 64              // edge slices
// hist partition: packed ushort bins, 2 nodes per u32
#define HR_H 32768         // nodes per hist range (16384 u32 = 64 KB LDS)
#define NR_H 4             // ceil(100000/32768)
// fillp partition: int bins
#define HR_F 16384         // nodes per fillp range (64 KB LDS)
#define NR_F 7             // ceil(100000/16384)

typedef __attribute__((ext_vector_type(8))) short short8v;   // 8 bf16 (4 VGPRs)
typedef __attribute__((ext_vector_type(4))) float f32x4;

__device__ inline unsigned short bf16r(float f) {
    __hip_bfloat16 h = __float2bfloat16(f);
    return *reinterpret_cast<unsigned short*>(&h);
}

// ---------------- fused src+dst histograms: packed ushort LDS bins ----------------
// grid = 2*NR_H*HS blocks (plane 0: src, plane 1: dst); 512 threads
__global__ __launch_bounds__(512) void hist2_kernel(const int* __restrict__ src,
        const int* __restrict__ dst, unsigned* __restrict__ Hs,
        unsigned* __restrict__ Hd, int E, int SL) {
    __shared__ unsigned h[HR_H / 2];
    const int t = threadIdx.x;
    const int which = blockIdx.x >> 8;          // 0: src, 1: dst
    const int rs = blockIdx.x & 255;
    const int r = rs >> 6;
    const int s = rs & 63;
    const int base = r * HR_H;
    const int* key = which ? dst : src;
    unsigned* H = which ? Hd : Hs;
    for (int i = t; i < HR_H / 2; i += 512) h[i] = 0u;
    __syncthreads();
    const int e0 = s * SL;
    const int e1 = min(e0 + SL, E);
    const int nq = (e1 > e0) ? (e1 - e0) >> 2 : 0;
    for (int g = t; g < nq; g += 512) {
        int4 k4 = *reinterpret_cast<const int4*>(key + e0 + 4 * g);
        unsigned v0 = (unsigned)(k4.x - base);
        unsigned v1 = (unsigned)(k4.y - base);
        unsigned v2 = (unsigned)(k4.z - base);
        unsigned v3 = (unsigned)(k4.w - base);
        if (v0 < HR_H) atomicAdd(&h[v0 >> 1], 1u << ((v0 & 1) << 4));
        if (v1 < HR_H) atomicAdd(&h[v1 >> 1], 1u << ((v1 & 1) << 4));
        if (v2 < HR_H) atomicAdd(&h[v2 >> 1], 1u << ((v2 & 1) << 4));
        if (v3 < HR_H) atomicAdd(&h[v3 >> 1], 1u << ((v3 & 1) << 4));
    }
    for (int e = e0 + 4 * nq + t; e < e1; e += 512) {
        unsigned v = (unsigned)(key[e] - base);
        if (v < HR_H) atomicAdd(&h[v >> 1], 1u << ((v & 1) << 4));
    }
    __syncthreads();
    unsigned* Hp = H + (size_t)(r * HS + s) * (HR_H / 2);
    for (int i = t; i < HR_H / 2; i += 512) Hp[i] = h[i];
}

// ---------------- prep: word-parallel (2 nodes/thread) ----------------
// merge src partials -> nout; prefix dst partials in place -> cnt_dst, nin
__global__ __launch_bounds__(256) void prep_kernel(const unsigned* __restrict__ Hs,
        unsigned* __restrict__ Hd, int* __restrict__ cnt_dst,
        float* __restrict__ nout, float* __restrict__ nin, int N) {
    int w = blockIdx.x * 256 + threadIdx.x;     // word = node pair (2w, 2w+1)
    int NW = (N + 1) >> 1;
    if (w >= NW) return;
    int r  = w >> 14;                           // 16384 words per range
    int lw = w & 16383;
    const unsigned* ps = Hs + (size_t)r * HS * (HR_H / 2) + lw;
    unsigned s_lo = 0, s_hi = 0;
    #pragma unroll 8
    for (int s = 0; s < HS; ++s) {
        unsigned v = ps[(size_t)s * (HR_H / 2)];
        s_lo += v & 0xffffu;
        s_hi += v >> 16;
    }
    unsigned* pd = Hd + (size_t)r * HS * (HR_H / 2) + lw;
    unsigned run_lo = 0, run_hi = 0;
    for (int s = 0; s < HS; ++s) {
        unsigned v = pd[(size_t)s * (HR_H / 2)];
        pd[(size_t)s * (HR_H / 2)] = run_lo | (run_hi << 16);
        run_lo += v & 0xffffu;
        run_hi += v >> 16;
    }
    int n0 = 2 * w, n1 = 2 * w + 1;
    cnt_dst[n0] = (int)run_lo;
    nout[n0] = s_lo ? rsqrtf((float)s_lo) : 0.f;
    nin[n0]  = run_lo ? rsqrtf((float)run_lo) : 0.f;
    if (n1 < N) {
        cnt_dst[n1] = (int)run_hi;
        nout[n1] = s_hi ? rsqrtf((float)s_hi) : 0.f;
        nin[n1]  = run_hi ? rsqrtf((float)run_hi) : 0.f;
    }
}

// ---------------- parallel 3-phase exclusive scan: cnt_dst -> rowstart ----------------
__global__ __launch_bounds__(256) void scan_blocks_kernel(const int* __restrict__ deg,
        int* __restrict__ rowstart, int* __restrict__ bsum, int N) {
    __shared__ int sh[256];
    const int b = blockIdx.x, t = threadIdx.x;
    const int base = b * 1024 + t * 4;
    int v0 = (base + 0 < N) ? deg[base + 0] : 0;
    int v1 = (base + 1 < N) ? deg[base + 1] : 0;
    int v2 = (base + 2 < N) ? deg[base + 2] : 0;
    int v3 = (base + 3 < N) ? deg[base + 3] : 0;
    sh[t] = v0 + v1 + v2 + v3;
    __syncthreads();
    for (int off = 1; off < 256; off <<= 1) {
        int x = (t >= off) ? sh[t - off] : 0;
        __syncthreads();
        sh[t] += x;
        __syncthreads();
    }
    if (t == 255) bsum[b] = sh[255];
    int run = (t == 0) ? 0 : sh[t - 1];
    if (base + 0 < N) { rowstart[base + 0] = run; run += v0; }
    if (base + 1 < N) { rowstart[base + 1] = run; run += v1; }
    if (base + 2 < N) { rowstart[base + 2] = run; run += v2; }
    if (base + 3 < N) { rowstart[base + 3] = run; }
}

__global__ __launch_bounds__(1024) void scan_bsums_kernel(int* __restrict__ bsum, int NB) {
    __shared__ int sh[1024];
    const int t = threadIdx.x;
    int v = (t < NB) ? bsum[t] : 0;
    sh[t] = v;
    __syncthreads();
    for (int off = 1; off < 1024; off <<= 1) {
        int x = (t >= off) ? sh[t - off] : 0;
        __syncthreads();
        sh[t] += x;
        __syncthreads();
    }
    if (t < NB) bsum[t] = sh[t] - v;   // exclusive
}

__global__ __launch_bounds__(256) void scan_add_kernel(int* __restrict__ rowstart,
        const int* __restrict__ bsum, int N) {
    const int b = blockIdx.x;
    if (b == 0) return;
    const int t = threadIdx.x;
    const int off = bsum[b];
    const int base = b * 1024 + t * 4;
    if (base + 0 < N) rowstart[base + 0] += off;
    if (base + 1 < N) rowstart[base + 1] += off;
    if (base + 2 < N) rowstart[base + 2] += off;
    if (base + 3 < N) rowstart[base + 3] += off;
}

// ---------------- fillp: LDS counting-sort scatter (no global atomics) ----------------
// int bins seeded rowstart + packed slice-prefix; 512 threads, 64 KB LDS
__global__ __launch_bounds__(512) void fillp_kernel(const int* __restrict__ src,
        const int* __restrict__ dst, const int* __restrict__ rowstart,
        const unsigned* __restrict__ Hd, int* __restrict__ esrc, int E, int N, int SL) {
    __shared__ int h[HR_F];
    const int t = threadIdx.x;
    const int r = blockIdx.x >> 6;      // 0..NR_F-1
    const int s = blockIdx.x & 63;
    const int base = r * HR_F;
    const int rh   = r >> 1;            // hist range
    const int off0 = (r & 1) * HR_F;    // node offset within hist range
    const unsigned* Hp = Hd + (size_t)(rh * HS + s) * (HR_H / 2);
    for (int i = t; i < HR_F; i += 512) {
        int n = base + i;
        int seed = 0;
        if (n < N) {
            int l = off0 + i;
            unsigned v = Hp[l >> 1];
            unsigned pre = (l & 1) ? (v >> 16) : (v & 0xffffu);
            seed = rowstart[n] + (int)pre;
        }
        h[i] = seed;
    }
    __syncthreads();
    const int e0 = s * SL;
    const int e1 = min(e0 + SL, E);
    const int nq = (e1 > e0) ? (e1 - e0) >> 2 : 0;
    for (int g = t; g < nq; g += 512) {
        const int e = e0 + 4 * g;
        int4 d4 = *reinterpret_cast<const int4*>(dst + e);
        int4 s4 = *reinterpret_cast<const int4*>(src + e);
        unsigned v0 = (unsigned)(d4.x - base);
        unsigned v1 = (unsigned)(d4.y - base);
        unsigned v2 = (unsigned)(d4.z - base);
        unsigned v3 = (unsigned)(d4.w - base);
        if (v0 < HR_F) esrc[atomicAdd(&h[v0], 1)] = s4.x;
        if (v1 < HR_F) esrc[atomicAdd(&h[v1], 1)] = s4.y;
        if (v2 < HR_F) esrc[atomicAdd(&h[v2], 1)] = s4.z;
        if (v3 < HR_F) esrc[atomicAdd(&h[v3], 1)] = s4.w;
    }
    for (int e = e0 + 4 * nq + t; e < e1; e += 512) {
        unsigned v = (unsigned)(dst[e] - base);
        if (v < HR_F) esrc[atomicAdd(&h[v], 1)] = src[e];
    }
}

// ---------------- W transpose to bf16: WT[o][k] = bf16(W[k][o]) ----------------
__global__ __launch_bounds__(256) void wt_kernel(const float* __restrict__ W1,
        const float* __restrict__ W2, unsigned short* __restrict__ W1T,
        unsigned short* __restrict__ W2T) {
    int i = blockIdx.x * 256 + threadIdx.x;
    if (i < 128 * 128) {
        int o = i >> 7, k = i & 127;
        W1T[i] = bf16r(W1[k * 128 + o]);
    }
    if (i < 64 * 128) {
        int o = i >> 7, k = i & 127;
        W2T[i] = bf16r(W2[k * 64 + o]);
    }
}

// ---------------- MFMA GEMM: H[N,OUT] = bf16( (X*rowscale) @ W ), bf16 out ----------------
template<int OUT, bool BF16IN>
__global__ __launch_bounds__(256) void gemm_mfma_kernel(const void* __restrict__ Xv,
        const float* __restrict__ rowscale,            // may be null (fp32 path only)
        const unsigned short* __restrict__ WT,         // bf16 [OUT][128]
        unsigned short* __restrict__ H, int N) {
    constexpr int K   = 128;
    constexpr int LDP = K + 8;
    constexpr int NT  = OUT / 16;

    __shared__ unsigned short sX[64 * LDP];
    __shared__ unsigned short sWT[OUT * LDP];

    const int tid  = threadIdx.x;
    const int row0 = blockIdx.x * 64;

    if constexpr (BF16IN) {
        const unsigned short* X = (const unsigned short*)Xv;
        for (int i = tid; i < 64 * 16; i += 256) {
            int rr = i >> 4, kq = i & 15;
            int gr = row0 + rr;
            int4 u = make_int4(0, 0, 0, 0);
            if (gr < N)
                u = *reinterpret_cast<const int4*>(&X[(size_t)gr * K + kq * 8]);
            *reinterpret_cast<int4*>(&sX[rr * LDP + kq * 8]) = u;
        }
    } else {
        const float* X = (const float*)Xv;
        for (int i = tid; i < 64 * 32; i += 256) {
            int rr = i >> 5, kq = i & 31;
            int gr = row0 + rr;
            float4 v = make_float4(0.f, 0.f, 0.f, 0.f);
            if (gr < N) {
                v = reinterpret_cast<const float4*>(X)[(size_t)gr * 32 + kq];
                if (rowscale) { float s = rowscale[gr]; v.x *= s; v.y *= s; v.z *= s; v.w *= s; }
            }
            ushort4 u;
            u.x = bf16r(v.x); u.y = bf16r(v.y); u.z = bf16r(v.z); u.w = bf16r(v.w);
            *reinterpret_cast<ushort4*>(&sX[rr * LDP + kq * 4]) = u;
        }
    }
    for (int i = tid; i < OUT * (K / 8); i += 256) {
        int o = i >> 4, kq = i & 15;
        *reinterpret_cast<int4*>(&sWT[o * LDP + kq * 8]) =
            *reinterpret_cast<const int4*>(&WT[o * K + kq * 8]);
    }
    __syncthreads();

    const int w  = tid >> 6;
    const int l  = tid & 63;
    const int lr = l & 15;
    const int lk = (l >> 4) * 8;

    f32x4 acc[NT];
    #pragma unroll
    for (int n = 0; n < NT; ++n) acc[n] = (f32x4){0.f, 0.f, 0.f, 0.f};

    #pragma unroll
    for (int k0 = 0; k0 < K; k0 += 32) {
        short8v a = *reinterpret_cast<const short8v*>(&sX[(w * 16 + lr) * LDP + k0 + lk]);
        #pragma unroll
        for (int n = 0; n < NT; ++n) {
            short8v b = *reinterpret_cast<const short8v*>(&sWT[(n * 16 + lr) * LDP + k0 + lk]);
            acc[n] = __builtin_amdgcn_mfma_f32_16x16x32_bf16(a, b, acc[n], 0, 0, 0);
        }
    }

    const int rbase = row0 + w * 16 + (l >> 4) * 4;
    #pragma unroll
    for (int j = 0; j < 4; ++j) {
        int gr = rbase + j;
        if (gr < N) {
            #pragma unroll
            for (int n = 0; n < NT; ++n)
                H[(size_t)gr * OUT + n * 16 + lr] = bf16r(acc[n][j]);
        }
    }
}

// ---------------- CSR gather-aggregate: shfl-prefetched indices, 8-way MLP ----------------

__global__ __launch_bounds__(256) void agg128_kernel(const __hip_bfloat162* __restrict__ H,
        const int* __restrict__ esrc, const int* __restrict__ rowstart,
        const int* __restrict__ cnt,
        const float* __restrict__ nin, const float* __restrict__ bias,
        const float* __restrict__ nout, unsigned int* __restrict__ outb, int N) {
    int wid  = (blockIdx.x * 256 + threadIdx.x) >> 6;
    int lane = threadIdx.x & 63;
    if (wid >= N) return;
    int beg = rowstart[wid];
    int cw  = cnt[wid];
    float2 a0 = make_float2(0.f, 0.f), a1 = make_float2(0.f, 0.f);
    float2 a2 = make_float2(0.f, 0.f), a3 = make_float2(0.f, 0.f);
    float2 a4 = make_float2(0.f, 0.f), a5 = make_float2(0.f, 0.f);
    float2 a6 = make_float2(0.f, 0.f), a7 = make_float2(0.f, 0.f);
    for (int j0 = 0; j0 < cw; j0 += 64) {
        int m = min(64, cw - j0);
        int idx = (lane < m) ? esrc[beg + j0 + lane] : 0;
        int jj = 0;
        for (; jj + 8 <= m; jj += 8) {
            int s0 = __shfl(idx, jj + 0);
            int s1 = __shfl(idx, jj + 1);
            int s2 = __shfl(idx, jj + 2);
            int s3 = __shfl(idx, jj + 3);
            int s4 = __shfl(idx, jj + 4);
            int s5 = __shfl(idx, jj + 5);
            int s6 = __shfl(idx, jj + 6);
            int s7 = __shfl(idx, jj + 7);
            float2 v0 = __bfloat1622float2(H[(size_t)s0 * 64 + lane]);
            float2 v1 = __bfloat1622float2(H[(size_t)s1 * 64 + lane]);
            float2 v2 = __bfloat1622float2(H[(size_t)s2 * 64 + lane]);
            float2 v3 = __bfloat1622float2(H[(size_t)s3 * 64 + lane]);
            float2 v4 = __bfloat1622float2(H[(size_t)s4 * 64 + lane]);
            float2 v5 = __bfloat1622float2(H[(size_t)s5 * 64 + lane]);
            float2 v6 = __bfloat1622float2(H[(size_t)s6 * 64 + lane]);
            float2 v7 = __bfloat1622float2(H[(size_t)s7 * 64 + lane]);
            a0.x += v0.x; a0.y += v0.y;  a1.x += v1.x; a1.y += v1.y;
            a2.x += v2.x; a2.y += v2.y;  a3.x += v3.x; a3.y += v3.y;
            a4.x += v4.x; a4.y += v4.y;  a5.x += v5.x; a5.y += v5.y;
            a6.x += v6.x; a6.y += v6.y;  a7.x += v7.x; a7.y += v7.y;
        }
        for (; jj < m; ++jj) {
            int s0 = __shfl(idx, jj);
            float2 v0 = __bfloat1622float2(H[(size_t)s0 * 64 + lane]);
            a0.x += v0.x; a0.y += v0.y;
        }
    }
    a0.x += a1.x + a2.x + a3.x + a4.x + a5.x + a6.x + a7.x;
    a0.y += a1.y + a2.y + a3.y + a4.y + a5.y + a6.y + a7.y;
    float s = nin[wid];
    float2 b = ((const float2*)bias)[lane];
    float r0 = fmaxf(fmaf(a0.x, s, b.x), 0.f);
    float r1 = fmaxf(fmaf(a0.y, s, b.y), 0.f);
    float t = nout[wid];
    r0 *= t; r1 *= t;
    __hip_bfloat162 p = __float22bfloat162_rn(make_float2(r0, r1));
    outb[(size_t)wid * 64 + lane] = *reinterpret_cast<unsigned int*>(&p);
}

__global__ __launch_bounds__(256) void agg64_kernel(const __hip_bfloat16* __restrict__ H,
        const int* __restrict__ esrc, const int* __restrict__ rowstart,
        const int* __restrict__ cnt,
        const float* __restrict__ nin, const float* __restrict__ bias,
        float* __restrict__ out, int N) {
    int wid  = (blockIdx.x * 256 + threadIdx.x) >> 6;
    int lane = threadIdx.x & 63;
    if (wid >= N) return;
    int beg = rowstart[wid];
    int cw  = cnt[wid];
    float a0 = 0.f, a1 = 0.f, a2 = 0.f, a3 = 0.f;
    float a4 = 0.f, a5 = 0.f, a6 = 0.f, a7 = 0.f;
    for (int j0 = 0; j0 < cw; j0 += 64) {
        int m = min(64, cw - j0);
        int idx = (lane < m) ? esrc[beg + j0 + lane] : 0;
        int jj = 0;
        for (; jj + 8 <= m; jj += 8) {
            int s0 = __shfl(idx, jj + 0);
            int s1 = __shfl(idx, jj + 1);
            int s2 = __shfl(idx, jj + 2);
            int s3 = __shfl(idx, jj + 3);
            int s4 = __shfl(idx, jj + 4);
            int s5 = __shfl(idx, jj + 5);
            int s6 = __shfl(idx, jj + 6);
            int s7 = __shfl(idx, jj + 7);
            a0 += __bfloat162float(H[(size_t)s0 * 64 + lane]);
            a1 += __bfloat162float(H[(size_t)s1 * 64 + lane]);
            a2 += __bfloat162float(H[(size_t)s2 * 64 + lane]);
            a3 += __bfloat162float(H[(size_t)s3 * 64 + lane]);
            a4 += __bfloat162float(H[(size_t)s4 * 64 + lane]);
            a5 += __bfloat162float(H[(size_t)s5 * 64 + lane]);
            a6 += __bfloat162float(H[(size_t)s6 * 64 + lane]);
            a7 += __bfloat162float(H[(size_t)s7 * 64 + lane]);
        }
        for (; jj < m; ++jj) {
            int s0 = __shfl(idx, jj);
            a0 += __bfloat162float(H[(size_t)s0 * 64 + lane]);
        }
    }
    float acc = ((a0 + a1) + (a2 + a3)) + ((a4 + a5) + (a6 + a7));
    float r = fmaxf(fmaf(acc, nin[wid], bias[lane]), 0.f);
    out[(size_t)wid * 64 + lane] = r;
}

// ---------------- launch ----------------

extern "C" void kernel_launch(void* const* d_in, const int* in_sizes, int n_in,
                              void* d_out, int out_size, void* d_ws, size_t ws_size,
                              hipStream_t stream) {
    const float* x  = (const float*)d_in[0];
    const float* W1 = (const float*)d_in[1];
    const float* b1 = (const float*)d_in[2];
    const float* W2 = (const float*)d_in[3];
    const float* b2 = (const float*)d_in[4];
    const int*   src = (const int*)d_in[5];
    const int*   dst = (const int*)d_in[6];

    const int N = in_sizes[0] / INF;   // 100000
    const int E = in_sizes[5];         // 1600000

    char* ws = (char*)d_ws;
    const size_t padN    = (((size_t)N * 4 + 255) / 256) * 256;
    const size_t padE    = (((size_t)E * 4 + 255) / 256) * 256;
    const size_t HPbytes = (size_t)NR_H * HS * (HR_H / 2) * sizeof(unsigned);  // 16.8 MB
    const size_t padAbf  = (((size_t)N * INF * 2 + 255) / 256) * 256;          // 25.6 MB
    const size_t padWT   = 49152;

    float* out = (float*)d_out;

    int*   cnt_dst  = (int*)  (ws);
    int*   rowstart = (int*)  (ws + padN);
    float* nout     = (float*)(ws + 2 * padN);
    float* nin      = (float*)(ws + 3 * padN);
    int*   bsum     = (int*)  (ws + 4 * padN);
    unsigned short* W1T = (unsigned short*)(ws + 5 * padN);
    unsigned short* W2T = (unsigned short*)(ws + 5 * padN + 32768);
    int*   esrc     = (int*)  (ws + 5 * padN + padWT);
    char*  regionA  = ws + 5 * padN + padWT + padE;          // Hpart_src, then Abf
    unsigned short* Bbf = (unsigned short*)(regionA + padAbf);   // bf16 N x 128
    unsigned* Hpart_dst = (unsigned*)(regionA + padAbf + padAbf);

    unsigned* Hpart_src = (unsigned*)regionA;   // dead after prep; gemm1 reuses regionA
    unsigned short* Abf = (unsigned short*)regionA;

    const int NB = (N + 1023) / 1024;
    const int NW = (N + 1) >> 1;
    const int SL = ((((E + HS - 1) / HS) + 3) / 4) * 4;      // edges/slice, mult of 4

    // W transposes (tiny)
    wt_kernel<<<64, 256, 0, stream>>>(W1, W2, W1T, W2T);

    // fused src+dst histograms (packed ushort bins, zero global atomics)
    hist2_kernel<<<2 * NR_H * HS, 512, 0, stream>>>(src, dst, Hpart_src, Hpart_dst, E, SL);

    // merge src partials -> nout; prefix dst partials -> cnt_dst, nin
    prep_kernel<<<(NW + 255) / 256, 256, 0, stream>>>(Hpart_src, Hpart_dst,
                                                      cnt_dst, nout, nin, N);

    // rowstart = exclusive scan of cnt_dst
    scan_blocks_kernel<<<NB, 256, 0, stream>>>(cnt_dst, rowstart, bsum, N);
    scan_bsums_kernel<<<1, 1024, 0, stream>>>(bsum, NB);
    scan_add_kernel<<<NB, 256, 0, stream>>>(rowstart, bsum, N);

    // dst-sorted edge fill via LDS counting sort
    fillp_kernel<<<NR_F * HS, 512, 0, stream>>>(src, dst, rowstart, Hpart_dst, esrc, E, N, SL);

    const int GB = (N + 63) / 64;

    // layer 1: Abf = bf16((x*nout) @ W1) ; Bbf = bf16(relu(csr_sum(Abf)*nin + b1) * nout)
    gemm_mfma_kernel<128, false><<<GB, 256, 0, stream>>>(x, nout, W1T, Abf, N);
    agg128_kernel<<<(N * 64 + 255) / 256, 256, 0, stream>>>(
        (const __hip_bfloat162*)Abf, esrc, rowstart, cnt_dst, nin, b1, nout,
        (unsigned int*)Bbf, N);

    // layer 2: Abf = bf16(Bbf @ W2) ; out = relu(csr_sum(Abf)*nin + b2)
    gemm_mfma_kernel<64, true><<<GB, 256, 0, stream>>>(Bbf, nullptr, W2T, Abf, N);
    agg64_kernel<<<(N * 64 + 255) / 256, 256, 0, stream>>>(
        (const __hip_bfloat16*)Abf, esrc, rowstart, cnt_dst, nin, b2, out, N);
}